// Round 2
// baseline (418.686 us; speedup 1.0000x reference)
//
#include <hip/hip_runtime.h>
#include <hip/hip_bf16.h>
#include <stdint.h>

typedef unsigned short u16;
typedef __attribute__((ext_vector_type(8))) short short8;
typedef __attribute__((ext_vector_type(4))) float f32x4;

#define S_LEN 2048
#define D_DIM 1024
#define NHEAD 16
#define HDIM 64
#define NROWS 4096

__device__ __forceinline__ u16 f2bf(float f) {
  union { float f; uint32_t u; } c; c.f = f;
  uint32_t r = (c.u + 0x7fffu + ((c.u >> 16) & 1u)) >> 16;
  return (u16)r;
}

__device__ __forceinline__ void gload_lds16(const void* g, void* l) {
  typedef const __attribute__((address_space(1))) unsigned int gq_t;
  typedef __attribute__((address_space(3))) unsigned int lq_t;
  __builtin_amdgcn_global_load_lds((gq_t*)(uintptr_t)g,
                                   (lq_t*)(uint32_t)(uintptr_t)l, 16, 0, 0);
}

// ---------------- fp32 -> bf16 cast ----------------
__global__ __launch_bounds__(256) void cast_kernel(const float* __restrict__ src,
                                                   u16* __restrict__ dst, int n4) {
  int i = blockIdx.x * 256 + threadIdx.x;
  if (i >= n4) return;
  float4 v = ((const float4*)src)[i];
  ushort4 o = make_ushort4(f2bf(v.x), f2bf(v.y), f2bf(v.z), f2bf(v.w));
  ((ushort4*)dst)[i] = o;
}

// ---------------- LayerNorm fp32 -> bf16 ----------------
__global__ __launch_bounds__(256) void ln_kernel(const float* __restrict__ x,
                                                 const float* __restrict__ g,
                                                 const float* __restrict__ be,
                                                 u16* __restrict__ out) {
  int row = blockIdx.x;
  int tid = threadIdx.x;
  const float4 v = ((const float4*)(x + (size_t)row * D_DIM))[tid];
  float s = v.x + v.y + v.z + v.w;
  float s2 = v.x * v.x + v.y * v.y + v.z * v.z + v.w * v.w;
#pragma unroll
  for (int off = 1; off < 64; off <<= 1) {
    s += __shfl_xor(s, off);
    s2 += __shfl_xor(s2, off);
  }
  __shared__ float ss[4], ss2[4];
  if ((tid & 63) == 0) { ss[tid >> 6] = s; ss2[tid >> 6] = s2; }
  __syncthreads();
  s = ss[0] + ss[1] + ss[2] + ss[3];
  s2 = ss2[0] + ss2[1] + ss2[2] + ss2[3];
  float mu = s * (1.0f / D_DIM);
  float var = s2 * (1.0f / D_DIM) - mu * mu;
  float rs = rsqrtf(var + 1e-5f);
  float4 gv = ((const float4*)g)[tid];
  float4 bv = ((const float4*)be)[tid];
  ushort4 o = make_ushort4(f2bf((v.x - mu) * rs * gv.x + bv.x),
                           f2bf((v.y - mu) * rs * gv.y + bv.y),
                           f2bf((v.z - mu) * rs * gv.z + bv.z),
                           f2bf((v.w - mu) * rs * gv.w + bv.w));
  ((ushort4*)(out + (size_t)row * D_DIM))[tid] = o;
}

// ---------------- NT GEMM: C[M,N] = A[M,K] * B[N,K]^T (bf16 in, MFMA) -------
// EPI 0: bf16 out. EPI 1: f32 out = acc + bias[col] + resid[idx].
// EPI 2: bf16 out = relu(acc + bias[col]).
template <int EPI>
__global__ __launch_bounds__(256) void gemm_bt(const u16* __restrict__ A,
                                               const u16* __restrict__ Bw,
                                               void* __restrict__ Cout,
                                               const float* __restrict__ bias,
                                               const float* __restrict__ resid,
                                               int M, int N, int K) {
  __shared__ u16 lsA[128 * 64];
  __shared__ u16 lsB[128 * 64];
  const int tid = threadIdx.x;
  const int wid = tid >> 6, lane = tid & 63;
  const int l4 = lane & 15, lh = lane >> 4;
  const int nbn = N >> 7;
  const int bm = blockIdx.x / nbn, bn = blockIdx.x % nbn;
  const int wr = wid >> 1, wc = wid & 1;

  f32x4 acc[4][4];
#pragma unroll
  for (int i = 0; i < 4; ++i)
#pragma unroll
    for (int j = 0; j < 4; ++j) acc[i][j] = (f32x4){0.f, 0.f, 0.f, 0.f};

  const u16* Ab = A + (size_t)bm * 128 * K;
  const u16* Bb = Bw + (size_t)bn * 128 * K;
  const int srow = (lane >> 3);     // 0..7
  const int scol = (lane & 7) * 8;  // 0..56

  for (int k0 = 0; k0 < K; k0 += 64) {
#pragma unroll
    for (int c = 0; c < 4; ++c) {
      int ch = wid * 4 + c;
      int row = ch * 8 + srow;
      gload_lds16(Ab + (size_t)row * K + k0 + scol, &lsA[ch * 512]);
      gload_lds16(Bb + (size_t)row * K + k0 + scol, &lsB[ch * 512]);
    }
    __syncthreads();
#pragma unroll
    for (int ks = 0; ks < 2; ++ks) {
      short8 af[4], bf[4];
#pragma unroll
      for (int i = 0; i < 4; ++i) {
        af[i] = *(const short8*)&lsA[(wr * 64 + i * 16 + l4) * 64 + ks * 32 + lh * 8];
        bf[i] = *(const short8*)&lsB[(wc * 64 + i * 16 + l4) * 64 + ks * 32 + lh * 8];
      }
#pragma unroll
      for (int i = 0; i < 4; ++i)
#pragma unroll
        for (int j = 0; j < 4; ++j)
          acc[i][j] = __builtin_amdgcn_mfma_f32_16x16x32_bf16(af[i], bf[j], acc[i][j], 0, 0, 0);
    }
    __syncthreads();
  }

  const int row0 = bm * 128 + wr * 64;
  const int col0 = bn * 128 + wc * 64;
#pragma unroll
  for (int i = 0; i < 4; ++i) {
#pragma unroll
    for (int j = 0; j < 4; ++j) {
      int col = col0 + j * 16 + l4;
#pragma unroll
      for (int r = 0; r < 4; ++r) {
        int row = row0 + i * 16 + lh * 4 + r;
        size_t idx = (size_t)row * N + col;
        float v = acc[i][j][r];
        if (EPI == 0) {
          ((u16*)Cout)[idx] = f2bf(v);
        } else if (EPI == 1) {
          ((float*)Cout)[idx] = v + bias[col] + resid[idx];
        } else {
          v += bias[col];
          ((u16*)Cout)[idx] = f2bf(v > 0.f ? v : 0.f);
        }
      }
    }
  }
}

// ---------------- Flash attention with ALiBi (non-causal) ----------------
// qkv: (4096, 3072) bf16 rows = b*2048+s, [q|k|v] each 1024 (h*64+d)
// ao : (4096, 1024) bf16
__global__ __launch_bounds__(256) void attn_kernel(const u16* __restrict__ qkv,
                                                   u16* __restrict__ ao) {
  const int qt = blockIdx.x;  // 0..31 q-tile
  const int bh = blockIdx.y;  // 0..31
  const int b = bh >> 4, h = bh & 15;
  const int tid = threadIdx.x;
  const int wid = tid >> 6, lane = tid & 63;
  const int l4 = lane & 15, lh = lane >> 4;

  __shared__ u16 Kt[64 * 64];  // [key][d], XOR-swizzled
  __shared__ u16 Vt[64 * 64];  // [d][key], XOR-swizzled (transposed)
  __shared__ u16 Pt[64 * 64];  // [qrow][key], XOR-swizzled, per-wave 16 rows

  const size_t RS = 3 * D_DIM;
  const u16* base = qkv + (size_t)b * S_LEN * RS + h * HDIM;
  const u16* kbase = base + D_DIM;
  const u16* vbase = base + 2 * D_DIM;

  short8 qf[2];
  {
    const u16* qp = base + (size_t)(qt * 64 + wid * 16 + l4) * RS + lh * 8;
    qf[0] = *(const short8*)qp;
    qf[1] = *(const short8*)(qp + 32);
  }

  const float slope = exp2f(-0.5f * (float)(h + 1));
  float m_r[4], l_r[4];
  f32x4 accO[4];
#pragma unroll
  for (int r = 0; r < 4; ++r) { m_r[r] = -1e30f; l_r[r] = 0.f; }
#pragma unroll
  for (int nd = 0; nd < 4; ++nd) accO[nd] = (f32x4){0.f, 0.f, 0.f, 0.f};

  const int ig = qt * 64 + wid * 16 + lh * 4;  // + r

  for (int kt = 0; kt < 32; ++kt) {
    __syncthreads();  // protect K/V LDS from previous iteration's readers
#pragma unroll
    for (int c = 0; c < 2; ++c) {
      int idx = tid + c * 256;
      int key = idx >> 3;
      int d8 = (idx & 7) * 8;
      short8 kv = *(const short8*)(kbase + (size_t)(kt * 64 + key) * RS + d8);
      *(short8*)((char*)Kt + key * 128 + ((d8 * 2) ^ ((key & 7) << 4))) = kv;
      short8 vv = *(const short8*)(vbase + (size_t)(kt * 64 + key) * RS + d8);
#pragma unroll
      for (int j = 0; j < 8; ++j) {
        int d = d8 + j;
        *(u16*)((char*)Vt + d * 128 + ((key * 2) ^ ((d & 7) << 4))) = (u16)vv[j];
      }
    }
    __syncthreads();

    // S = Q * K^T  (rows=q, cols=key)
    f32x4 sacc[4];
#pragma unroll
    for (int nb = 0; nb < 4; ++nb) sacc[nb] = (f32x4){0.f, 0.f, 0.f, 0.f};
#pragma unroll
    for (int ks = 0; ks < 2; ++ks) {
#pragma unroll
      for (int nb = 0; nb < 4; ++nb) {
        int krow = nb * 16 + l4;
        short8 kf = *(const short8*)((char*)Kt + krow * 128 +
                                     (((ks * 32 + lh * 8) * 2) ^ ((krow & 7) << 4)));
        sacc[nb] = __builtin_amdgcn_mfma_f32_16x16x32_bf16(qf[ks], kf, sacc[nb], 0, 0, 0);
      }
    }

    // online softmax with ALiBi bias
    float pv[4][4];
    float tmax[4] = {-1e30f, -1e30f, -1e30f, -1e30f};
    const int jg = kt * 64 + l4;
#pragma unroll
    for (int nb = 0; nb < 4; ++nb)
#pragma unroll
      for (int r = 0; r < 4; ++r) {
        float v = sacc[nb][r] * 0.125f + slope * (float)(jg + nb * 16 - ig - r);
        pv[nb][r] = v;
        tmax[r] = fmaxf(tmax[r], v);
      }
#pragma unroll
    for (int off = 1; off < 16; off <<= 1)
#pragma unroll
      for (int r = 0; r < 4; ++r) tmax[r] = fmaxf(tmax[r], __shfl_xor(tmax[r], off));
    float corr[4], rsum[4];
#pragma unroll
    for (int r = 0; r < 4; ++r) {
      float mn = fmaxf(m_r[r], tmax[r]);
      corr[r] = __expf(m_r[r] - mn);
      m_r[r] = mn;
      rsum[r] = 0.f;
    }
#pragma unroll
    for (int nb = 0; nb < 4; ++nb)
#pragma unroll
      for (int r = 0; r < 4; ++r) {
        float p = __expf(pv[nb][r] - m_r[r]);
        pv[nb][r] = p;
        rsum[r] += p;
      }
#pragma unroll
    for (int off = 1; off < 16; off <<= 1)
#pragma unroll
      for (int r = 0; r < 4; ++r) rsum[r] += __shfl_xor(rsum[r], off);
#pragma unroll
    for (int r = 0; r < 4; ++r) l_r[r] = l_r[r] * corr[r] + rsum[r];
#pragma unroll
    for (int nd = 0; nd < 4; ++nd)
#pragma unroll
      for (int r = 0; r < 4; ++r) accO[nd][r] *= corr[r];

    // P -> LDS (wave-private 16 rows), then PV MFMAs
#pragma unroll
    for (int nb = 0; nb < 4; ++nb)
#pragma unroll
      for (int r = 0; r < 4; ++r) {
        int prow = wid * 16 + lh * 4 + r;
        int pcol = nb * 16 + l4;
        *(u16*)((char*)Pt + prow * 128 + ((pcol * 2) ^ ((prow & 7) << 4))) = f2bf(pv[nb][r]);
      }
    asm volatile("s_waitcnt lgkmcnt(0)" ::: "memory");

#pragma unroll
    for (int ks = 0; ks < 2; ++ks) {
      int prow = wid * 16 + l4;
      short8 pf = *(const short8*)((char*)Pt + prow * 128 +
                                   (((ks * 32 + lh * 8) * 2) ^ ((prow & 7) << 4)));
#pragma unroll
      for (int nd = 0; nd < 4; ++nd) {
        int vrow = nd * 16 + l4;
        short8 vf = *(const short8*)((char*)Vt + vrow * 128 +
                                     (((ks * 32 + lh * 8) * 2) ^ ((vrow & 7) << 4)));
        accO[nd] = __builtin_amdgcn_mfma_f32_16x16x32_bf16(pf, vf, accO[nd], 0, 0, 0);
      }
    }
  }

  u16* aop = ao + ((size_t)(b * S_LEN + qt * 64 + wid * 16 + lh * 4)) * D_DIM + h * HDIM;
#pragma unroll
  for (int nd = 0; nd < 4; ++nd)
#pragma unroll
    for (int r = 0; r < 4; ++r)
      aop[(size_t)r * D_DIM + nd * 16 + l4] = f2bf(accO[nd][r] / l_r[r]);
}

extern "C" void kernel_launch(void* const* d_in, const int* in_sizes, int n_in,
                              void* d_out, int out_size, void* d_ws, size_t ws_size,
                              hipStream_t stream) {
  const float* x   = (const float*)d_in[0];
  const float* Wq  = (const float*)d_in[1];
  const float* Wk  = (const float*)d_in[2];
  const float* Wv  = (const float*)d_in[3];
  const float* Wo  = (const float*)d_in[4];
  const float* bo  = (const float*)d_in[5];
  const float* W1  = (const float*)d_in[6];
  const float* b1  = (const float*)d_in[7];
  const float* W2  = (const float*)d_in[8];
  const float* b2  = (const float*)d_in[9];
  const float* g1  = (const float*)d_in[10];
  const float* be1 = (const float*)d_in[11];
  const float* g2  = (const float*)d_in[12];
  const float* be2 = (const float*)d_in[13];

  char* p = (char*)d_ws;
  u16* wqkv = (u16*)p; p += (size_t)3072 * 1024 * 2;
  u16* wo   = (u16*)p; p += (size_t)1024 * 1024 * 2;
  u16* w1   = (u16*)p; p += (size_t)4096 * 1024 * 2;
  u16* w2   = (u16*)p; p += (size_t)4096 * 1024 * 2;
  u16* hb   = (u16*)p; p += (size_t)4096 * 1024 * 2;
  u16* qkvb = (u16*)p; p += (size_t)4096 * 3072 * 2;
  u16* aob  = (u16*)p; p += (size_t)4096 * 1024 * 2;
  float* x1 = (float*)p; p += (size_t)4096 * 1024 * 4;
  u16* h2b  = (u16*)p; p += (size_t)4096 * 1024 * 2;
  u16* ff1  = (u16*)p; p += (size_t)4096 * 4096 * 2;

  // weight casts
  cast_kernel<<<1024, 256, 0, stream>>>(Wq, wqkv, 262144);
  cast_kernel<<<1024, 256, 0, stream>>>(Wk, wqkv + 1024 * 1024, 262144);
  cast_kernel<<<1024, 256, 0, stream>>>(Wv, wqkv + 2 * 1024 * 1024, 262144);
  cast_kernel<<<1024, 256, 0, stream>>>(Wo, wo, 262144);
  cast_kernel<<<4096, 256, 0, stream>>>(W1, w1, 1048576);
  cast_kernel<<<4096, 256, 0, stream>>>(W2, w2, 1048576);

  // h = LN1(x)
  ln_kernel<<<4096, 256, 0, stream>>>(x, g1, be1, hb);
  // qkv = h @ [Wq|Wk|Wv]^T
  gemm_bt<0><<<32 * 24, 256, 0, stream>>>(hb, wqkv, qkvb, nullptr, nullptr, 4096, 3072, 1024);
  // attention
  attn_kernel<<<dim3(32, 32), 256, 0, stream>>>(qkvb, aob);
  // x1 = x + ao @ Wo^T + bo
  gemm_bt<1><<<32 * 8, 256, 0, stream>>>(aob, wo, x1, bo, x, 4096, 1024, 1024);
  // h2 = LN2(x1)
  ln_kernel<<<4096, 256, 0, stream>>>(x1, g2, be2, h2b);
  // ff1 = relu(h2 @ W1^T + b1)
  gemm_bt<2><<<32 * 32, 256, 0, stream>>>(h2b, w1, ff1, b1, nullptr, 4096, 4096, 1024);
  // out = x1 + ff1 @ W2^T + b2
  gemm_bt<1><<<32 * 8, 256, 0, stream>>>(ff1, w2, (float*)d_out, b2, x1, 4096, 1024, 4096);
}

// Round 3
// 395.888 us; speedup vs baseline: 1.0576x; 1.0576x over previous
//
#include <hip/hip_runtime.h>
#include <hip/hip_bf16.h>
#include <stdint.h>

typedef unsigned short u16;
typedef __attribute__((ext_vector_type(8))) short short8;
typedef __attribute__((ext_vector_type(4))) float f32x4;

#define S_LEN 2048
#define D_DIM 1024
#define NHEAD 16
#define HDIM 64
#define NROWS 4096

__device__ __forceinline__ u16 f2bf(float f) {
  union { float f; uint32_t u; } c; c.f = f;
  uint32_t r = (c.u + 0x7fffu + ((c.u >> 16) & 1u)) >> 16;
  return (u16)r;
}

__device__ __forceinline__ void gload_lds16(const void* g, void* l) {
  typedef const __attribute__((address_space(1))) unsigned int gq_t;
  typedef __attribute__((address_space(3))) unsigned int lq_t;
  __builtin_amdgcn_global_load_lds((gq_t*)(uintptr_t)g,
                                   (lq_t*)(uint32_t)(uintptr_t)l, 16, 0, 0);
}

// ---------------- fp32 -> bf16 cast ----------------
__global__ __launch_bounds__(256) void cast_kernel(const float* __restrict__ src,
                                                   u16* __restrict__ dst, int n4) {
  int i = blockIdx.x * 256 + threadIdx.x;
  if (i >= n4) return;
  float4 v = ((const float4*)src)[i];
  ushort4 o = make_ushort4(f2bf(v.x), f2bf(v.y), f2bf(v.z), f2bf(v.w));
  ((ushort4*)dst)[i] = o;
}

// ---------------- LayerNorm fp32 -> bf16 ----------------
__global__ __launch_bounds__(256) void ln_kernel(const float* __restrict__ x,
                                                 const float* __restrict__ g,
                                                 const float* __restrict__ be,
                                                 u16* __restrict__ out) {
  int row = blockIdx.x;
  int tid = threadIdx.x;
  const float4 v = ((const float4*)(x + (size_t)row * D_DIM))[tid];
  float s = v.x + v.y + v.z + v.w;
  float s2 = v.x * v.x + v.y * v.y + v.z * v.z + v.w * v.w;
#pragma unroll
  for (int off = 1; off < 64; off <<= 1) {
    s += __shfl_xor(s, off);
    s2 += __shfl_xor(s2, off);
  }
  __shared__ float ss[4], ss2[4];
  if ((tid & 63) == 0) { ss[tid >> 6] = s; ss2[tid >> 6] = s2; }
  __syncthreads();
  s = ss[0] + ss[1] + ss[2] + ss[3];
  s2 = ss2[0] + ss2[1] + ss2[2] + ss2[3];
  float mu = s * (1.0f / D_DIM);
  float var = s2 * (1.0f / D_DIM) - mu * mu;
  float rs = rsqrtf(var + 1e-5f);
  float4 gv = ((const float4*)g)[tid];
  float4 bv = ((const float4*)be)[tid];
  ushort4 o = make_ushort4(f2bf((v.x - mu) * rs * gv.x + bv.x),
                           f2bf((v.y - mu) * rs * gv.y + bv.y),
                           f2bf((v.z - mu) * rs * gv.z + bv.z),
                           f2bf((v.w - mu) * rs * gv.w + bv.w));
  ((ushort4*)(out + (size_t)row * D_DIM))[tid] = o;
}

// ---------------- NT GEMM: C[M,N] = A[M,K] * B[N,K]^T (bf16 in, MFMA) -------
template <int EPI>
__global__ __launch_bounds__(256) void gemm_bt(const u16* __restrict__ A,
                                               const u16* __restrict__ Bw,
                                               void* __restrict__ Cout,
                                               const float* __restrict__ bias,
                                               const float* __restrict__ resid,
                                               int M, int N, int K) {
  __shared__ u16 lsA[128 * 64];
  __shared__ u16 lsB[128 * 64];
  const int tid = threadIdx.x;
  const int wid = tid >> 6, lane = tid & 63;
  const int l4 = lane & 15, lh = lane >> 4;
  const int nbn = N >> 7;
  const int bm = blockIdx.x / nbn, bn = blockIdx.x % nbn;
  const int wr = wid >> 1, wc = wid & 1;

  f32x4 acc[4][4];
#pragma unroll
  for (int i = 0; i < 4; ++i)
#pragma unroll
    for (int j = 0; j < 4; ++j) acc[i][j] = (f32x4){0.f, 0.f, 0.f, 0.f};

  const u16* Ab = A + (size_t)bm * 128 * K;
  const u16* Bb = Bw + (size_t)bn * 128 * K;
  const int srow = (lane >> 3);     // 0..7
  const int scol = (lane & 7) * 8;  // 0..56

  for (int k0 = 0; k0 < K; k0 += 64) {
#pragma unroll
    for (int c = 0; c < 4; ++c) {
      int ch = wid * 4 + c;
      int row = ch * 8 + srow;
      gload_lds16(Ab + (size_t)row * K + k0 + scol, &lsA[ch * 512]);
      gload_lds16(Bb + (size_t)row * K + k0 + scol, &lsB[ch * 512]);
    }
    __syncthreads();
#pragma unroll
    for (int ks = 0; ks < 2; ++ks) {
      short8 af[4], bf[4];
#pragma unroll
      for (int i = 0; i < 4; ++i) {
        af[i] = *(const short8*)&lsA[(wr * 64 + i * 16 + l4) * 64 + ks * 32 + lh * 8];
        bf[i] = *(const short8*)&lsB[(wc * 64 + i * 16 + l4) * 64 + ks * 32 + lh * 8];
      }
#pragma unroll
      for (int i = 0; i < 4; ++i)
#pragma unroll
        for (int j = 0; j < 4; ++j)
          acc[i][j] = __builtin_amdgcn_mfma_f32_16x16x32_bf16(af[i], bf[j], acc[i][j], 0, 0, 0);
    }
    __syncthreads();
  }

  const int row0 = bm * 128 + wr * 64;
  const int col0 = bn * 128 + wc * 64;
#pragma unroll
  for (int i = 0; i < 4; ++i) {
#pragma unroll
    for (int j = 0; j < 4; ++j) {
      int col = col0 + j * 16 + l4;
#pragma unroll
      for (int r = 0; r < 4; ++r) {
        int row = row0 + i * 16 + lh * 4 + r;
        size_t idx = (size_t)row * N + col;
        float v = acc[i][j][r];
        if (EPI == 0) {
          ((u16*)Cout)[idx] = f2bf(v);
        } else if (EPI == 1) {
          ((float*)Cout)[idx] = v + bias[col] + resid[idx];
        } else {
          v += bias[col];
          ((u16*)Cout)[idx] = f2bf(v > 0.f ? v : 0.f);
        }
      }
    }
  }
}

// ---------------- V transpose: qkv V-region -> vt[b,h,d,s] ----------------
// One wave transposes a 64s x 64d tile. Coalesced 128B reads, 16B scattered
// stores (write-combined in L2).
__global__ __launch_bounds__(256) void transpose_v(const u16* __restrict__ qkv,
                                                   u16* __restrict__ vt) {
  const int gw = blockIdx.x * 4 + (threadIdx.x >> 6);  // 0..1023
  const int lane = threadIdx.x & 63;                   // = d
  const int bh = gw >> 5;                              // 0..31
  const int st = gw & 31;                              // s-tile
  const int b = bh >> 4, h = bh & 15;
  const u16* src = qkv + (size_t)(b * S_LEN + st * 64) * 3072 + 2048 + h * 64 + lane;
  short8 acc8[8];
#pragma unroll
  for (int o = 0; o < 8; ++o)
#pragma unroll
    for (int i = 0; i < 8; ++i)
      acc8[o][i] = (short)src[(size_t)(o * 8 + i) * 3072];
  u16* dst = vt + ((size_t)bh * 64 + lane) * S_LEN + st * 64;
#pragma unroll
  for (int o = 0; o < 8; ++o) *(short8*)(dst + o * 8) = acc8[o];
}

// ---------------- Flash attention with ALiBi (non-causal) ----------------
// qkv: (4096, 3072) bf16 rows = b*2048+s, [q|k|v]; vt: (32, 64, 2048) bf16
// ao : (4096, 1024) bf16
__global__ __launch_bounds__(256) void attn_kernel(const u16* __restrict__ qkv,
                                                   const u16* __restrict__ vt,
                                                   u16* __restrict__ ao) {
  const int qt = blockIdx.x;  // 0..31 q-tile
  const int bh = blockIdx.y;  // 0..31
  const int b = bh >> 4, h = bh & 15;
  const int tid = threadIdx.x;
  const int wid = tid >> 6, lane = tid & 63;
  const int l4 = lane & 15, lh = lane >> 4;

  __shared__ u16 Kt[64 * 64];  // [key][d], XOR-swizzled
  __shared__ u16 Vt[64 * 64];  // [d][key], XOR-swizzled
  __shared__ u16 Pt[64 * 64];  // [qrow][key], XOR-swizzled, per-wave 16 rows

  const size_t RS = 3 * D_DIM;
  const u16* base = qkv + (size_t)b * S_LEN * RS + h * HDIM;
  const u16* kbase = base + D_DIM;
  const u16* vtb = vt + (size_t)bh * HDIM * S_LEN;

  short8 qf[2];
  {
    const u16* qp = base + (size_t)(qt * 64 + wid * 16 + l4) * RS + lh * 8;
    qf[0] = *(const short8*)qp;
    qf[1] = *(const short8*)(qp + 32);
  }

  // log2-domain softmax: fold log2(e) into scale and slope
  const float slope = exp2f(-0.5f * (float)(h + 1)) * 1.44269504088896f;
  const float scale2 = 0.125f * 1.44269504088896f;
  float m_r[4], l_r[4];
  f32x4 accO[4];
#pragma unroll
  for (int r = 0; r < 4; ++r) { m_r[r] = -1e30f; l_r[r] = 0.f; }
#pragma unroll
  for (int nd = 0; nd < 4; ++nd) accO[nd] = (f32x4){0.f, 0.f, 0.f, 0.f};

  const int ig = qt * 64 + wid * 16 + lh * 4;  // + r

  // staging lambda: tile kt -> regs
  const int srow = tid >> 3;          // 0..31 (+32 for c=1)
  const int sc8 = (tid & 7) * 8;      // 0..56
  short8 kreg[2], vreg[2];
#define STAGE_LOAD(KT)                                                              \
  {                                                                                 \
    kreg[0] = *(const short8*)(kbase + (size_t)((KT)*64 + srow) * RS + sc8);        \
    kreg[1] = *(const short8*)(kbase + (size_t)((KT)*64 + srow + 32) * RS + sc8);   \
    vreg[0] = *(const short8*)(vtb + (size_t)srow * S_LEN + (KT)*64 + sc8);         \
    vreg[1] = *(const short8*)(vtb + (size_t)(srow + 32) * S_LEN + (KT)*64 + sc8);  \
  }
#define STAGE_WRITE()                                                                  \
  {                                                                                    \
    *(short8*)((char*)Kt + srow * 128 + ((sc8 * 2) ^ ((srow & 7) << 4))) = kreg[0];    \
    *(short8*)((char*)Kt + (srow + 32) * 128 + ((sc8 * 2) ^ (((srow + 32) & 7) << 4))) = kreg[1]; \
    *(short8*)((char*)Vt + srow * 128 + ((sc8 * 2) ^ ((srow & 7) << 4))) = vreg[0];    \
    *(short8*)((char*)Vt + (srow + 32) * 128 + ((sc8 * 2) ^ (((srow + 32) & 7) << 4))) = vreg[1]; \
  }

  STAGE_LOAD(31);
  STAGE_WRITE();
  __syncthreads();

  // reverse order: largest ALiBi bias first -> running max set early (T13)
  for (int kt = 31; kt >= 0; --kt) {
    if (kt > 0) STAGE_LOAD(kt - 1);  // async: latency hides under compute (T14)

    // S = Q * K^T
    f32x4 sacc[4];
#pragma unroll
    for (int nb = 0; nb < 4; ++nb) sacc[nb] = (f32x4){0.f, 0.f, 0.f, 0.f};
#pragma unroll
    for (int ks = 0; ks < 2; ++ks) {
#pragma unroll
      for (int nb = 0; nb < 4; ++nb) {
        int krow = nb * 16 + l4;
        short8 kf = *(const short8*)((char*)Kt + krow * 128 +
                                     (((ks * 32 + lh * 8) * 2) ^ ((krow & 7) << 4)));
        sacc[nb] = __builtin_amdgcn_mfma_f32_16x16x32_bf16(qf[ks], kf, sacc[nb], 0, 0, 0);
      }
    }

    // online softmax (log2 domain) with ALiBi bias
    float pv[4][4];
    float tmax[4] = {-1e30f, -1e30f, -1e30f, -1e30f};
    const int jg = kt * 64 + l4;
#pragma unroll
    for (int nb = 0; nb < 4; ++nb)
#pragma unroll
      for (int r = 0; r < 4; ++r) {
        float v = sacc[nb][r] * scale2 + slope * (float)(jg + nb * 16 - ig - r);
        pv[nb][r] = v;
        tmax[r] = fmaxf(tmax[r], v);
      }
#pragma unroll
    for (int off = 1; off < 16; off <<= 1)
#pragma unroll
      for (int r = 0; r < 4; ++r) tmax[r] = fmaxf(tmax[r], __shfl_xor(tmax[r], off));

    bool grow = (tmax[0] > m_r[0]) | (tmax[1] > m_r[1]) |
                (tmax[2] > m_r[2]) | (tmax[3] > m_r[3]);
    if (__any(grow)) {
      float corr[4];
#pragma unroll
      for (int r = 0; r < 4; ++r) {
        float mn = fmaxf(m_r[r], tmax[r]);
        corr[r] = exp2f(m_r[r] - mn);
        m_r[r] = mn;
        l_r[r] *= corr[r];
      }
#pragma unroll
      for (int nd = 0; nd < 4; ++nd)
#pragma unroll
        for (int r = 0; r < 4; ++r) accO[nd][r] *= corr[r];
    }

    float rsum[4] = {0.f, 0.f, 0.f, 0.f};
#pragma unroll
    for (int nb = 0; nb < 4; ++nb)
#pragma unroll
      for (int r = 0; r < 4; ++r) {
        float p = exp2f(pv[nb][r] - m_r[r]);
        pv[nb][r] = p;
        rsum[r] += p;
      }
#pragma unroll
    for (int off = 1; off < 16; off <<= 1)
#pragma unroll
      for (int r = 0; r < 4; ++r) rsum[r] += __shfl_xor(rsum[r], off);
#pragma unroll
    for (int r = 0; r < 4; ++r) l_r[r] += rsum[r];

    // P -> LDS (wave-private rows), then PV MFMAs
#pragma unroll
    for (int nb = 0; nb < 4; ++nb)
#pragma unroll
      for (int r = 0; r < 4; ++r) {
        int prow = wid * 16 + lh * 4 + r;
        int pcol = nb * 16 + l4;
        *(u16*)((char*)Pt + prow * 128 + ((pcol * 2) ^ ((prow & 7) << 4))) = f2bf(pv[nb][r]);
      }
    asm volatile("s_waitcnt lgkmcnt(0)" ::: "memory");

#pragma unroll
    for (int ks = 0; ks < 2; ++ks) {
      int prow = wid * 16 + l4;
      short8 pf = *(const short8*)((char*)Pt + prow * 128 +
                                   (((ks * 32 + lh * 8) * 2) ^ ((prow & 7) << 4)));
#pragma unroll
      for (int nd = 0; nd < 4; ++nd) {
        int vrow = nd * 16 + l4;
        short8 vf = *(const short8*)((char*)Vt + vrow * 128 +
                                     (((ks * 32 + lh * 8) * 2) ^ ((vrow & 7) << 4)));
        accO[nd] = __builtin_amdgcn_mfma_f32_16x16x32_bf16(pf, vf, accO[nd], 0, 0, 0);
      }
    }

    if (kt > 0) {
      __syncthreads();  // all waves done reading Kt/Vt
      STAGE_WRITE();    // compiler inserts vmcnt wait on kreg/vreg
      __syncthreads();  // staged tile visible
    }
  }

  u16* aop = ao + ((size_t)(b * S_LEN + qt * 64 + wid * 16 + lh * 4)) * D_DIM + h * HDIM;
#pragma unroll
  for (int nd = 0; nd < 4; ++nd) {
#pragma unroll
    for (int r = 0; r < 4; ++r) {
      float inv = 1.0f / l_r[r];
      aop[(size_t)r * D_DIM + nd * 16 + l4] = f2bf(accO[nd][r] * inv);
    }
  }
#undef STAGE_LOAD
#undef STAGE_WRITE
}

extern "C" void kernel_launch(void* const* d_in, const int* in_sizes, int n_in,
                              void* d_out, int out_size, void* d_ws, size_t ws_size,
                              hipStream_t stream) {
  const float* x   = (const float*)d_in[0];
  const float* Wq  = (const float*)d_in[1];
  const float* Wk  = (const float*)d_in[2];
  const float* Wv  = (const float*)d_in[3];
  const float* Wo  = (const float*)d_in[4];
  const float* bo  = (const float*)d_in[5];
  const float* W1  = (const float*)d_in[6];
  const float* b1  = (const float*)d_in[7];
  const float* W2  = (const float*)d_in[8];
  const float* b2  = (const float*)d_in[9];
  const float* g1  = (const float*)d_in[10];
  const float* be1 = (const float*)d_in[11];
  const float* g2  = (const float*)d_in[12];
  const float* be2 = (const float*)d_in[13];

  char* p = (char*)d_ws;
  u16* wqkv = (u16*)p; p += (size_t)3072 * 1024 * 2;
  u16* wo   = (u16*)p; p += (size_t)1024 * 1024 * 2;
  u16* w1   = (u16*)p; p += (size_t)4096 * 1024 * 2;
  u16* w2   = (u16*)p; p += (size_t)4096 * 1024 * 2;
  u16* hb   = (u16*)p; p += (size_t)4096 * 1024 * 2;
  u16* qkvb = (u16*)p; p += (size_t)4096 * 3072 * 2;
  u16* aob  = (u16*)p; p += (size_t)4096 * 1024 * 2;
  float* x1 = (float*)p; p += (size_t)4096 * 1024 * 4;
  u16* h2b  = (u16*)p; p += (size_t)4096 * 1024 * 2;
  u16* ff1  = (u16*)p; p += (size_t)4096 * 4096 * 2;
  u16* vt   = ff1;  // alias: vt dead before ff1 is written (attn before FFN1)

  // weight casts
  cast_kernel<<<1024, 256, 0, stream>>>(Wq, wqkv, 262144);
  cast_kernel<<<1024, 256, 0, stream>>>(Wk, wqkv + 1024 * 1024, 262144);
  cast_kernel<<<1024, 256, 0, stream>>>(Wv, wqkv + 2 * 1024 * 1024, 262144);
  cast_kernel<<<1024, 256, 0, stream>>>(Wo, wo, 262144);
  cast_kernel<<<4096, 256, 0, stream>>>(W1, w1, 1048576);
  cast_kernel<<<4096, 256, 0, stream>>>(W2, w2, 1048576);

  // h = LN1(x)
  ln_kernel<<<4096, 256, 0, stream>>>(x, g1, be1, hb);
  // qkv = h @ [Wq|Wk|Wv]^T
  gemm_bt<0><<<32 * 24, 256, 0, stream>>>(hb, wqkv, qkvb, nullptr, nullptr, 4096, 3072, 1024);
  // vt = V^T
  transpose_v<<<256, 256, 0, stream>>>(qkvb, vt);
  // attention
  attn_kernel<<<dim3(32, 32), 256, 0, stream>>>(qkvb, vt, aob);
  // x1 = x + ao @ Wo^T + bo
  gemm_bt<1><<<32 * 8, 256, 0, stream>>>(aob, wo, x1, bo, x, 4096, 1024, 1024);
  // h2 = LN2(x1)
  ln_kernel<<<4096, 256, 0, stream>>>(x1, g2, be2, h2b);
  // ff1 = relu(h2 @ W1^T + b1)
  gemm_bt<2><<<32 * 32, 256, 0, stream>>>(h2b, w1, ff1, b1, nullptr, 4096, 4096, 1024);
  // out = x1 + ff1 @ W2^T + b2
  gemm_bt<1><<<32 * 8, 256, 0, stream>>>(ff1, w2, (float*)d_out, b2, x1, 4096, 1024, 4096);
}

// Round 4
// 327.938 us; speedup vs baseline: 1.2767x; 1.2072x over previous
//
#include <hip/hip_runtime.h>
#include <hip/hip_bf16.h>
#include <stdint.h>

typedef unsigned short u16;
typedef __attribute__((ext_vector_type(8))) short short8;
typedef __attribute__((ext_vector_type(4))) float f32x4;

#define S_LEN 2048
#define D_DIM 1024
#define NHEAD 16
#define HDIM 64
#define NROWS 4096

__device__ __forceinline__ u16 f2bf(float f) {
  union { float f; uint32_t u; } c; c.f = f;
  uint32_t r = (c.u + 0x7fffu + ((c.u >> 16) & 1u)) >> 16;
  return (u16)r;
}

__device__ __forceinline__ uint32_t pack_bf2(float a, float b) {
  __hip_bfloat162 h = __float22bfloat162_rn(float2{a, b});
  union { __hip_bfloat162 h; uint32_t u; } c; c.h = h;
  return c.u;
}

__device__ __forceinline__ void gload_lds16(const void* g, void* l) {
  typedef const __attribute__((address_space(1))) unsigned int gq_t;
  typedef __attribute__((address_space(3))) unsigned int lq_t;
  __builtin_amdgcn_global_load_lds((gq_t*)(uintptr_t)g,
                                   (lq_t*)(uint32_t)(uintptr_t)l, 16, 0, 0);
}

// ---------------- fp32 -> bf16 cast ----------------
__global__ __launch_bounds__(256) void cast_kernel(const float* __restrict__ src,
                                                   u16* __restrict__ dst, int n4) {
  int i = blockIdx.x * 256 + threadIdx.x;
  if (i >= n4) return;
  float4 v = ((const float4*)src)[i];
  ushort4 o = make_ushort4(f2bf(v.x), f2bf(v.y), f2bf(v.z), f2bf(v.w));
  ((ushort4*)dst)[i] = o;
}

// ---------------- LayerNorm fp32 -> bf16 ----------------
__global__ __launch_bounds__(256) void ln_kernel(const float* __restrict__ x,
                                                 const float* __restrict__ g,
                                                 const float* __restrict__ be,
                                                 u16* __restrict__ out) {
  int row = blockIdx.x;
  int tid = threadIdx.x;
  const float4 v = ((const float4*)(x + (size_t)row * D_DIM))[tid];
  float s = v.x + v.y + v.z + v.w;
  float s2 = v.x * v.x + v.y * v.y + v.z * v.z + v.w * v.w;
#pragma unroll
  for (int off = 1; off < 64; off <<= 1) {
    s += __shfl_xor(s, off);
    s2 += __shfl_xor(s2, off);
  }
  __shared__ float ss[4], ss2[4];
  if ((tid & 63) == 0) { ss[tid >> 6] = s; ss2[tid >> 6] = s2; }
  __syncthreads();
  s = ss[0] + ss[1] + ss[2] + ss[3];
  s2 = ss2[0] + ss2[1] + ss2[2] + ss2[3];
  float mu = s * (1.0f / D_DIM);
  float var = s2 * (1.0f / D_DIM) - mu * mu;
  float rs = rsqrtf(var + 1e-5f);
  float4 gv = ((const float4*)g)[tid];
  float4 bv = ((const float4*)be)[tid];
  ushort4 o = make_ushort4(f2bf((v.x - mu) * rs * gv.x + bv.x),
                           f2bf((v.y - mu) * rs * gv.y + bv.y),
                           f2bf((v.z - mu) * rs * gv.z + bv.z),
                           f2bf((v.w - mu) * rs * gv.w + bv.w));
  ((ushort4*)(out + (size_t)row * D_DIM))[tid] = o;
}

// ---------------- NT GEMM: C[M,N] = A[M,K] * B[N,K]^T (bf16 in, MFMA) -------
template <int EPI>
__global__ __launch_bounds__(256) void gemm_bt(const u16* __restrict__ A,
                                               const u16* __restrict__ Bw,
                                               void* __restrict__ Cout,
                                               const float* __restrict__ bias,
                                               const float* __restrict__ resid,
                                               int M, int N, int K) {
  __shared__ u16 lsA[128 * 64];
  __shared__ u16 lsB[128 * 64];
  const int tid = threadIdx.x;
  const int wid = tid >> 6, lane = tid & 63;
  const int l4 = lane & 15, lh = lane >> 4;
  const int nbn = N >> 7;
  const int bm = blockIdx.x / nbn, bn = blockIdx.x % nbn;
  const int wr = wid >> 1, wc = wid & 1;

  f32x4 acc[4][4];
#pragma unroll
  for (int i = 0; i < 4; ++i)
#pragma unroll
    for (int j = 0; j < 4; ++j) acc[i][j] = (f32x4){0.f, 0.f, 0.f, 0.f};

  const u16* Ab = A + (size_t)bm * 128 * K;
  const u16* Bb = Bw + (size_t)bn * 128 * K;
  const int srow = (lane >> 3);     // 0..7
  const int scol = (lane & 7) * 8;  // 0..56

  for (int k0 = 0; k0 < K; k0 += 64) {
#pragma unroll
    for (int c = 0; c < 4; ++c) {
      int ch = wid * 4 + c;
      int row = ch * 8 + srow;
      gload_lds16(Ab + (size_t)row * K + k0 + scol, &lsA[ch * 512]);
      gload_lds16(Bb + (size_t)row * K + k0 + scol, &lsB[ch * 512]);
    }
    __syncthreads();
#pragma unroll
    for (int ks = 0; ks < 2; ++ks) {
      short8 af[4], bf[4];
#pragma unroll
      for (int i = 0; i < 4; ++i) {
        af[i] = *(const short8*)&lsA[(wr * 64 + i * 16 + l4) * 64 + ks * 32 + lh * 8];
        bf[i] = *(const short8*)&lsB[(wc * 64 + i * 16 + l4) * 64 + ks * 32 + lh * 8];
      }
#pragma unroll
      for (int i = 0; i < 4; ++i)
#pragma unroll
        for (int j = 0; j < 4; ++j)
          acc[i][j] = __builtin_amdgcn_mfma_f32_16x16x32_bf16(af[i], bf[j], acc[i][j], 0, 0, 0);
    }
    __syncthreads();
  }

  const int row0 = bm * 128 + wr * 64;
  const int col0 = bn * 128 + wc * 64;
#pragma unroll
  for (int i = 0; i < 4; ++i) {
#pragma unroll
    for (int j = 0; j < 4; ++j) {
      int col = col0 + j * 16 + l4;
#pragma unroll
      for (int r = 0; r < 4; ++r) {
        int row = row0 + i * 16 + lh * 4 + r;
        size_t idx = (size_t)row * N + col;
        float v = acc[i][j][r];
        if (EPI == 0) {
          ((u16*)Cout)[idx] = f2bf(v);
        } else if (EPI == 1) {
          ((float*)Cout)[idx] = v + bias[col] + resid[idx];
        } else {
          v += bias[col];
          ((u16*)Cout)[idx] = f2bf(v > 0.f ? v : 0.f);
        }
      }
    }
  }
}

// ---------------- V transpose: qkv V-region -> vt[b,h,d,s] ----------------
__global__ __launch_bounds__(256) void transpose_v(const u16* __restrict__ qkv,
                                                   u16* __restrict__ vt) {
  const int gw = blockIdx.x * 4 + (threadIdx.x >> 6);  // 0..1023
  const int lane = threadIdx.x & 63;                   // = d
  const int bh = gw >> 5;                              // 0..31
  const int st = gw & 31;                              // s-tile
  const int b = bh >> 4, h = bh & 15;
  const u16* src = qkv + (size_t)(b * S_LEN + st * 64) * 3072 + 2048 + h * 64 + lane;
  short8 acc8[8];
#pragma unroll
  for (int o = 0; o < 8; ++o)
#pragma unroll
    for (int i = 0; i < 8; ++i)
      acc8[o][i] = (short)src[(size_t)(o * 8 + i) * 3072];
  u16* dst = vt + ((size_t)bh * 64 + lane) * S_LEN + st * 64;
#pragma unroll
  for (int o = 0; o < 8; ++o) *(short8*)(dst + o * 8) = acc8[o];
}

// ---------------- Flash attention with ALiBi (swapped-S, non-causal) --------
// qkv: (4096, 3072) bf16; vt: (32, 64, 2048) bf16; ao: (4096, 1024) bf16
__global__ __launch_bounds__(256, 4) void attn_kernel(const u16* __restrict__ qkv,
                                                      const u16* __restrict__ vt,
                                                      u16* __restrict__ ao) {
  // XCD-aware mapping: all 32 q-tiles of one (b,h) land on one XCD -> K/V L2-hot
  const int id = blockIdx.x;
  const int xcd = id & 7, slot = id >> 3;
  const int bh = xcd + 8 * (slot >> 5);
  const int qt = slot & 31;
  const int b = bh >> 4, h = bh & 15;
  const int tid = threadIdx.x;
  const int wid = tid >> 6, lane = tid & 63;
  const int l4 = lane & 15, lh = lane >> 4;

  __shared__ u16 Kt[2][64 * 64];  // [key][d], 16B-block XOR-swizzled
  __shared__ u16 Vt[2][64 * 64];  // [d][key], 16B-block XOR-swizzled
  __shared__ u16 Pt[4][16 * 64];  // per-wave [q][key], swizzled

  const size_t RS = 3 * D_DIM;
  const u16* base = qkv + (size_t)b * S_LEN * RS + h * HDIM;
  const u16* kbase = base + D_DIM;
  const u16* vtb = vt + (size_t)bh * HDIM * S_LEN;
  char* PtW = (char*)Pt[wid];

  // Q fragment (B-operand: col=q=l4, k=d=lh*8+i)
  short8 qf[2];
  {
    const u16* qp = base + (size_t)(qt * 64 + wid * 16 + l4) * RS + lh * 8;
    qf[0] = *(const short8*)qp;
    qf[1] = *(const short8*)(qp + 32);
  }

  // hoisted LDS byte offsets (loop-invariant)
  int koff[4][2];  // A-frag rows nb*16+l4 (K) == B-frag rows nd*16+l4 (V^T)
#pragma unroll
  for (int nb = 0; nb < 4; ++nb)
#pragma unroll
    for (int ks = 0; ks < 2; ++ks) {
      int row = nb * 16 + l4;
      koff[nb][ks] = row * 128 + (((ks * 32 + lh * 8) * 2) ^ ((row & 7) << 4));
    }
  int poff[2];  // P A-frag read: row q=l4
#pragma unroll
  for (int ks = 0; ks < 2; ++ks)
    poff[ks] = l4 * 128 + (((ks * 64 + lh * 16)) ^ ((l4 & 7) << 4));
  int pwoff[4];  // P b64 write: keys lh*4+nb*16, row q=l4
#pragma unroll
  for (int nb = 0; nb < 4; ++nb)
    pwoff[nb] = l4 * 128 + (((lh * 8 + nb * 32)) ^ ((l4 & 7) << 4));

  // log2-domain softmax constants
  const float slope2 = exp2f(-0.5f * (float)(h + 1)) * 1.44269504088896f;
  const float scale2 = 0.125f * 1.44269504088896f;
  const int ibase = lh * 4 - (qt * 64 + wid * 16 + l4);  // key_local_base - q_global
  float bc[4][4];
#pragma unroll
  for (int nb = 0; nb < 4; ++nb)
#pragma unroll
    for (int r = 0; r < 4; ++r)
      bc[nb][r] = slope2 * (float)(ibase + 16 * nb + r);

  float m = -1e30f, l = 0.f;
  f32x4 accO[4];
#pragma unroll
  for (int nd = 0; nd < 4; ++nd) accO[nd] = (f32x4){0.f, 0.f, 0.f, 0.f};

  // staging: 512B/lane-group, double-buffered
  const int srow = tid >> 3;       // 0..31 (+32)
  const int sc8 = (tid & 7) * 8;   // 0..56
  const int swo = srow * 128 + ((sc8 * 2) ^ ((srow & 7) << 4));
  short8 kreg[2], vreg[2];
#define STAGE_LOAD(KT)                                                              \
  {                                                                                 \
    kreg[0] = *(const short8*)(kbase + (size_t)((KT)*64 + srow) * RS + sc8);        \
    kreg[1] = *(const short8*)(kbase + (size_t)((KT)*64 + srow + 32) * RS + sc8);   \
    vreg[0] = *(const short8*)(vtb + (size_t)srow * S_LEN + (KT)*64 + sc8);         \
    vreg[1] = *(const short8*)(vtb + (size_t)(srow + 32) * S_LEN + (KT)*64 + sc8);  \
  }
#define STAGE_WRITE(B)                                   \
  {                                                      \
    *(short8*)((char*)Kt[B] + swo) = kreg[0];            \
    *(short8*)((char*)Kt[B] + swo + 4096) = kreg[1];     \
    *(short8*)((char*)Vt[B] + swo) = vreg[0];            \
    *(short8*)((char*)Vt[B] + swo + 4096) = vreg[1];     \
  }

  STAGE_LOAD(31);
  STAGE_WRITE(0);
  __syncthreads();
  int cur = 0;

  for (int kt = 31; kt >= 0; --kt) {
    if (kt > 0) STAGE_LOAD(kt - 1);  // issue early, write late (T14)
    const char* Kc = (const char*)Kt[cur];
    const char* Vc = (const char*)Vt[cur];

    // S^T = K * Q^T : C[key][q], lane: q=l4, keys=lh*4+r+16nb
    f32x4 sacc[4];
#pragma unroll
    for (int nb = 0; nb < 4; ++nb) sacc[nb] = (f32x4){0.f, 0.f, 0.f, 0.f};
    __builtin_amdgcn_s_setprio(1);
#pragma unroll
    for (int ks = 0; ks < 2; ++ks)
#pragma unroll
      for (int nb = 0; nb < 4; ++nb) {
        short8 kf = *(const short8*)(Kc + koff[nb][ks]);
        sacc[nb] = __builtin_amdgcn_mfma_f32_16x16x32_bf16(kf, qf[ks], sacc[nb], 0, 0, 0);
      }
    __builtin_amdgcn_s_setprio(0);

    // biased scores (log2 domain), in-lane
    float p[4][4];
    const float ktoff = slope2 * (float)(kt * 64);
#pragma unroll
    for (int nb = 0; nb < 4; ++nb)
#pragma unroll
      for (int r = 0; r < 4; ++r)
        p[nb][r] = fmaf(sacc[nb][r], scale2, bc[nb][r] + ktoff);

    // in-lane max tree + 2 shfl
    float mx0 = fmaxf(fmaxf(p[0][0], p[0][1]), fmaxf(p[0][2], p[0][3]));
    float mx1 = fmaxf(fmaxf(p[1][0], p[1][1]), fmaxf(p[1][2], p[1][3]));
    float mx2 = fmaxf(fmaxf(p[2][0], p[2][1]), fmaxf(p[2][2], p[2][3]));
    float mx3 = fmaxf(fmaxf(p[3][0], p[3][1]), fmaxf(p[3][2], p[3][3]));
    float tm = fmaxf(fmaxf(mx0, mx1), fmaxf(mx2, mx3));
    tm = fmaxf(tm, __shfl_xor(tm, 16));
    tm = fmaxf(tm, __shfl_xor(tm, 32));

    if (__any(tm > m)) {  // rarely taken after first tile (reverse-kt, T13)
      float mn = fmaxf(m, tm);
      float corr = exp2f(m - mn);
      m = mn;
      l *= corr;
      float cb[4];
#pragma unroll
      for (int r = 0; r < 4; ++r)
        cb[r] = __shfl(corr, (lane & 48) | (lh * 4 + r));
#pragma unroll
      for (int nd = 0; nd < 4; ++nd)
#pragma unroll
        for (int r = 0; r < 4; ++r) accO[nd][r] *= cb[r];
    }

#pragma unroll
    for (int nb = 0; nb < 4; ++nb)
#pragma unroll
      for (int r = 0; r < 4; ++r) p[nb][r] = exp2f(p[nb][r] - m);

    float s0 = (p[0][0] + p[0][1]) + (p[0][2] + p[0][3]);
    float s1 = (p[1][0] + p[1][1]) + (p[1][2] + p[1][3]);
    float s2 = (p[2][0] + p[2][1]) + (p[2][2] + p[2][3]);
    float s3 = (p[3][0] + p[3][1]) + (p[3][2] + p[3][3]);
    float rs = (s0 + s1) + (s2 + s3);
    rs += __shfl_xor(rs, 16);
    rs += __shfl_xor(rs, 32);
    l += rs;

    // pack P (hw cvt_pk) and write 4 x b64 to wave-private LDS
#pragma unroll
    for (int nb = 0; nb < 4; ++nb) {
      uint32_t w0 = pack_bf2(p[nb][0], p[nb][1]);
      uint32_t w1 = pack_bf2(p[nb][2], p[nb][3]);
      *(uint2*)(PtW + pwoff[nb]) = make_uint2(w0, w1);
    }
    asm volatile("s_waitcnt lgkmcnt(0)" ::: "memory");

    // O[q][d] += P[q][k] * V^T[k][d]
    __builtin_amdgcn_s_setprio(1);
#pragma unroll
    for (int ks = 0; ks < 2; ++ks) {
      short8 pf = *(const short8*)(PtW + poff[ks]);
#pragma unroll
      for (int nd = 0; nd < 4; ++nd) {
        short8 vf = *(const short8*)(Vc + koff[nd][ks]);
        accO[nd] = __builtin_amdgcn_mfma_f32_16x16x32_bf16(pf, vf, accO[nd], 0, 0, 0);
      }
    }
    __builtin_amdgcn_s_setprio(0);

    if (kt > 0) STAGE_WRITE(cur ^ 1);  // waits vmcnt, writes other buffer
    __syncthreads();                   // single barrier per iteration
    cur ^= 1;
  }

  float rinv = 1.0f / l;
  float ib[4];
#pragma unroll
  for (int r = 0; r < 4; ++r)
    ib[r] = __shfl(rinv, (lane & 48) | (lh * 4 + r));
  u16* aop = ao + ((size_t)(b * S_LEN + qt * 64 + wid * 16 + lh * 4)) * D_DIM + h * HDIM;
#pragma unroll
  for (int nd = 0; nd < 4; ++nd)
#pragma unroll
    for (int r = 0; r < 4; ++r)
      aop[(size_t)r * D_DIM + nd * 16 + l4] = f2bf(accO[nd][r] * ib[r]);
#undef STAGE_LOAD
#undef STAGE_WRITE
}

extern "C" void kernel_launch(void* const* d_in, const int* in_sizes, int n_in,
                              void* d_out, int out_size, void* d_ws, size_t ws_size,
                              hipStream_t stream) {
  const float* x   = (const float*)d_in[0];
  const float* Wq  = (const float*)d_in[1];
  const float* Wk  = (const float*)d_in[2];
  const float* Wv  = (const float*)d_in[3];
  const float* Wo  = (const float*)d_in[4];
  const float* bo  = (const float*)d_in[5];
  const float* W1  = (const float*)d_in[6];
  const float* b1  = (const float*)d_in[7];
  const float* W2  = (const float*)d_in[8];
  const float* b2  = (const float*)d_in[9];
  const float* g1  = (const float*)d_in[10];
  const float* be1 = (const float*)d_in[11];
  const float* g2  = (const float*)d_in[12];
  const float* be2 = (const float*)d_in[13];

  char* p = (char*)d_ws;
  u16* wqkv = (u16*)p; p += (size_t)3072 * 1024 * 2;
  u16* wo   = (u16*)p; p += (size_t)1024 * 1024 * 2;
  u16* w1   = (u16*)p; p += (size_t)4096 * 1024 * 2;
  u16* w2   = (u16*)p; p += (size_t)4096 * 1024 * 2;
  u16* hb   = (u16*)p; p += (size_t)4096 * 1024 * 2;
  u16* qkvb = (u16*)p; p += (size_t)4096 * 3072 * 2;
  u16* aob  = (u16*)p; p += (size_t)4096 * 1024 * 2;
  float* x1 = (float*)p; p += (size_t)4096 * 1024 * 4;
  u16* h2b  = (u16*)p; p += (size_t)4096 * 1024 * 2;
  u16* ff1  = (u16*)p; p += (size_t)4096 * 4096 * 2;
  u16* vt   = ff1;  // alias: vt dead before ff1 is written

  cast_kernel<<<1024, 256, 0, stream>>>(Wq, wqkv, 262144);
  cast_kernel<<<1024, 256, 0, stream>>>(Wk, wqkv + 1024 * 1024, 262144);
  cast_kernel<<<1024, 256, 0, stream>>>(Wv, wqkv + 2 * 1024 * 1024, 262144);
  cast_kernel<<<1024, 256, 0, stream>>>(Wo, wo, 262144);
  cast_kernel<<<4096, 256, 0, stream>>>(W1, w1, 1048576);
  cast_kernel<<<4096, 256, 0, stream>>>(W2, w2, 1048576);

  ln_kernel<<<4096, 256, 0, stream>>>(x, g1, be1, hb);
  gemm_bt<0><<<32 * 24, 256, 0, stream>>>(hb, wqkv, qkvb, nullptr, nullptr, 4096, 3072, 1024);
  transpose_v<<<256, 256, 0, stream>>>(qkvb, vt);
  attn_kernel<<<1024, 256, 0, stream>>>(qkvb, vt, aob);
  gemm_bt<1><<<32 * 8, 256, 0, stream>>>(aob, wo, x1, bo, x, 4096, 1024, 1024);
  ln_kernel<<<4096, 256, 0, stream>>>(x1, g2, be2, h2b);
  gemm_bt<2><<<32 * 32, 256, 0, stream>>>(h2b, w1, ff1, b1, nullptr, 4096, 4096, 1024);
  gemm_bt<1><<<32 * 8, 256, 0, stream>>>(ff1, w2, (float*)d_out, b2, x1, 4096, 1024, 4096);
}

// Round 5
// 310.876 us; speedup vs baseline: 1.3468x; 1.0549x over previous
//
#include <hip/hip_runtime.h>
#include <hip/hip_bf16.h>
#include <stdint.h>

typedef unsigned short u16;
typedef __attribute__((ext_vector_type(8))) short short8;
typedef __attribute__((ext_vector_type(4))) float f32x4;

#define S_LEN 2048
#define D_DIM 1024
#define NHEAD 16
#define HDIM 64
#define NROWS 4096

__device__ __forceinline__ u16 f2bf(float f) {
  union { float f; uint32_t u; } c; c.f = f;
  uint32_t r = (c.u + 0x7fffu + ((c.u >> 16) & 1u)) >> 16;
  return (u16)r;
}

__device__ __forceinline__ uint32_t pack_bf2(float a, float b) {
  __hip_bfloat162 h = __float22bfloat162_rn(float2{a, b});
  union { __hip_bfloat162 h; uint32_t u; } c; c.h = h;
  return c.u;
}

__device__ __forceinline__ void gload_lds16(const void* g, void* l) {
  typedef const __attribute__((address_space(1))) unsigned int gq_t;
  typedef __attribute__((address_space(3))) unsigned int lq_t;
  __builtin_amdgcn_global_load_lds((gq_t*)(uintptr_t)g,
                                   (lq_t*)(uint32_t)(uintptr_t)l, 16, 0, 0);
}

// ---------------- fp32 -> bf16 cast ----------------
__global__ __launch_bounds__(256) void cast_kernel(const float* __restrict__ src,
                                                   u16* __restrict__ dst, int n4) {
  int i = blockIdx.x * 256 + threadIdx.x;
  if (i >= n4) return;
  float4 v = ((const float4*)src)[i];
  ushort4 o = make_ushort4(f2bf(v.x), f2bf(v.y), f2bf(v.z), f2bf(v.w));
  ((ushort4*)dst)[i] = o;
}

// ---------------- LayerNorm fp32 -> bf16 ----------------
__global__ __launch_bounds__(256) void ln_kernel(const float* __restrict__ x,
                                                 const float* __restrict__ g,
                                                 const float* __restrict__ be,
                                                 u16* __restrict__ out) {
  int row = blockIdx.x;
  int tid = threadIdx.x;
  const float4 v = ((const float4*)(x + (size_t)row * D_DIM))[tid];
  float s = v.x + v.y + v.z + v.w;
  float s2 = v.x * v.x + v.y * v.y + v.z * v.z + v.w * v.w;
#pragma unroll
  for (int off = 1; off < 64; off <<= 1) {
    s += __shfl_xor(s, off);
    s2 += __shfl_xor(s2, off);
  }
  __shared__ float ss[4], ss2[4];
  if ((tid & 63) == 0) { ss[tid >> 6] = s; ss2[tid >> 6] = s2; }
  __syncthreads();
  s = ss[0] + ss[1] + ss[2] + ss[3];
  s2 = ss2[0] + ss2[1] + ss2[2] + ss2[3];
  float mu = s * (1.0f / D_DIM);
  float var = s2 * (1.0f / D_DIM) - mu * mu;
  float rs = rsqrtf(var + 1e-5f);
  float4 gv = ((const float4*)g)[tid];
  float4 bv = ((const float4*)be)[tid];
  ushort4 o = make_ushort4(f2bf((v.x - mu) * rs * gv.x + bv.x),
                           f2bf((v.y - mu) * rs * gv.y + bv.y),
                           f2bf((v.z - mu) * rs * gv.z + bv.z),
                           f2bf((v.w - mu) * rs * gv.w + bv.w));
  ((ushort4*)(out + (size_t)row * D_DIM))[tid] = o;
}

// ---------------- NT GEMM: C[M,N] = A[M,K] * B[N,K]^T (bf16 in, MFMA) -------
// EPI 0: bf16 out. EPI 1: f32 out = acc + bias[col] + resid. EPI 2: bf16 relu.
// EPI 3: f32 partial acc (split-K slice -> Cout + slice*M*N).
// Grid = ksl * nwgs; per-slice ids are XCD-chunk swizzled (nwgs % 8 == 0).
template <int EPI>
__global__ __launch_bounds__(256) void gemm_bt(const u16* __restrict__ A,
                                               const u16* __restrict__ Bw,
                                               void* __restrict__ Cout,
                                               const float* __restrict__ bias,
                                               const float* __restrict__ resid,
                                               int M, int N, int K, int ksl) {
  __shared__ u16 lsA[128 * 64];
  __shared__ u16 lsB[128 * 64];
  const int tid = threadIdx.x;
  const int wid = tid >> 6, lane = tid & 63;
  const int l4 = lane & 15, lh = lane >> 4;
  const int nbn = N >> 7;
  const int nwgs = (M >> 7) * nbn;
  const int slice = blockIdx.x / nwgs;
  const int id0 = blockIdx.x % nwgs;
  // XCD-chunk swizzle (T1): XCD x gets a contiguous tile range
  const int t = (id0 & 7) * (nwgs >> 3) + (id0 >> 3);
  const int bm = t / nbn, bn = t % nbn;
  const int wr = wid >> 1, wc = wid & 1;
  const int Ks = K / ksl;

  f32x4 acc[4][4];
#pragma unroll
  for (int i = 0; i < 4; ++i)
#pragma unroll
    for (int j = 0; j < 4; ++j) acc[i][j] = (f32x4){0.f, 0.f, 0.f, 0.f};

  const u16* Ab = A + (size_t)bm * 128 * K + (size_t)slice * Ks;
  const u16* Bb = Bw + (size_t)bn * 128 * K + (size_t)slice * Ks;
  const int srow = (lane >> 3);     // 0..7
  const int scol = (lane & 7) * 8;  // 0..56

  for (int k0 = 0; k0 < Ks; k0 += 64) {
#pragma unroll
    for (int c = 0; c < 4; ++c) {
      int ch = wid * 4 + c;
      int row = ch * 8 + srow;
      gload_lds16(Ab + (size_t)row * K + k0 + scol, &lsA[ch * 512]);
      gload_lds16(Bb + (size_t)row * K + k0 + scol, &lsB[ch * 512]);
    }
    __syncthreads();
#pragma unroll
    for (int ks = 0; ks < 2; ++ks) {
      short8 af[4], bf[4];
#pragma unroll
      for (int i = 0; i < 4; ++i) {
        af[i] = *(const short8*)&lsA[(wr * 64 + i * 16 + l4) * 64 + ks * 32 + lh * 8];
        bf[i] = *(const short8*)&lsB[(wc * 64 + i * 16 + l4) * 64 + ks * 32 + lh * 8];
      }
#pragma unroll
      for (int i = 0; i < 4; ++i)
#pragma unroll
        for (int j = 0; j < 4; ++j)
          acc[i][j] = __builtin_amdgcn_mfma_f32_16x16x32_bf16(af[i], bf[j], acc[i][j], 0, 0, 0);
    }
    __syncthreads();
  }

  const int row0 = bm * 128 + wr * 64;
  const int col0 = bn * 128 + wc * 64;
  float* Cp = (float*)Cout + (size_t)slice * M * N;
#pragma unroll
  for (int i = 0; i < 4; ++i) {
#pragma unroll
    for (int j = 0; j < 4; ++j) {
      int col = col0 + j * 16 + l4;
#pragma unroll
      for (int r = 0; r < 4; ++r) {
        int row = row0 + i * 16 + lh * 4 + r;
        size_t idx = (size_t)row * N + col;
        float v = acc[i][j][r];
        if (EPI == 0) {
          ((u16*)Cout)[idx] = f2bf(v);
        } else if (EPI == 1) {
          ((float*)Cout)[idx] = v + bias[col] + resid[idx];
        } else if (EPI == 2) {
          v += bias[col];
          ((u16*)Cout)[idx] = f2bf(v > 0.f ? v : 0.f);
        } else {
          Cp[idx] = v;
        }
      }
    }
  }
}

// ---------------- split-K reduce: out = p0 + p1 + bias + resid ----------------
__global__ __launch_bounds__(256) void reduce2_kernel(const float* __restrict__ p0,
                                                      const float* __restrict__ p1,
                                                      const float* __restrict__ resid,
                                                      const float* __restrict__ bias,
                                                      float* __restrict__ out) {
  for (int i = blockIdx.x * 256 + threadIdx.x; i < (NROWS * D_DIM) / 4;
       i += gridDim.x * 256) {
    float4 a = ((const float4*)p0)[i];
    float4 b = ((const float4*)p1)[i];
    float4 r = ((const float4*)resid)[i];
    float4 bb = ((const float4*)bias)[i & 255];
    float4 o;
    o.x = a.x + b.x + r.x + bb.x;
    o.y = a.y + b.y + r.y + bb.y;
    o.z = a.z + b.z + r.z + bb.z;
    o.w = a.w + b.w + r.w + bb.w;
    ((float4*)out)[i] = o;
  }
}

// ---------------- V transpose: qkv V-region -> vt[b,h,d,s] ----------------
__global__ __launch_bounds__(256) void transpose_v(const u16* __restrict__ qkv,
                                                   u16* __restrict__ vt) {
  const int gw = blockIdx.x * 4 + (threadIdx.x >> 6);  // 0..1023
  const int lane = threadIdx.x & 63;                   // = d
  const int bh = gw >> 5;                              // 0..31
  const int st = gw & 31;                              // s-tile
  const int b = bh >> 4, h = bh & 15;
  const u16* src = qkv + (size_t)(b * S_LEN + st * 64) * 3072 + 2048 + h * 64 + lane;
  short8 acc8[8];
#pragma unroll
  for (int o = 0; o < 8; ++o)
#pragma unroll
    for (int i = 0; i < 8; ++i)
      acc8[o][i] = (short)src[(size_t)(o * 8 + i) * 3072];
  u16* dst = vt + ((size_t)bh * 64 + lane) * S_LEN + st * 64;
#pragma unroll
  for (int o = 0; o < 8; ++o) *(short8*)(dst + o * 8) = acc8[o];
}

// ---------------- Flash attention with ALiBi (swapped-S, non-causal) --------
__global__ __launch_bounds__(256, 4) void attn_kernel(const u16* __restrict__ qkv,
                                                      const u16* __restrict__ vt,
                                                      u16* __restrict__ ao) {
  const int id = blockIdx.x;
  const int xcd = id & 7, slot = id >> 3;
  const int bh = xcd + 8 * (slot >> 5);
  const int qt = slot & 31;
  const int b = bh >> 4, h = bh & 15;
  const int tid = threadIdx.x;
  const int wid = tid >> 6, lane = tid & 63;
  const int l4 = lane & 15, lh = lane >> 4;

  __shared__ u16 Kt[2][64 * 64];
  __shared__ u16 Vt[2][64 * 64];
  __shared__ u16 Pt[4][16 * 64];

  const size_t RS = 3 * D_DIM;
  const u16* base = qkv + (size_t)b * S_LEN * RS + h * HDIM;
  const u16* kbase = base + D_DIM;
  const u16* vtb = vt + (size_t)bh * HDIM * S_LEN;
  char* PtW = (char*)Pt[wid];

  short8 qf[2];
  {
    const u16* qp = base + (size_t)(qt * 64 + wid * 16 + l4) * RS + lh * 8;
    qf[0] = *(const short8*)qp;
    qf[1] = *(const short8*)(qp + 32);
  }

  int koff[4][2];
#pragma unroll
  for (int nb = 0; nb < 4; ++nb)
#pragma unroll
    for (int ks = 0; ks < 2; ++ks) {
      int row = nb * 16 + l4;
      koff[nb][ks] = row * 128 + (((ks * 32 + lh * 8) * 2) ^ ((row & 7) << 4));
    }
  int poff[2];
#pragma unroll
  for (int ks = 0; ks < 2; ++ks)
    poff[ks] = l4 * 128 + (((ks * 64 + lh * 16)) ^ ((l4 & 7) << 4));
  int pwoff[4];
#pragma unroll
  for (int nb = 0; nb < 4; ++nb)
    pwoff[nb] = l4 * 128 + (((lh * 8 + nb * 32)) ^ ((l4 & 7) << 4));

  const float slope2 = exp2f(-0.5f * (float)(h + 1)) * 1.44269504088896f;
  const float scale2 = 0.125f * 1.44269504088896f;
  const int ibase = lh * 4 - (qt * 64 + wid * 16 + l4);
  float bc[4][4];
#pragma unroll
  for (int nb = 0; nb < 4; ++nb)
#pragma unroll
    for (int r = 0; r < 4; ++r)
      bc[nb][r] = slope2 * (float)(ibase + 16 * nb + r);

  float m = -1e30f, l = 0.f;
  f32x4 accO[4];
#pragma unroll
  for (int nd = 0; nd < 4; ++nd) accO[nd] = (f32x4){0.f, 0.f, 0.f, 0.f};

  const int srow = tid >> 3;
  const int sc8 = (tid & 7) * 8;
  const int swo = srow * 128 + ((sc8 * 2) ^ ((srow & 7) << 4));
  short8 kreg[2], vreg[2];
#define STAGE_LOAD(KT)                                                              \
  {                                                                                 \
    kreg[0] = *(const short8*)(kbase + (size_t)((KT)*64 + srow) * RS + sc8);        \
    kreg[1] = *(const short8*)(kbase + (size_t)((KT)*64 + srow + 32) * RS + sc8);   \
    vreg[0] = *(const short8*)(vtb + (size_t)srow * S_LEN + (KT)*64 + sc8);         \
    vreg[1] = *(const short8*)(vtb + (size_t)(srow + 32) * S_LEN + (KT)*64 + sc8);  \
  }
#define STAGE_WRITE(B)                                   \
  {                                                      \
    *(short8*)((char*)Kt[B] + swo) = kreg[0];            \
    *(short8*)((char*)Kt[B] + swo + 4096) = kreg[1];     \
    *(short8*)((char*)Vt[B] + swo) = vreg[0];            \
    *(short8*)((char*)Vt[B] + swo + 4096) = vreg[1];     \
  }

  STAGE_LOAD(31);
  STAGE_WRITE(0);
  __syncthreads();
  int cur = 0;

  for (int kt = 31; kt >= 0; --kt) {
    if (kt > 0) STAGE_LOAD(kt - 1);
    const char* Kc = (const char*)Kt[cur];
    const char* Vc = (const char*)Vt[cur];

    f32x4 sacc[4];
#pragma unroll
    for (int nb = 0; nb < 4; ++nb) sacc[nb] = (f32x4){0.f, 0.f, 0.f, 0.f};
    __builtin_amdgcn_s_setprio(1);
#pragma unroll
    for (int ks = 0; ks < 2; ++ks)
#pragma unroll
      for (int nb = 0; nb < 4; ++nb) {
        short8 kf = *(const short8*)(Kc + koff[nb][ks]);
        sacc[nb] = __builtin_amdgcn_mfma_f32_16x16x32_bf16(kf, qf[ks], sacc[nb], 0, 0, 0);
      }
    __builtin_amdgcn_s_setprio(0);

    float p[4][4];
    const float ktoff = slope2 * (float)(kt * 64);
#pragma unroll
    for (int nb = 0; nb < 4; ++nb)
#pragma unroll
      for (int r = 0; r < 4; ++r)
        p[nb][r] = fmaf(sacc[nb][r], scale2, bc[nb][r] + ktoff);

    float mx0 = fmaxf(fmaxf(p[0][0], p[0][1]), fmaxf(p[0][2], p[0][3]));
    float mx1 = fmaxf(fmaxf(p[1][0], p[1][1]), fmaxf(p[1][2], p[1][3]));
    float mx2 = fmaxf(fmaxf(p[2][0], p[2][1]), fmaxf(p[2][2], p[2][3]));
    float mx3 = fmaxf(fmaxf(p[3][0], p[3][1]), fmaxf(p[3][2], p[3][3]));
    float tm = fmaxf(fmaxf(mx0, mx1), fmaxf(mx2, mx3));
    tm = fmaxf(tm, __shfl_xor(tm, 16));
    tm = fmaxf(tm, __shfl_xor(tm, 32));

    if (__any(tm > m)) {
      float mn = fmaxf(m, tm);
      float corr = exp2f(m - mn);
      m = mn;
      l *= corr;
      float cb[4];
#pragma unroll
      for (int r = 0; r < 4; ++r)
        cb[r] = __shfl(corr, (lane & 48) | (lh * 4 + r));
#pragma unroll
      for (int nd = 0; nd < 4; ++nd)
#pragma unroll
        for (int r = 0; r < 4; ++r) accO[nd][r] *= cb[r];
    }

#pragma unroll
    for (int nb = 0; nb < 4; ++nb)
#pragma unroll
      for (int r = 0; r < 4; ++r) p[nb][r] = exp2f(p[nb][r] - m);

    float s0 = (p[0][0] + p[0][1]) + (p[0][2] + p[0][3]);
    float s1 = (p[1][0] + p[1][1]) + (p[1][2] + p[1][3]);
    float s2 = (p[2][0] + p[2][1]) + (p[2][2] + p[2][3]);
    float s3 = (p[3][0] + p[3][1]) + (p[3][2] + p[3][3]);
    float rs = (s0 + s1) + (s2 + s3);
    rs += __shfl_xor(rs, 16);
    rs += __shfl_xor(rs, 32);
    l += rs;

#pragma unroll
    for (int nb = 0; nb < 4; ++nb) {
      uint32_t w0 = pack_bf2(p[nb][0], p[nb][1]);
      uint32_t w1 = pack_bf2(p[nb][2], p[nb][3]);
      *(uint2*)(PtW + pwoff[nb]) = make_uint2(w0, w1);
    }
    asm volatile("s_waitcnt lgkmcnt(0)" ::: "memory");

    __builtin_amdgcn_s_setprio(1);
#pragma unroll
    for (int ks = 0; ks < 2; ++ks) {
      short8 pf = *(const short8*)(PtW + poff[ks]);
#pragma unroll
      for (int nd = 0; nd < 4; ++nd) {
        short8 vf = *(const short8*)(Vc + koff[nd][ks]);
        accO[nd] = __builtin_amdgcn_mfma_f32_16x16x32_bf16(pf, vf, accO[nd], 0, 0, 0);
      }
    }
    __builtin_amdgcn_s_setprio(0);

    if (kt > 0) STAGE_WRITE(cur ^ 1);
    __syncthreads();
    cur ^= 1;
  }

  float rinv = 1.0f / l;
  float ib[4];
#pragma unroll
  for (int r = 0; r < 4; ++r)
    ib[r] = __shfl(rinv, (lane & 48) | (lh * 4 + r));
  u16* aop = ao + ((size_t)(b * S_LEN + qt * 64 + wid * 16 + lh * 4)) * D_DIM + h * HDIM;
#pragma unroll
  for (int nd = 0; nd < 4; ++nd)
#pragma unroll
    for (int r = 0; r < 4; ++r)
      aop[(size_t)r * D_DIM + nd * 16 + l4] = f2bf(accO[nd][r] * ib[r]);
#undef STAGE_LOAD
#undef STAGE_WRITE
}

extern "C" void kernel_launch(void* const* d_in, const int* in_sizes, int n_in,
                              void* d_out, int out_size, void* d_ws, size_t ws_size,
                              hipStream_t stream) {
  const float* x   = (const float*)d_in[0];
  const float* Wq  = (const float*)d_in[1];
  const float* Wk  = (const float*)d_in[2];
  const float* Wv  = (const float*)d_in[3];
  const float* Wo  = (const float*)d_in[4];
  const float* bo  = (const float*)d_in[5];
  const float* W1  = (const float*)d_in[6];
  const float* b1  = (const float*)d_in[7];
  const float* W2  = (const float*)d_in[8];
  const float* b2  = (const float*)d_in[9];
  const float* g1  = (const float*)d_in[10];
  const float* be1 = (const float*)d_in[11];
  const float* g2  = (const float*)d_in[12];
  const float* be2 = (const float*)d_in[13];

  char* p = (char*)d_ws;
  u16* wqkv = (u16*)p; p += (size_t)3072 * 1024 * 2;
  u16* wo   = (u16*)p; p += (size_t)1024 * 1024 * 2;
  u16* w1   = (u16*)p; p += (size_t)4096 * 1024 * 2;
  u16* w2   = (u16*)p; p += (size_t)4096 * 1024 * 2;
  u16* hb   = (u16*)p; p += (size_t)4096 * 1024 * 2;
  u16* qkvb = (u16*)p; p += (size_t)4096 * 3072 * 2;
  u16* aob  = (u16*)p; p += (size_t)4096 * 1024 * 2;
  float* x1 = (float*)p; p += (size_t)4096 * 1024 * 4;
  u16* h2b  = (u16*)p; p += (size_t)4096 * 1024 * 2;
  u16* ff1  = (u16*)p; p += (size_t)4096 * 4096 * 2;
  u16* vt   = ff1;            // alias: vt dead before ff1 written
  float* pk = (float*)hb;     // alias: hb+qkvb (32MB) dead before FFN2;
                              // holds 2 split-K partials (2 x 16MB f32)

  cast_kernel<<<1024, 256, 0, stream>>>(Wq, wqkv, 262144);
  cast_kernel<<<1024, 256, 0, stream>>>(Wk, wqkv + 1024 * 1024, 262144);
  cast_kernel<<<1024, 256, 0, stream>>>(Wv, wqkv + 2 * 1024 * 1024, 262144);
  cast_kernel<<<1024, 256, 0, stream>>>(Wo, wo, 262144);
  cast_kernel<<<4096, 256, 0, stream>>>(W1, w1, 1048576);
  cast_kernel<<<4096, 256, 0, stream>>>(W2, w2, 1048576);

  ln_kernel<<<4096, 256, 0, stream>>>(x, g1, be1, hb);
  gemm_bt<0><<<32 * 24, 256, 0, stream>>>(hb, wqkv, qkvb, nullptr, nullptr, 4096, 3072, 1024, 1);
  transpose_v<<<256, 256, 0, stream>>>(qkvb, vt);
  attn_kernel<<<1024, 256, 0, stream>>>(qkvb, vt, aob);
  gemm_bt<1><<<32 * 8, 256, 0, stream>>>(aob, wo, x1, bo, x, 4096, 1024, 1024, 1);
  ln_kernel<<<4096, 256, 0, stream>>>(x1, g2, be2, h2b);
  gemm_bt<2><<<32 * 32, 256, 0, stream>>>(h2b, w1, ff1, b1, nullptr, 4096, 4096, 1024, 1);
  // FFN2 split-K=2: partials then fused reduce (+bias +residual)
  gemm_bt<3><<<2 * 32 * 8, 256, 0, stream>>>(ff1, w2, pk, nullptr, nullptr, 4096, 1024, 4096, 2);
  reduce2_kernel<<<2048, 256, 0, stream>>>(pk, pk + (size_t)4096 * 1024, x1, b2, (float*)d_out);
}

// Round 6
// 290.970 us; speedup vs baseline: 1.4389x; 1.0684x over previous
//
#include <hip/hip_runtime.h>
#include <hip/hip_bf16.h>
#include <stdint.h>

typedef unsigned short u16;
typedef __attribute__((ext_vector_type(8))) short short8;
typedef __attribute__((ext_vector_type(4))) float f32x4;

#define S_LEN 2048
#define D_DIM 1024
#define NHEAD 16
#define HDIM 64
#define NROWS 4096

__device__ __forceinline__ u16 f2bf(float f) {
  union { float f; uint32_t u; } c; c.f = f;
  uint32_t r = (c.u + 0x7fffu + ((c.u >> 16) & 1u)) >> 16;
  return (u16)r;
}

__device__ __forceinline__ uint32_t pack_bf2(float a, float b) {
  __hip_bfloat162 h = __float22bfloat162_rn(float2{a, b});
  union { __hip_bfloat162 h; uint32_t u; } c; c.h = h;
  return c.u;
}

__device__ __forceinline__ void gload_lds16(const void* g, void* l) {
  typedef const __attribute__((address_space(1))) unsigned int gq_t;
  typedef __attribute__((address_space(3))) unsigned int lq_t;
  __builtin_amdgcn_global_load_lds((gq_t*)(uintptr_t)g,
                                   (lq_t*)(uint32_t)(uintptr_t)l, 16, 0, 0);
}

// ---------------- fp32 -> bf16 cast ----------------
__global__ __launch_bounds__(256) void cast_kernel(const float* __restrict__ src,
                                                   u16* __restrict__ dst, int n4) {
  int i = blockIdx.x * 256 + threadIdx.x;
  if (i >= n4) return;
  float4 v = ((const float4*)src)[i];
  ushort4 o = make_ushort4(f2bf(v.x), f2bf(v.y), f2bf(v.z), f2bf(v.w));
  ((ushort4*)dst)[i] = o;
}

// ---------------- LayerNorm fp32 -> bf16 ----------------
__global__ __launch_bounds__(256) void ln_kernel(const float* __restrict__ x,
                                                 const float* __restrict__ g,
                                                 const float* __restrict__ be,
                                                 u16* __restrict__ out) {
  int row = blockIdx.x;
  int tid = threadIdx.x;
  const float4 v = ((const float4*)(x + (size_t)row * D_DIM))[tid];
  float s = v.x + v.y + v.z + v.w;
  float s2 = v.x * v.x + v.y * v.y + v.z * v.z + v.w * v.w;
#pragma unroll
  for (int off = 1; off < 64; off <<= 1) {
    s += __shfl_xor(s, off);
    s2 += __shfl_xor(s2, off);
  }
  __shared__ float ss[4], ss2[4];
  if ((tid & 63) == 0) { ss[tid >> 6] = s; ss2[tid >> 6] = s2; }
  __syncthreads();
  s = ss[0] + ss[1] + ss[2] + ss[3];
  s2 = ss2[0] + ss2[1] + ss2[2] + ss2[3];
  float mu = s * (1.0f / D_DIM);
  float var = s2 * (1.0f / D_DIM) - mu * mu;
  float rs = rsqrtf(var + 1e-5f);
  float4 gv = ((const float4*)g)[tid];
  float4 bv = ((const float4*)be)[tid];
  ushort4 o = make_ushort4(f2bf((v.x - mu) * rs * gv.x + bv.x),
                           f2bf((v.y - mu) * rs * gv.y + bv.y),
                           f2bf((v.z - mu) * rs * gv.z + bv.z),
                           f2bf((v.w - mu) * rs * gv.w + bv.w));
  ((ushort4*)(out + (size_t)row * D_DIM))[tid] = o;
}

// ---------------- NT GEMM: C[M,N] = A[M,K] * B[N,K]^T (bf16 in, MFMA) -------
// EPI 0: bf16 out. EPI 1: f32 out = acc + bias[col] + resid. EPI 2: bf16 relu.
// EPI 3: f32 partial acc (split-K slice -> Cout + slice*M*N).
template <int EPI>
__global__ __launch_bounds__(256) void gemm_bt(const u16* __restrict__ A,
                                               const u16* __restrict__ Bw,
                                               void* __restrict__ Cout,
                                               const float* __restrict__ bias,
                                               const float* __restrict__ resid,
                                               int M, int N, int K, int ksl) {
  __shared__ u16 lsA[128 * 64];
  __shared__ u16 lsB[128 * 64];
  const int tid = threadIdx.x;
  const int wid = tid >> 6, lane = tid & 63;
  const int l4 = lane & 15, lh = lane >> 4;
  const int nbn = N >> 7;
  const int nwgs = (M >> 7) * nbn;
  const int slice = blockIdx.x / nwgs;
  const int id0 = blockIdx.x % nwgs;
  // XCD-chunk swizzle (T1)
  const int t = (id0 & 7) * (nwgs >> 3) + (id0 >> 3);
  const int bm = t / nbn, bn = t % nbn;
  const int wr = wid >> 1, wc = wid & 1;
  const int Ks = K / ksl;

  f32x4 acc[4][4];
#pragma unroll
  for (int i = 0; i < 4; ++i)
#pragma unroll
    for (int j = 0; j < 4; ++j) acc[i][j] = (f32x4){0.f, 0.f, 0.f, 0.f};

  const u16* Ab = A + (size_t)bm * 128 * K + (size_t)slice * Ks;
  const u16* Bb = Bw + (size_t)bn * 128 * K + (size_t)slice * Ks;
  const int srow = (lane >> 3);
  const int scol = (lane & 7) * 8;

  for (int k0 = 0; k0 < Ks; k0 += 64) {
#pragma unroll
    for (int c = 0; c < 4; ++c) {
      int ch = wid * 4 + c;
      int row = ch * 8 + srow;
      gload_lds16(Ab + (size_t)row * K + k0 + scol, &lsA[ch * 512]);
      gload_lds16(Bb + (size_t)row * K + k0 + scol, &lsB[ch * 512]);
    }
    __syncthreads();
#pragma unroll
    for (int ks = 0; ks < 2; ++ks) {
      short8 af[4], bf[4];
#pragma unroll
      for (int i = 0; i < 4; ++i) {
        af[i] = *(const short8*)&lsA[(wr * 64 + i * 16 + l4) * 64 + ks * 32 + lh * 8];
        bf[i] = *(const short8*)&lsB[(wc * 64 + i * 16 + l4) * 64 + ks * 32 + lh * 8];
      }
#pragma unroll
      for (int i = 0; i < 4; ++i)
#pragma unroll
        for (int j = 0; j < 4; ++j)
          acc[i][j] = __builtin_amdgcn_mfma_f32_16x16x32_bf16(af[i], bf[j], acc[i][j], 0, 0, 0);
    }
    __syncthreads();
  }

  const int row0 = bm * 128 + wr * 64;
  const int col0 = bn * 128 + wc * 64;
  float* Cp = (float*)Cout + (size_t)slice * M * N;
#pragma unroll
  for (int i = 0; i < 4; ++i) {
#pragma unroll
    for (int j = 0; j < 4; ++j) {
      int col = col0 + j * 16 + l4;
#pragma unroll
      for (int r = 0; r < 4; ++r) {
        int row = row0 + i * 16 + lh * 4 + r;
        size_t idx = (size_t)row * N + col;
        float v = acc[i][j][r];
        if (EPI == 0) {
          ((u16*)Cout)[idx] = f2bf(v);
        } else if (EPI == 1) {
          ((float*)Cout)[idx] = v + bias[col] + resid[idx];
        } else if (EPI == 2) {
          v += bias[col];
          ((u16*)Cout)[idx] = f2bf(v > 0.f ? v : 0.f);
        } else {
          Cp[idx] = v;
        }
      }
    }
  }
}

// ---------------- split-K reduce: out = p0 + p1 + bias + resid ----------------
__global__ __launch_bounds__(256) void reduce2_kernel(const float* __restrict__ p0,
                                                      const float* __restrict__ p1,
                                                      const float* __restrict__ resid,
                                                      const float* __restrict__ bias,
                                                      float* __restrict__ out) {
  for (int i = blockIdx.x * 256 + threadIdx.x; i < (NROWS * D_DIM) / 4;
       i += gridDim.x * 256) {
    float4 a = ((const float4*)p0)[i];
    float4 b = ((const float4*)p1)[i];
    float4 r = ((const float4*)resid)[i];
    float4 bb = ((const float4*)bias)[i & 255];
    float4 o;
    o.x = a.x + b.x + r.x + bb.x;
    o.y = a.y + b.y + r.y + bb.y;
    o.z = a.z + b.z + r.z + bb.z;
    o.w = a.w + b.w + r.w + bb.w;
    ((float4*)out)[i] = o;
  }
}

// ---------------- V transpose: qkv V-region -> vt[b,h,d,s] ----------------
__global__ __launch_bounds__(256) void transpose_v(const u16* __restrict__ qkv,
                                                   u16* __restrict__ vt) {
  const int gw = blockIdx.x * 4 + (threadIdx.x >> 6);
  const int lane = threadIdx.x & 63;
  const int bh = gw >> 5;
  const int st = gw & 31;
  const int b = bh >> 4, h = bh & 15;
  const u16* src = qkv + (size_t)(b * S_LEN + st * 64) * 3072 + 2048 + h * 64 + lane;
  short8 acc8[8];
#pragma unroll
  for (int o = 0; o < 8; ++o)
#pragma unroll
    for (int i = 0; i < 8; ++i)
      acc8[o][i] = (short)src[(size_t)(o * 8 + i) * 3072];
  u16* dst = vt + ((size_t)bh * 64 + lane) * S_LEN + st * 64;
#pragma unroll
  for (int o = 0; o < 8; ++o) *(short8*)(dst + o * 8) = acc8[o];
}

// ---------------- Flash attention with ALiBi (swapped-S, tile-skip) --------
// Non-causal ALiBi: bias slope*(j-i) is maximal at j=S-1 for every i, so only
// the top nt(h) key-tiles contribute (dropped keys' weight <= 2^-33 of max).
__global__ __launch_bounds__(256, 4) void attn_kernel(const u16* __restrict__ qkv,
                                                      const u16* __restrict__ vt,
                                                      u16* __restrict__ ao) {
  // balanced XCD mapping: XCD x hosts heads {x, 15-x} (both batches)
  const int id = blockIdx.x;
  const int xcd = id & 7, slot = id >> 3;
  const int u = slot >> 5;      // 0..3
  const int qt = slot & 31;
  const int h = (u >> 1) ? (15 - xcd) : xcd;
  const int b = u & 1;
  const int bh = b * 16 + h;
  const int tid = threadIdx.x;
  const int wid = tid >> 6, lane = tid & 63;
  const int l4 = lane & 15, lh = lane >> 4;

  __shared__ u16 Kt[2][64 * 64];
  __shared__ u16 Vt[2][64 * 64];
  __shared__ u16 Pt[4][16 * 64];

  const size_t RS = 3 * D_DIM;
  const u16* base = qkv + (size_t)b * S_LEN * RS + h * HDIM;
  const u16* kbase = base + D_DIM;
  const u16* vtb = vt + (size_t)bh * HDIM * S_LEN;
  char* PtW = (char*)Pt[wid];

  short8 qf[2];
  {
    const u16* qp = base + (size_t)(qt * 64 + wid * 16 + l4) * RS + lh * 8;
    qf[0] = *(const short8*)qp;
    qf[1] = *(const short8*)(qp + 32);
  }

  int koff[4][2];
#pragma unroll
  for (int nb = 0; nb < 4; ++nb)
#pragma unroll
    for (int ks = 0; ks < 2; ++ks) {
      int row = nb * 16 + l4;
      koff[nb][ks] = row * 128 + (((ks * 32 + lh * 8) * 2) ^ ((row & 7) << 4));
    }
  int poff[2];
#pragma unroll
  for (int ks = 0; ks < 2; ++ks)
    poff[ks] = l4 * 128 + (((ks * 64 + lh * 16)) ^ ((l4 & 7) << 4));
  int pwoff[4];
#pragma unroll
  for (int nb = 0; nb < 4; ++nb)
    pwoff[nb] = l4 * 128 + (((lh * 8 + nb * 32)) ^ ((l4 & 7) << 4));

  const float slope2 = exp2f(-0.5f * (float)(h + 1)) * 1.44269504088896f;
  const float scale2 = 0.125f * 1.44269504088896f;
  const int ibase = lh * 4 - (qt * 64 + wid * 16 + l4);
  float bc[4][4];
#pragma unroll
  for (int nb = 0; nb < 4; ++nb)
#pragma unroll
    for (int r = 0; r < 4; ++r)
      bc[nb][r] = slope2 * (float)(ibase + 16 * nb + r);

  // ALiBi tile-skip: keep top nt tiles; dropped-key deficit >= 35 log2 units
  int nt = (int)ceilf(40.0f / (64.0f * slope2)) + 1;
  if (nt > 32) nt = 32;
  const int ktmin = 32 - nt;

  float m = -1e30f, l = 0.f;
  f32x4 accO[4];
#pragma unroll
  for (int nd = 0; nd < 4; ++nd) accO[nd] = (f32x4){0.f, 0.f, 0.f, 0.f};

  const int srow = tid >> 3;
  const int sc8 = (tid & 7) * 8;
  const int swo = srow * 128 + ((sc8 * 2) ^ ((srow & 7) << 4));
  short8 kreg[2], vreg[2];
#define STAGE_LOAD(KT)                                                              \
  {                                                                                 \
    kreg[0] = *(const short8*)(kbase + (size_t)((KT)*64 + srow) * RS + sc8);        \
    kreg[1] = *(const short8*)(kbase + (size_t)((KT)*64 + srow + 32) * RS + sc8);   \
    vreg[0] = *(const short8*)(vtb + (size_t)srow * S_LEN + (KT)*64 + sc8);         \
    vreg[1] = *(const short8*)(vtb + (size_t)(srow + 32) * S_LEN + (KT)*64 + sc8);  \
  }
#define STAGE_WRITE(B)                                   \
  {                                                      \
    *(short8*)((char*)Kt[B] + swo) = kreg[0];            \
    *(short8*)((char*)Kt[B] + swo + 4096) = kreg[1];     \
    *(short8*)((char*)Vt[B] + swo) = vreg[0];            \
    *(short8*)((char*)Vt[B] + swo + 4096) = vreg[1];     \
  }

  STAGE_LOAD(31);
  STAGE_WRITE(0);
  __syncthreads();
  int cur = 0;

  for (int kt = 31; kt >= ktmin; --kt) {
    if (kt > ktmin) STAGE_LOAD(kt - 1);
    const char* Kc = (const char*)Kt[cur];
    const char* Vc = (const char*)Vt[cur];

    f32x4 sacc[4];
#pragma unroll
    for (int nb = 0; nb < 4; ++nb) sacc[nb] = (f32x4){0.f, 0.f, 0.f, 0.f};
    __builtin_amdgcn_s_setprio(1);
#pragma unroll
    for (int ks = 0; ks < 2; ++ks)
#pragma unroll
      for (int nb = 0; nb < 4; ++nb) {
        short8 kf = *(const short8*)(Kc + koff[nb][ks]);
        sacc[nb] = __builtin_amdgcn_mfma_f32_16x16x32_bf16(kf, qf[ks], sacc[nb], 0, 0, 0);
      }
    __builtin_amdgcn_s_setprio(0);

    float p[4][4];
    const float ktoff = slope2 * (float)(kt * 64);
#pragma unroll
    for (int nb = 0; nb < 4; ++nb)
#pragma unroll
      for (int r = 0; r < 4; ++r)
        p[nb][r] = fmaf(sacc[nb][r], scale2, bc[nb][r] + ktoff);

    float mx0 = fmaxf(fmaxf(p[0][0], p[0][1]), fmaxf(p[0][2], p[0][3]));
    float mx1 = fmaxf(fmaxf(p[1][0], p[1][1]), fmaxf(p[1][2], p[1][3]));
    float mx2 = fmaxf(fmaxf(p[2][0], p[2][1]), fmaxf(p[2][2], p[2][3]));
    float mx3 = fmaxf(fmaxf(p[3][0], p[3][1]), fmaxf(p[3][2], p[3][3]));
    float tm = fmaxf(fmaxf(mx0, mx1), fmaxf(mx2, mx3));
    tm = fmaxf(tm, __shfl_xor(tm, 16));
    tm = fmaxf(tm, __shfl_xor(tm, 32));

    if (__any(tm > m)) {
      float mn = fmaxf(m, tm);
      float corr = exp2f(m - mn);
      m = mn;
      l *= corr;
      float cb[4];
#pragma unroll
      for (int r = 0; r < 4; ++r)
        cb[r] = __shfl(corr, (lane & 48) | (lh * 4 + r));
#pragma unroll
      for (int nd = 0; nd < 4; ++nd)
#pragma unroll
        for (int r = 0; r < 4; ++r) accO[nd][r] *= cb[r];
    }

#pragma unroll
    for (int nb = 0; nb < 4; ++nb)
#pragma unroll
      for (int r = 0; r < 4; ++r) p[nb][r] = exp2f(p[nb][r] - m);

    float s0 = (p[0][0] + p[0][1]) + (p[0][2] + p[0][3]);
    float s1 = (p[1][0] + p[1][1]) + (p[1][2] + p[1][3]);
    float s2 = (p[2][0] + p[2][1]) + (p[2][2] + p[2][3]);
    float s3 = (p[3][0] + p[3][1]) + (p[3][2] + p[3][3]);
    float rs = (s0 + s1) + (s2 + s3);
    rs += __shfl_xor(rs, 16);
    rs += __shfl_xor(rs, 32);
    l += rs;

#pragma unroll
    for (int nb = 0; nb < 4; ++nb) {
      uint32_t w0 = pack_bf2(p[nb][0], p[nb][1]);
      uint32_t w1 = pack_bf2(p[nb][2], p[nb][3]);
      *(uint2*)(PtW + pwoff[nb]) = make_uint2(w0, w1);
    }
    asm volatile("s_waitcnt lgkmcnt(0)" ::: "memory");

    __builtin_amdgcn_s_setprio(1);
#pragma unroll
    for (int ks = 0; ks < 2; ++ks) {
      short8 pf = *(const short8*)(PtW + poff[ks]);
#pragma unroll
      for (int nd = 0; nd < 4; ++nd) {
        short8 vf = *(const short8*)(Vc + koff[nd][ks]);
        accO[nd] = __builtin_amdgcn_mfma_f32_16x16x32_bf16(pf, vf, accO[nd], 0, 0, 0);
      }
    }
    __builtin_amdgcn_s_setprio(0);

    if (kt > ktmin) STAGE_WRITE(cur ^ 1);
    __syncthreads();
    cur ^= 1;
  }

  float rinv = 1.0f / l;
  float ib[4];
#pragma unroll
  for (int r = 0; r < 4; ++r)
    ib[r] = __shfl(rinv, (lane & 48) | (lh * 4 + r));
  u16* aop = ao + ((size_t)(b * S_LEN + qt * 64 + wid * 16 + lh * 4)) * D_DIM + h * HDIM;
#pragma unroll
  for (int nd = 0; nd < 4; ++nd)
#pragma unroll
    for (int r = 0; r < 4; ++r)
      aop[(size_t)r * D_DIM + nd * 16 + l4] = f2bf(accO[nd][r] * ib[r]);
#undef STAGE_LOAD
#undef STAGE_WRITE
}

extern "C" void kernel_launch(void* const* d_in, const int* in_sizes, int n_in,
                              void* d_out, int out_size, void* d_ws, size_t ws_size,
                              hipStream_t stream) {
  const float* x   = (const float*)d_in[0];
  const float* Wq  = (const float*)d_in[1];
  const float* Wk  = (const float*)d_in[2];
  const float* Wv  = (const float*)d_in[3];
  const float* Wo  = (const float*)d_in[4];
  const float* bo  = (const float*)d_in[5];
  const float* W1  = (const float*)d_in[6];
  const float* b1  = (const float*)d_in[7];
  const float* W2  = (const float*)d_in[8];
  const float* b2  = (const float*)d_in[9];
  const float* g1  = (const float*)d_in[10];
  const float* be1 = (const float*)d_in[11];
  const float* g2  = (const float*)d_in[12];
  const float* be2 = (const float*)d_in[13];

  char* p = (char*)d_ws;
  u16* wqkv = (u16*)p; p += (size_t)3072 * 1024 * 2;
  u16* wo   = (u16*)p; p += (size_t)1024 * 1024 * 2;
  u16* w1   = (u16*)p; p += (size_t)4096 * 1024 * 2;
  u16* w2   = (u16*)p; p += (size_t)4096 * 1024 * 2;
  u16* hb   = (u16*)p; p += (size_t)4096 * 1024 * 2;
  u16* qkvb = (u16*)p; p += (size_t)4096 * 3072 * 2;
  u16* aob  = (u16*)p; p += (size_t)4096 * 1024 * 2;
  float* x1 = (float*)p; p += (size_t)4096 * 1024 * 4;
  u16* h2b  = (u16*)p; p += (size_t)4096 * 1024 * 2;
  u16* ff1  = (u16*)p; p += (size_t)4096 * 4096 * 2;
  u16* vt   = ff1;            // alias: vt dead before ff1 written
  float* pk = (float*)hb;     // alias: hb+qkvb dead before FFN2

  cast_kernel<<<1024, 256, 0, stream>>>(Wq, wqkv, 262144);
  cast_kernel<<<1024, 256, 0, stream>>>(Wk, wqkv + 1024 * 1024, 262144);
  cast_kernel<<<1024, 256, 0, stream>>>(Wv, wqkv + 2 * 1024 * 1024, 262144);
  cast_kernel<<<1024, 256, 0, stream>>>(Wo, wo, 262144);
  cast_kernel<<<4096, 256, 0, stream>>>(W1, w1, 1048576);
  cast_kernel<<<4096, 256, 0, stream>>>(W2, w2, 1048576);

  ln_kernel<<<4096, 256, 0, stream>>>(x, g1, be1, hb);
  gemm_bt<0><<<32 * 24, 256, 0, stream>>>(hb, wqkv, qkvb, nullptr, nullptr, 4096, 3072, 1024, 1);
  transpose_v<<<256, 256, 0, stream>>>(qkvb, vt);
  attn_kernel<<<1024, 256, 0, stream>>>(qkvb, vt, aob);
  gemm_bt<1><<<32 * 8, 256, 0, stream>>>(aob, wo, x1, bo, x, 4096, 1024, 1024, 1);
  ln_kernel<<<4096, 256, 0, stream>>>(x1, g2, be2, h2b);
  gemm_bt<2><<<32 * 32, 256, 0, stream>>>(h2b, w1, ff1, b1, nullptr, 4096, 4096, 1024, 1);
  gemm_bt<3><<<2 * 32 * 8, 256, 0, stream>>>(ff1, w2, pk, nullptr, nullptr, 4096, 1024, 4096, 2);
  reduce2_kernel<<<2048, 256, 0, stream>>>(pk, pk + (size_t)4096 * 1024, x1, b2, (float*)d_out);
}

// Round 7
// 250.803 us; speedup vs baseline: 1.6694x; 1.1602x over previous
//
#include <hip/hip_runtime.h>
#include <hip/hip_bf16.h>
#include <stdint.h>

typedef unsigned short u16;
typedef __attribute__((ext_vector_type(8))) short short8;
typedef __attribute__((ext_vector_type(4))) float f32x4;

#define S_LEN 2048
#define D_DIM 1024
#define NHEAD 16
#define HDIM 64
#define NROWS 4096

__device__ __forceinline__ u16 f2bf(float f) {
  union { float f; uint32_t u; } c; c.f = f;
  uint32_t r = (c.u + 0x7fffu + ((c.u >> 16) & 1u)) >> 16;
  return (u16)r;
}

__device__ __forceinline__ uint32_t pack_bf2(float a, float b) {
  __hip_bfloat162 h = __float22bfloat162_rn(float2{a, b});
  union { __hip_bfloat162 h; uint32_t u; } c; c.h = h;
  return c.u;
}

__device__ __forceinline__ void gload_lds16(const void* g, void* l) {
  typedef const __attribute__((address_space(1))) unsigned int gq_t;
  typedef __attribute__((address_space(3))) unsigned int lq_t;
  __builtin_amdgcn_global_load_lds((gq_t*)(uintptr_t)g,
                                   (lq_t*)(uint32_t)(uintptr_t)l, 16, 0, 0);
}

// ---------------- fp32 -> bf16 cast ----------------
__global__ __launch_bounds__(256) void cast_kernel(const float* __restrict__ src,
                                                   u16* __restrict__ dst, int n4) {
  int i = blockIdx.x * 256 + threadIdx.x;
  if (i >= n4) return;
  float4 v = ((const float4*)src)[i];
  ushort4 o = make_ushort4(f2bf(v.x), f2bf(v.y), f2bf(v.z), f2bf(v.w));
  ((ushort4*)dst)[i] = o;
}

// ---------------- LayerNorm fp32 -> bf16 ----------------
__global__ __launch_bounds__(256) void ln_kernel(const float* __restrict__ x,
                                                 const float* __restrict__ g,
                                                 const float* __restrict__ be,
                                                 u16* __restrict__ out) {
  int row = blockIdx.x;
  int tid = threadIdx.x;
  const float4 v = ((const float4*)(x + (size_t)row * D_DIM))[tid];
  float s = v.x + v.y + v.z + v.w;
  float s2 = v.x * v.x + v.y * v.y + v.z * v.z + v.w * v.w;
#pragma unroll
  for (int off = 1; off < 64; off <<= 1) {
    s += __shfl_xor(s, off);
    s2 += __shfl_xor(s2, off);
  }
  __shared__ float ss[4], ss2[4];
  if ((tid & 63) == 0) { ss[tid >> 6] = s; ss2[tid >> 6] = s2; }
  __syncthreads();
  s = ss[0] + ss[1] + ss[2] + ss[3];
  s2 = ss2[0] + ss2[1] + ss2[2] + ss2[3];
  float mu = s * (1.0f / D_DIM);
  float var = s2 * (1.0f / D_DIM) - mu * mu;
  float rs = rsqrtf(var + 1e-5f);
  float4 gv = ((const float4*)g)[tid];
  float4 bv = ((const float4*)be)[tid];
  ushort4 o = make_ushort4(f2bf((v.x - mu) * rs * gv.x + bv.x),
                           f2bf((v.y - mu) * rs * gv.y + bv.y),
                           f2bf((v.z - mu) * rs * gv.z + bv.z),
                           f2bf((v.w - mu) * rs * gv.w + bv.w));
  ((ushort4*)(out + (size_t)row * D_DIM))[tid] = o;
}

// ====== 256x256 BK=32 deep-pipe NT GEMM: C = A[M,K] * B[N,K]^T ======
// 8 waves (2Mx4N), per-wave 128x64 out. LDS 64KB double-buffered.
// Bank-swizzle: LDS[row][blk] holds G[row][blk ^ ((row>>1)&3)] (16B blks),
// applied via pre-swizzled global source + swizzled read (rule #21).
// Prefetch tile t+1 into other buffer at top of tile t; single barrier/tile
// (compiler's pre-barrier vmcnt(0) drains loads issued a full tile earlier).
// EPI 0: bf16 out. EPI 2: bf16 relu(acc + bias[col]).
template <int EPI>
__global__ __launch_bounds__(512, 2) void gemm_bt2(const u16* __restrict__ A,
                                                   const u16* __restrict__ Bw,
                                                   void* __restrict__ Cout,
                                                   const float* __restrict__ bias,
                                                   int M, int N, int K) {
  __shared__ u16 lsA[2][256 * 32];
  __shared__ u16 lsB[2][256 * 32];
  const int tid = threadIdx.x;
  const int wid = tid >> 6, lane = tid & 63;
  const int l4 = lane & 15, lh = lane >> 4;
  const int wr = wid >> 2, wc = wid & 3;
  const int nbn = N >> 8;
  const int nwg = (M >> 8) * nbn;
  // XCD-chunk swizzle (T1), nwg % 8 == 0
  const int t0 = (blockIdx.x & 7) * (nwg >> 3) + (blockIdx.x >> 3);
  const int bm = t0 / nbn, bn = t0 % nbn;

  f32x4 acc[8][4];
#pragma unroll
  for (int i = 0; i < 8; ++i)
#pragma unroll
    for (int j = 0; j < 4; ++j) acc[i][j] = (f32x4){0.f, 0.f, 0.f, 0.f};

  // staging: wave w stages chunks {2w,2w+1} of A and B (1KB each = 16 rows)
  const int srow = lane >> 2;                       // row within chunk
  const int sblk = (lane & 3) ^ ((lane >> 3) & 3);  // pre-swizzled source blk
  const u16* Abase = A + ((size_t)bm * 256 + wid * 32 + srow) * K + sblk * 8;
  const u16* Bbase = Bw + ((size_t)bn * 256 + wid * 32 + srow) * K + sblk * 8;
  const size_t r16 = (size_t)16 * K;  // 16-row stride
#define STAGE(BUF, KT)                                              \
  {                                                                 \
    int ko = (KT) * 32;                                             \
    gload_lds16(Abase + ko, (char*)lsA[BUF] + wid * 2048);          \
    gload_lds16(Abase + r16 + ko, (char*)lsA[BUF] + wid * 2048 + 1024); \
    gload_lds16(Bbase + ko, (char*)lsB[BUF] + wid * 2048);          \
    gload_lds16(Bbase + r16 + ko, (char*)lsB[BUF] + wid * 2048 + 1024); \
  }

  // hoisted read offsets; swizzle term (lh ^ ((l4>>1)&3)) is lane-constant
  const int swz = (lh ^ ((l4 >> 1) & 3)) << 4;
  int aoff[8], boff[4];
#pragma unroll
  for (int m = 0; m < 8; ++m) aoff[m] = (wr * 128 + m * 16 + l4) * 64 + swz;
#pragma unroll
  for (int n = 0; n < 4; ++n) boff[n] = (wc * 64 + n * 16 + l4) * 64 + swz;

  STAGE(0, 0);
  __syncthreads();
  int cur = 0;
  const int NT = K >> 5;

  for (int t = 0; t < NT; ++t) {
    if (t + 1 < NT) STAGE(cur ^ 1, t + 1);  // prefetch into other buffer
    const char* La = (const char*)lsA[cur];
    const char* Lb = (const char*)lsB[cur];
    short8 aF[4], bF[4], aG[4];
#pragma unroll
    for (int m = 0; m < 4; ++m) aF[m] = *(const short8*)(La + aoff[m]);
#pragma unroll
    for (int n = 0; n < 4; ++n) bF[n] = *(const short8*)(Lb + boff[n]);
    __builtin_amdgcn_s_setprio(1);
#pragma unroll
    for (int m = 0; m < 4; ++m)
#pragma unroll
      for (int n = 0; n < 4; ++n)
        acc[m][n] = __builtin_amdgcn_mfma_f32_16x16x32_bf16(aF[m], bF[n], acc[m][n], 0, 0, 0);
    __builtin_amdgcn_s_setprio(0);
#pragma unroll
    for (int m = 0; m < 4; ++m) aG[m] = *(const short8*)(La + aoff[m + 4]);
    __builtin_amdgcn_s_setprio(1);
#pragma unroll
    for (int m = 0; m < 4; ++m)
#pragma unroll
      for (int n = 0; n < 4; ++n)
        acc[m + 4][n] = __builtin_amdgcn_mfma_f32_16x16x32_bf16(aG[m], bF[n], acc[m + 4][n], 0, 0, 0);
    __builtin_amdgcn_s_setprio(0);
    if (t + 1 < NT) __syncthreads();  // drain vmcnt + switch
    cur ^= 1;
  }

  const int row0 = bm * 256 + wr * 128 + lh * 4;
  const int col0 = bn * 256 + wc * 64 + l4;
#pragma unroll
  for (int m = 0; m < 8; ++m) {
#pragma unroll
    for (int n = 0; n < 4; ++n) {
      int col = col0 + n * 16;
#pragma unroll
      for (int r = 0; r < 4; ++r) {
        size_t idx = (size_t)(row0 + m * 16 + r) * N + col;
        float v = acc[m][n][r];
        if (EPI == 0) {
          ((u16*)Cout)[idx] = f2bf(v);
        } else {
          v += bias[col];
          ((u16*)Cout)[idx] = f2bf(v > 0.f ? v : 0.f);
        }
      }
    }
  }
#undef STAGE
}

// ---------------- 128x128 NT GEMM (kept for O-proj / FFN2 split-K) ----------
// EPI 1: f32 out = acc + bias[col] + resid. EPI 3: f32 partial (split-K).
template <int EPI>
__global__ __launch_bounds__(256) void gemm_bt(const u16* __restrict__ A,
                                               const u16* __restrict__ Bw,
                                               void* __restrict__ Cout,
                                               const float* __restrict__ bias,
                                               const float* __restrict__ resid,
                                               int M, int N, int K, int ksl) {
  __shared__ u16 lsA[128 * 64];
  __shared__ u16 lsB[128 * 64];
  const int tid = threadIdx.x;
  const int wid = tid >> 6, lane = tid & 63;
  const int l4 = lane & 15, lh = lane >> 4;
  const int nbn = N >> 7;
  const int nwgs = (M >> 7) * nbn;
  const int slice = blockIdx.x / nwgs;
  const int id0 = blockIdx.x % nwgs;
  const int t = (id0 & 7) * (nwgs >> 3) + (id0 >> 3);
  const int bm = t / nbn, bn = t % nbn;
  const int wr = wid >> 1, wc = wid & 1;
  const int Ks = K / ksl;

  f32x4 acc[4][4];
#pragma unroll
  for (int i = 0; i < 4; ++i)
#pragma unroll
    for (int j = 0; j < 4; ++j) acc[i][j] = (f32x4){0.f, 0.f, 0.f, 0.f};

  const u16* Ab = A + (size_t)bm * 128 * K + (size_t)slice * Ks;
  const u16* Bb = Bw + (size_t)bn * 128 * K + (size_t)slice * Ks;
  const int srow = (lane >> 3);
  const int scol = (lane & 7) * 8;

  for (int k0 = 0; k0 < Ks; k0 += 64) {
#pragma unroll
    for (int c = 0; c < 4; ++c) {
      int ch = wid * 4 + c;
      int row = ch * 8 + srow;
      gload_lds16(Ab + (size_t)row * K + k0 + scol, &lsA[ch * 512]);
      gload_lds16(Bb + (size_t)row * K + k0 + scol, &lsB[ch * 512]);
    }
    __syncthreads();
#pragma unroll
    for (int ks = 0; ks < 2; ++ks) {
      short8 af[4], bf[4];
#pragma unroll
      for (int i = 0; i < 4; ++i) {
        af[i] = *(const short8*)&lsA[(wr * 64 + i * 16 + l4) * 64 + ks * 32 + lh * 8];
        bf[i] = *(const short8*)&lsB[(wc * 64 + i * 16 + l4) * 64 + ks * 32 + lh * 8];
      }
#pragma unroll
      for (int i = 0; i < 4; ++i)
#pragma unroll
        for (int j = 0; j < 4; ++j)
          acc[i][j] = __builtin_amdgcn_mfma_f32_16x16x32_bf16(af[i], bf[j], acc[i][j], 0, 0, 0);
    }
    __syncthreads();
  }

  const int row0 = bm * 128 + wr * 64;
  const int col0 = bn * 128 + wc * 64;
  float* Cp = (float*)Cout + (size_t)slice * M * N;
#pragma unroll
  for (int i = 0; i < 4; ++i) {
#pragma unroll
    for (int j = 0; j < 4; ++j) {
      int col = col0 + j * 16 + l4;
#pragma unroll
      for (int r = 0; r < 4; ++r) {
        int row = row0 + i * 16 + lh * 4 + r;
        size_t idx = (size_t)row * N + col;
        float v = acc[i][j][r];
        if (EPI == 1) {
          ((float*)Cout)[idx] = v + bias[col] + resid[idx];
        } else {
          Cp[idx] = v;
        }
      }
    }
  }
}

// ---------------- split-K reduce: out = p0 + p1 + bias + resid ----------------
__global__ __launch_bounds__(256) void reduce2_kernel(const float* __restrict__ p0,
                                                      const float* __restrict__ p1,
                                                      const float* __restrict__ resid,
                                                      const float* __restrict__ bias,
                                                      float* __restrict__ out) {
  for (int i = blockIdx.x * 256 + threadIdx.x; i < (NROWS * D_DIM) / 4;
       i += gridDim.x * 256) {
    float4 a = ((const float4*)p0)[i];
    float4 b = ((const float4*)p1)[i];
    float4 r = ((const float4*)resid)[i];
    float4 bb = ((const float4*)bias)[i & 255];
    float4 o;
    o.x = a.x + b.x + r.x + bb.x;
    o.y = a.y + b.y + r.y + bb.y;
    o.z = a.z + b.z + r.z + bb.z;
    o.w = a.w + b.w + r.w + bb.w;
    ((float4*)out)[i] = o;
  }
}

// ---------------- V transpose: qkv V-region -> vt[b,h,d,s] ----------------
__global__ __launch_bounds__(256) void transpose_v(const u16* __restrict__ qkv,
                                                   u16* __restrict__ vt) {
  const int gw = blockIdx.x * 4 + (threadIdx.x >> 6);
  const int lane = threadIdx.x & 63;
  const int bh = gw >> 5;
  const int st = gw & 31;
  const int b = bh >> 4, h = bh & 15;
  const u16* src = qkv + (size_t)(b * S_LEN + st * 64) * 3072 + 2048 + h * 64 + lane;
  short8 acc8[8];
#pragma unroll
  for (int o = 0; o < 8; ++o)
#pragma unroll
    for (int i = 0; i < 8; ++i)
      acc8[o][i] = (short)src[(size_t)(o * 8 + i) * 3072];
  u16* dst = vt + ((size_t)bh * 64 + lane) * S_LEN + st * 64;
#pragma unroll
  for (int o = 0; o < 8; ++o) *(short8*)(dst + o * 8) = acc8[o];
}

// ---------------- Flash attention with ALiBi (swapped-S, tile-skip) --------
__global__ __launch_bounds__(256, 4) void attn_kernel(const u16* __restrict__ qkv,
                                                      const u16* __restrict__ vt,
                                                      u16* __restrict__ ao) {
  const int id = blockIdx.x;
  const int xcd = id & 7, slot = id >> 3;
  const int u = slot >> 5;
  const int qt = slot & 31;
  const int h = (u >> 1) ? (15 - xcd) : xcd;
  const int b = u & 1;
  const int bh = b * 16 + h;
  const int tid = threadIdx.x;
  const int wid = tid >> 6, lane = tid & 63;
  const int l4 = lane & 15, lh = lane >> 4;

  __shared__ u16 Kt[2][64 * 64];
  __shared__ u16 Vt[2][64 * 64];
  __shared__ u16 Pt[4][16 * 64];

  const size_t RS = 3 * D_DIM;
  const u16* base = qkv + (size_t)b * S_LEN * RS + h * HDIM;
  const u16* kbase = base + D_DIM;
  const u16* vtb = vt + (size_t)bh * HDIM * S_LEN;
  char* PtW = (char*)Pt[wid];

  short8 qf[2];
  {
    const u16* qp = base + (size_t)(qt * 64 + wid * 16 + l4) * RS + lh * 8;
    qf[0] = *(const short8*)qp;
    qf[1] = *(const short8*)(qp + 32);
  }

  int koff[4][2];
#pragma unroll
  for (int nb = 0; nb < 4; ++nb)
#pragma unroll
    for (int ks = 0; ks < 2; ++ks) {
      int row = nb * 16 + l4;
      koff[nb][ks] = row * 128 + (((ks * 32 + lh * 8) * 2) ^ ((row & 7) << 4));
    }
  int poff[2];
#pragma unroll
  for (int ks = 0; ks < 2; ++ks)
    poff[ks] = l4 * 128 + (((ks * 64 + lh * 16)) ^ ((l4 & 7) << 4));
  int pwoff[4];
#pragma unroll
  for (int nb = 0; nb < 4; ++nb)
    pwoff[nb] = l4 * 128 + (((lh * 8 + nb * 32)) ^ ((l4 & 7) << 4));

  const float slope2 = exp2f(-0.5f * (float)(h + 1)) * 1.44269504088896f;
  const float scale2 = 0.125f * 1.44269504088896f;
  const int ibase = lh * 4 - (qt * 64 + wid * 16 + l4);
  float bc[4][4];
#pragma unroll
  for (int nb = 0; nb < 4; ++nb)
#pragma unroll
    for (int r = 0; r < 4; ++r)
      bc[nb][r] = slope2 * (float)(ibase + 16 * nb + r);

  int nt = (int)ceilf(40.0f / (64.0f * slope2)) + 1;
  if (nt > 32) nt = 32;
  const int ktmin = 32 - nt;

  float m = -1e30f, l = 0.f;
  f32x4 accO[4];
#pragma unroll
  for (int nd = 0; nd < 4; ++nd) accO[nd] = (f32x4){0.f, 0.f, 0.f, 0.f};

  const int srow = tid >> 3;
  const int sc8 = (tid & 7) * 8;
  const int swo = srow * 128 + ((sc8 * 2) ^ ((srow & 7) << 4));
  short8 kreg[2], vreg[2];
#define STAGE_LOAD(KT)                                                              \
  {                                                                                 \
    kreg[0] = *(const short8*)(kbase + (size_t)((KT)*64 + srow) * RS + sc8);        \
    kreg[1] = *(const short8*)(kbase + (size_t)((KT)*64 + srow + 32) * RS + sc8);   \
    vreg[0] = *(const short8*)(vtb + (size_t)srow * S_LEN + (KT)*64 + sc8);         \
    vreg[1] = *(const short8*)(vtb + (size_t)(srow + 32) * S_LEN + (KT)*64 + sc8);  \
  }
#define STAGE_WRITE(B)                                   \
  {                                                      \
    *(short8*)((char*)Kt[B] + swo) = kreg[0];            \
    *(short8*)((char*)Kt[B] + swo + 4096) = kreg[1];     \
    *(short8*)((char*)Vt[B] + swo) = vreg[0];            \
    *(short8*)((char*)Vt[B] + swo + 4096) = vreg[1];     \
  }

  STAGE_LOAD(31);
  STAGE_WRITE(0);
  __syncthreads();
  int cur = 0;

  for (int kt = 31; kt >= ktmin; --kt) {
    if (kt > ktmin) STAGE_LOAD(kt - 1);
    const char* Kc = (const char*)Kt[cur];
    const char* Vc = (const char*)Vt[cur];

    f32x4 sacc[4];
#pragma unroll
    for (int nb = 0; nb < 4; ++nb) sacc[nb] = (f32x4){0.f, 0.f, 0.f, 0.f};
    __builtin_amdgcn_s_setprio(1);
#pragma unroll
    for (int ks = 0; ks < 2; ++ks)
#pragma unroll
      for (int nb = 0; nb < 4; ++nb) {
        short8 kf = *(const short8*)(Kc + koff[nb][ks]);
        sacc[nb] = __builtin_amdgcn_mfma_f32_16x16x32_bf16(kf, qf[ks], sacc[nb], 0, 0, 0);
      }
    __builtin_amdgcn_s_setprio(0);

    float p[4][4];
    const float ktoff = slope2 * (float)(kt * 64);
#pragma unroll
    for (int nb = 0; nb < 4; ++nb)
#pragma unroll
      for (int r = 0; r < 4; ++r)
        p[nb][r] = fmaf(sacc[nb][r], scale2, bc[nb][r] + ktoff);

    float mx0 = fmaxf(fmaxf(p[0][0], p[0][1]), fmaxf(p[0][2], p[0][3]));
    float mx1 = fmaxf(fmaxf(p[1][0], p[1][1]), fmaxf(p[1][2], p[1][3]));
    float mx2 = fmaxf(fmaxf(p[2][0], p[2][1]), fmaxf(p[2][2], p[2][3]));
    float mx3 = fmaxf(fmaxf(p[3][0], p[3][1]), fmaxf(p[3][2], p[3][3]));
    float tm = fmaxf(fmaxf(mx0, mx1), fmaxf(mx2, mx3));
    tm = fmaxf(tm, __shfl_xor(tm, 16));
    tm = fmaxf(tm, __shfl_xor(tm, 32));

    if (__any(tm > m)) {
      float mn = fmaxf(m, tm);
      float corr = exp2f(m - mn);
      m = mn;
      l *= corr;
      float cb[4];
#pragma unroll
      for (int r = 0; r < 4; ++r)
        cb[r] = __shfl(corr, (lane & 48) | (lh * 4 + r));
#pragma unroll
      for (int nd = 0; nd < 4; ++nd)
#pragma unroll
        for (int r = 0; r < 4; ++r) accO[nd][r] *= cb[r];
    }

#pragma unroll
    for (int nb = 0; nb < 4; ++nb)
#pragma unroll
      for (int r = 0; r < 4; ++r) p[nb][r] = exp2f(p[nb][r] - m);

    float s0 = (p[0][0] + p[0][1]) + (p[0][2] + p[0][3]);
    float s1 = (p[1][0] + p[1][1]) + (p[1][2] + p[1][3]);
    float s2 = (p[2][0] + p[2][1]) + (p[2][2] + p[2][3]);
    float s3 = (p[3][0] + p[3][1]) + (p[3][2] + p[3][3]);
    float rs = (s0 + s1) + (s2 + s3);
    rs += __shfl_xor(rs, 16);
    rs += __shfl_xor(rs, 32);
    l += rs;

#pragma unroll
    for (int nb = 0; nb < 4; ++nb) {
      uint32_t w0 = pack_bf2(p[nb][0], p[nb][1]);
      uint32_t w1 = pack_bf2(p[nb][2], p[nb][3]);
      *(uint2*)(PtW + pwoff[nb]) = make_uint2(w0, w1);
    }
    asm volatile("s_waitcnt lgkmcnt(0)" ::: "memory");

    __builtin_amdgcn_s_setprio(1);
#pragma unroll
    for (int ks = 0; ks < 2; ++ks) {
      short8 pf = *(const short8*)(PtW + poff[ks]);
#pragma unroll
      for (int nd = 0; nd < 4; ++nd) {
        short8 vf = *(const short8*)(Vc + koff[nd][ks]);
        accO[nd] = __builtin_amdgcn_mfma_f32_16x16x32_bf16(pf, vf, accO[nd], 0, 0, 0);
      }
    }
    __builtin_amdgcn_s_setprio(0);

    if (kt > ktmin) STAGE_WRITE(cur ^ 1);
    __syncthreads();
    cur ^= 1;
  }

  float rinv = 1.0f / l;
  float ib[4];
#pragma unroll
  for (int r = 0; r < 4; ++r)
    ib[r] = __shfl(rinv, (lane & 48) | (lh * 4 + r));
  u16* aop = ao + ((size_t)(b * S_LEN + qt * 64 + wid * 16 + lh * 4)) * D_DIM + h * HDIM;
#pragma unroll
  for (int nd = 0; nd < 4; ++nd)
#pragma unroll
    for (int r = 0; r < 4; ++r)
      aop[(size_t)r * D_DIM + nd * 16 + l4] = f2bf(accO[nd][r] * ib[r]);
#undef STAGE_LOAD
#undef STAGE_WRITE
}

extern "C" void kernel_launch(void* const* d_in, const int* in_sizes, int n_in,
                              void* d_out, int out_size, void* d_ws, size_t ws_size,
                              hipStream_t stream) {
  const float* x   = (const float*)d_in[0];
  const float* Wq  = (const float*)d_in[1];
  const float* Wk  = (const float*)d_in[2];
  const float* Wv  = (const float*)d_in[3];
  const float* Wo  = (const float*)d_in[4];
  const float* bo  = (const float*)d_in[5];
  const float* W1  = (const float*)d_in[6];
  const float* b1  = (const float*)d_in[7];
  const float* W2  = (const float*)d_in[8];
  const float* b2  = (const float*)d_in[9];
  const float* g1  = (const float*)d_in[10];
  const float* be1 = (const float*)d_in[11];
  const float* g2  = (const float*)d_in[12];
  const float* be2 = (const float*)d_in[13];

  char* p = (char*)d_ws;
  u16* wqkv = (u16*)p; p += (size_t)3072 * 1024 * 2;
  u16* wo   = (u16*)p; p += (size_t)1024 * 1024 * 2;
  u16* w1   = (u16*)p; p += (size_t)4096 * 1024 * 2;
  u16* w2   = (u16*)p; p += (size_t)4096 * 1024 * 2;
  u16* hb   = (u16*)p; p += (size_t)4096 * 1024 * 2;
  u16* qkvb = (u16*)p; p += (size_t)4096 * 3072 * 2;
  u16* aob  = (u16*)p; p += (size_t)4096 * 1024 * 2;
  float* x1 = (float*)p; p += (size_t)4096 * 1024 * 4;
  u16* h2b  = (u16*)p; p += (size_t)4096 * 1024 * 2;
  u16* ff1  = (u16*)p; p += (size_t)4096 * 4096 * 2;
  u16* vt   = ff1;            // alias: vt dead before ff1 written
  float* pk = (float*)hb;     // alias: hb+qkvb dead before FFN2

  cast_kernel<<<1024, 256, 0, stream>>>(Wq, wqkv, 262144);
  cast_kernel<<<1024, 256, 0, stream>>>(Wk, wqkv + 1024 * 1024, 262144);
  cast_kernel<<<1024, 256, 0, stream>>>(Wv, wqkv + 2 * 1024 * 1024, 262144);
  cast_kernel<<<1024, 256, 0, stream>>>(Wo, wo, 262144);
  cast_kernel<<<4096, 256, 0, stream>>>(W1, w1, 1048576);
  cast_kernel<<<4096, 256, 0, stream>>>(W2, w2, 1048576);

  ln_kernel<<<4096, 256, 0, stream>>>(x, g1, be1, hb);
  // qkv = h @ [Wq|Wk|Wv]^T   (256^2 deep-pipe)
  gemm_bt2<0><<<16 * 12, 512, 0, stream>>>(hb, wqkv, qkvb, nullptr, 4096, 3072, 1024);
  transpose_v<<<256, 256, 0, stream>>>(qkvb, vt);
  attn_kernel<<<1024, 256, 0, stream>>>(qkvb, vt, aob);
  gemm_bt<1><<<32 * 8, 256, 0, stream>>>(aob, wo, x1, bo, x, 4096, 1024, 1024, 1);
  ln_kernel<<<4096, 256, 0, stream>>>(x1, g2, be2, h2b);
  // ff1 = relu(h2 @ W1^T + b1)   (256^2 deep-pipe)
  gemm_bt2<2><<<16 * 16, 512, 0, stream>>>(h2b, w1, ff1, b1, 4096, 4096, 1024);
  gemm_bt<3><<<2 * 32 * 8, 256, 0, stream>>>(ff1, w2, pk, nullptr, nullptr, 4096, 1024, 4096, 2);
  reduce2_kernel<<<2048, 256, 0, stream>>>(pk, pk + (size_t)4096 * 1024, x1, b2, (float*)d_out);
}

// Round 8
// 236.341 us; speedup vs baseline: 1.7715x; 1.0612x over previous
//
#include <hip/hip_runtime.h>
#include <hip/hip_bf16.h>
#include <stdint.h>

typedef unsigned short u16;
typedef __attribute__((ext_vector_type(8))) short short8;
typedef __attribute__((ext_vector_type(4))) float f32x4;

#define S_LEN 2048
#define D_DIM 1024
#define NHEAD 16
#define HDIM 64
#define NROWS 4096

__device__ __forceinline__ u16 f2bf(float f) {
  union { float f; uint32_t u; } c; c.f = f;
  uint32_t r = (c.u + 0x7fffu + ((c.u >> 16) & 1u)) >> 16;
  return (u16)r;
}

__device__ __forceinline__ uint32_t pack_bf2(float a, float b) {
  __hip_bfloat162 h = __float22bfloat162_rn(float2{a, b});
  union { __hip_bfloat162 h; uint32_t u; } c; c.h = h;
  return c.u;
}

__device__ __forceinline__ void gload_lds16(const void* g, void* l) {
  typedef const __attribute__((address_space(1))) unsigned int gq_t;
  typedef __attribute__((address_space(3))) unsigned int lq_t;
  __builtin_amdgcn_global_load_lds((gq_t*)(uintptr_t)g,
                                   (lq_t*)(uint32_t)(uintptr_t)l, 16, 0, 0);
}

// ---------------- all weight casts fused (fp32 -> bf16) ----------------
// float4 ranges: [0,786432) Wq|Wk|Wv -> wqkv, then Wo, W1, W2.
__global__ __launch_bounds__(256) void cast_all(const float* __restrict__ Wq,
                                                const float* __restrict__ Wk,
                                                const float* __restrict__ Wv,
                                                const float* __restrict__ Wo,
                                                const float* __restrict__ W1,
                                                const float* __restrict__ W2,
                                                u16* __restrict__ wqkv,
                                                u16* __restrict__ wo,
                                                u16* __restrict__ w1,
                                                u16* __restrict__ w2) {
  int i = blockIdx.x * 256 + threadIdx.x;  // 0..3145727
  const float* src;
  u16* dst;
  int rel;
  if (i < 786432) {
    int ws = i / 262144;
    rel = i - ws * 262144;
    src = (ws == 0) ? Wq : ((ws == 1) ? Wk : Wv);
    dst = wqkv + (size_t)ws * 1048576;
  } else if (i < 1048576) {
    rel = i - 786432; src = Wo; dst = wo;
  } else if (i < 2097152) {
    rel = i - 1048576; src = W1; dst = w1;
  } else {
    rel = i - 2097152; src = W2; dst = w2;
  }
  float4 v = ((const float4*)src)[rel];
  ((ushort4*)dst)[rel] = make_ushort4(f2bf(v.x), f2bf(v.y), f2bf(v.z), f2bf(v.w));
}

// ---------------- LayerNorm fp32 -> bf16 ----------------
__global__ __launch_bounds__(256) void ln_kernel(const float* __restrict__ x,
                                                 const float* __restrict__ g,
                                                 const float* __restrict__ be,
                                                 u16* __restrict__ out) {
  int row = blockIdx.x;
  int tid = threadIdx.x;
  const float4 v = ((const float4*)(x + (size_t)row * D_DIM))[tid];
  float s = v.x + v.y + v.z + v.w;
  float s2 = v.x * v.x + v.y * v.y + v.z * v.z + v.w * v.w;
#pragma unroll
  for (int off = 1; off < 64; off <<= 1) {
    s += __shfl_xor(s, off);
    s2 += __shfl_xor(s2, off);
  }
  __shared__ float ss[4], ss2[4];
  if ((tid & 63) == 0) { ss[tid >> 6] = s; ss2[tid >> 6] = s2; }
  __syncthreads();
  s = ss[0] + ss[1] + ss[2] + ss[3];
  s2 = ss2[0] + ss2[1] + ss2[2] + ss2[3];
  float mu = s * (1.0f / D_DIM);
  float var = s2 * (1.0f / D_DIM) - mu * mu;
  float rs = rsqrtf(var + 1e-5f);
  float4 gv = ((const float4*)g)[tid];
  float4 bv = ((const float4*)be)[tid];
  ushort4 o = make_ushort4(f2bf((v.x - mu) * rs * gv.x + bv.x),
                           f2bf((v.y - mu) * rs * gv.y + bv.y),
                           f2bf((v.z - mu) * rs * gv.z + bv.z),
                           f2bf((v.w - mu) * rs * gv.w + bv.w));
  ((ushort4*)(out + (size_t)row * D_DIM))[tid] = o;
}

// ====== 256x256 BK=32 deep-pipe NT GEMM ======
template <int EPI>
__global__ __launch_bounds__(512, 2) void gemm_bt2(const u16* __restrict__ A,
                                                   const u16* __restrict__ Bw,
                                                   void* __restrict__ Cout,
                                                   const float* __restrict__ bias,
                                                   int M, int N, int K) {
  __shared__ u16 lsA[2][256 * 32];
  __shared__ u16 lsB[2][256 * 32];
  const int tid = threadIdx.x;
  const int wid = tid >> 6, lane = tid & 63;
  const int l4 = lane & 15, lh = lane >> 4;
  const int wr = wid >> 2, wc = wid & 3;
  const int nbn = N >> 8;
  const int nwg = (M >> 8) * nbn;
  const int t0 = (blockIdx.x & 7) * (nwg >> 3) + (blockIdx.x >> 3);
  const int bm = t0 / nbn, bn = t0 % nbn;

  f32x4 acc[8][4];
#pragma unroll
  for (int i = 0; i < 8; ++i)
#pragma unroll
    for (int j = 0; j < 4; ++j) acc[i][j] = (f32x4){0.f, 0.f, 0.f, 0.f};

  const int srow = lane >> 2;
  const int sblk = (lane & 3) ^ ((lane >> 3) & 3);
  const u16* Abase = A + ((size_t)bm * 256 + wid * 32 + srow) * K + sblk * 8;
  const u16* Bbase = Bw + ((size_t)bn * 256 + wid * 32 + srow) * K + sblk * 8;
  const size_t r16 = (size_t)16 * K;
#define STAGE(BUF, KT)                                              \
  {                                                                 \
    int ko = (KT) * 32;                                             \
    gload_lds16(Abase + ko, (char*)lsA[BUF] + wid * 2048);          \
    gload_lds16(Abase + r16 + ko, (char*)lsA[BUF] + wid * 2048 + 1024); \
    gload_lds16(Bbase + ko, (char*)lsB[BUF] + wid * 2048);          \
    gload_lds16(Bbase + r16 + ko, (char*)lsB[BUF] + wid * 2048 + 1024); \
  }

  const int swz = (lh ^ ((l4 >> 1) & 3)) << 4;
  int aoff[8], boff[4];
#pragma unroll
  for (int m = 0; m < 8; ++m) aoff[m] = (wr * 128 + m * 16 + l4) * 64 + swz;
#pragma unroll
  for (int n = 0; n < 4; ++n) boff[n] = (wc * 64 + n * 16 + l4) * 64 + swz;

  STAGE(0, 0);
  __syncthreads();
  int cur = 0;
  const int NT = K >> 5;

  for (int t = 0; t < NT; ++t) {
    if (t + 1 < NT) STAGE(cur ^ 1, t + 1);
    const char* La = (const char*)lsA[cur];
    const char* Lb = (const char*)lsB[cur];
    short8 aF[4], bF[4], aG[4];
#pragma unroll
    for (int m = 0; m < 4; ++m) aF[m] = *(const short8*)(La + aoff[m]);
#pragma unroll
    for (int n = 0; n < 4; ++n) bF[n] = *(const short8*)(Lb + boff[n]);
    __builtin_amdgcn_s_setprio(1);
#pragma unroll
    for (int m = 0; m < 4; ++m)
#pragma unroll
      for (int n = 0; n < 4; ++n)
        acc[m][n] = __builtin_amdgcn_mfma_f32_16x16x32_bf16(aF[m], bF[n], acc[m][n], 0, 0, 0);
    __builtin_amdgcn_s_setprio(0);
#pragma unroll
    for (int m = 0; m < 4; ++m) aG[m] = *(const short8*)(La + aoff[m + 4]);
    __builtin_amdgcn_s_setprio(1);
#pragma unroll
    for (int m = 0; m < 4; ++m)
#pragma unroll
      for (int n = 0; n < 4; ++n)
        acc[m + 4][n] = __builtin_amdgcn_mfma_f32_16x16x32_bf16(aG[m], bF[n], acc[m + 4][n], 0, 0, 0);
    __builtin_amdgcn_s_setprio(0);
    if (t + 1 < NT) __syncthreads();
    cur ^= 1;
  }

  const int row0 = bm * 256 + wr * 128 + lh * 4;
  const int col0 = bn * 256 + wc * 64 + l4;
#pragma unroll
  for (int m = 0; m < 8; ++m) {
#pragma unroll
    for (int n = 0; n < 4; ++n) {
      int col = col0 + n * 16;
#pragma unroll
      for (int r = 0; r < 4; ++r) {
        size_t idx = (size_t)(row0 + m * 16 + r) * N + col;
        float v = acc[m][n][r];
        if (EPI == 0) {
          ((u16*)Cout)[idx] = f2bf(v);
        } else {
          v += bias[col];
          ((u16*)Cout)[idx] = f2bf(v > 0.f ? v : 0.f);
        }
      }
    }
  }
#undef STAGE
}

// ---------------- 128x128 NT GEMM (O-proj / FFN2 split-K) ----------
template <int EPI>
__global__ __launch_bounds__(256) void gemm_bt(const u16* __restrict__ A,
                                               const u16* __restrict__ Bw,
                                               void* __restrict__ Cout,
                                               const float* __restrict__ bias,
                                               const float* __restrict__ resid,
                                               int M, int N, int K, int ksl) {
  __shared__ u16 lsA[128 * 64];
  __shared__ u16 lsB[128 * 64];
  const int tid = threadIdx.x;
  const int wid = tid >> 6, lane = tid & 63;
  const int l4 = lane & 15, lh = lane >> 4;
  const int nbn = N >> 7;
  const int nwgs = (M >> 7) * nbn;
  const int slice = blockIdx.x / nwgs;
  const int id0 = blockIdx.x % nwgs;
  const int t = (id0 & 7) * (nwgs >> 3) + (id0 >> 3);
  const int bm = t / nbn, bn = t % nbn;
  const int wr = wid >> 1, wc = wid & 1;
  const int Ks = K / ksl;

  f32x4 acc[4][4];
#pragma unroll
  for (int i = 0; i < 4; ++i)
#pragma unroll
    for (int j = 0; j < 4; ++j) acc[i][j] = (f32x4){0.f, 0.f, 0.f, 0.f};

  const u16* Ab = A + (size_t)bm * 128 * K + (size_t)slice * Ks;
  const u16* Bb = Bw + (size_t)bn * 128 * K + (size_t)slice * Ks;
  const int srow = (lane >> 3);
  const int scol = (lane & 7) * 8;

  for (int k0 = 0; k0 < Ks; k0 += 64) {
#pragma unroll
    for (int c = 0; c < 4; ++c) {
      int ch = wid * 4 + c;
      int row = ch * 8 + srow;
      gload_lds16(Ab + (size_t)row * K + k0 + scol, &lsA[ch * 512]);
      gload_lds16(Bb + (size_t)row * K + k0 + scol, &lsB[ch * 512]);
    }
    __syncthreads();
#pragma unroll
    for (int ks = 0; ks < 2; ++ks) {
      short8 af[4], bf[4];
#pragma unroll
      for (int i = 0; i < 4; ++i) {
        af[i] = *(const short8*)&lsA[(wr * 64 + i * 16 + l4) * 64 + ks * 32 + lh * 8];
        bf[i] = *(const short8*)&lsB[(wc * 64 + i * 16 + l4) * 64 + ks * 32 + lh * 8];
      }
#pragma unroll
      for (int i = 0; i < 4; ++i)
#pragma unroll
        for (int j = 0; j < 4; ++j)
          acc[i][j] = __builtin_amdgcn_mfma_f32_16x16x32_bf16(af[i], bf[j], acc[i][j], 0, 0, 0);
    }
    __syncthreads();
  }

  const int row0 = bm * 128 + wr * 64;
  const int col0 = bn * 128 + wc * 64;
  float* Cp = (float*)Cout + (size_t)slice * M * N;
#pragma unroll
  for (int i = 0; i < 4; ++i) {
#pragma unroll
    for (int j = 0; j < 4; ++j) {
      int col = col0 + j * 16 + l4;
#pragma unroll
      for (int r = 0; r < 4; ++r) {
        int row = row0 + i * 16 + lh * 4 + r;
        size_t idx = (size_t)row * N + col;
        float v = acc[i][j][r];
        if (EPI == 1) {
          ((float*)Cout)[idx] = v + bias[col] + resid[idx];
        } else {
          Cp[idx] = v;
        }
      }
    }
  }
}

// ---------------- split-K reduce ----------------
__global__ __launch_bounds__(256) void reduce2_kernel(const float* __restrict__ p0,
                                                      const float* __restrict__ p1,
                                                      const float* __restrict__ resid,
                                                      const float* __restrict__ bias,
                                                      float* __restrict__ out) {
  for (int i = blockIdx.x * 256 + threadIdx.x; i < (NROWS * D_DIM) / 4;
       i += gridDim.x * 256) {
    float4 a = ((const float4*)p0)[i];
    float4 b = ((const float4*)p1)[i];
    float4 r = ((const float4*)resid)[i];
    float4 bb = ((const float4*)bias)[i & 255];
    float4 o;
    o.x = a.x + b.x + r.x + bb.x;
    o.y = a.y + b.y + r.y + bb.y;
    o.z = a.z + b.z + r.z + bb.z;
    o.w = a.w + b.w + r.w + bb.w;
    ((float4*)out)[i] = o;
  }
}

// ---------------- V transpose ----------------
__global__ __launch_bounds__(256) void transpose_v(const u16* __restrict__ qkv,
                                                   u16* __restrict__ vt) {
  const int gw = blockIdx.x * 4 + (threadIdx.x >> 6);
  const int lane = threadIdx.x & 63;
  const int bh = gw >> 5;
  const int st = gw & 31;
  const int b = bh >> 4, h = bh & 15;
  const u16* src = qkv + (size_t)(b * S_LEN + st * 64) * 3072 + 2048 + h * 64 + lane;
  short8 acc8[8];
#pragma unroll
  for (int o = 0; o < 8; ++o)
#pragma unroll
    for (int i = 0; i < 8; ++i)
      acc8[o][i] = (short)src[(size_t)(o * 8 + i) * 3072];
  u16* dst = vt + ((size_t)bh * 64 + lane) * S_LEN + st * 64;
#pragma unroll
  for (int o = 0; o < 8; ++o) *(short8*)(dst + o * 8) = acc8[o];
}

// ---------------- Flash attention with ALiBi (KV-split flash-decode) --------
// 28 chunk-units per (b,qt): heavy heads split into <=12-tile chunks.
// h<=8 (nsp==1): direct normalized write. h>=9: f32 partials (O,m,l) + combine.
__global__ __launch_bounds__(256, 4) void attn_kernel(const u16* __restrict__ qkv,
                                                      const u16* __restrict__ vt,
                                                      u16* __restrict__ ao,
                                                      float* __restrict__ pO,
                                                      float* __restrict__ pML) {
  const int id = blockIdx.x;
  const int sub = id & 63;   // (b,qt)
  const int ugrp = id >> 6;  // 0..27
  int h, j;
  if (ugrp < 15) { h = 15 - ugrp / 3; j = ugrp % 3; }
  else if (ugrp < 19) { h = 10 - ((ugrp - 15) >> 1); j = (ugrp - 15) & 1; }
  else { h = 27 - ugrp; j = 0; }
  const int b = sub >> 5, qt = sub & 31;
  const int bh = b * 16 + h;
  const int tid = threadIdx.x;
  const int wid = tid >> 6, lane = tid & 63;
  const int l4 = lane & 15, lh = lane >> 4;

  __shared__ u16 Kt[2][64 * 64];
  __shared__ u16 Vt[2][64 * 64];
  __shared__ u16 Pt[4][16 * 64];

  const size_t RS = 3 * D_DIM;
  const u16* base = qkv + (size_t)b * S_LEN * RS + h * HDIM;
  const u16* kbase = base + D_DIM;
  const u16* vtb = vt + (size_t)bh * HDIM * S_LEN;
  char* PtW = (char*)Pt[wid];

  short8 qf[2];
  {
    const u16* qp = base + (size_t)(qt * 64 + wid * 16 + l4) * RS + lh * 8;
    qf[0] = *(const short8*)qp;
    qf[1] = *(const short8*)(qp + 32);
  }

  int koff[4][2];
#pragma unroll
  for (int nb = 0; nb < 4; ++nb)
#pragma unroll
    for (int ks = 0; ks < 2; ++ks) {
      int row = nb * 16 + l4;
      koff[nb][ks] = row * 128 + (((ks * 32 + lh * 8) * 2) ^ ((row & 7) << 4));
    }
  int poff[2];
#pragma unroll
  for (int ks = 0; ks < 2; ++ks)
    poff[ks] = l4 * 128 + (((ks * 64 + lh * 16)) ^ ((l4 & 7) << 4));
  int pwoff[4];
#pragma unroll
  for (int nb = 0; nb < 4; ++nb)
    pwoff[nb] = l4 * 128 + (((lh * 8 + nb * 32)) ^ ((l4 & 7) << 4));

  const float slope2 = exp2f(-0.5f * (float)(h + 1)) * 1.44269504088896f;
  const float scale2 = 0.125f * 1.44269504088896f;
  const int ibase = lh * 4 - (qt * 64 + wid * 16 + l4);
  float bc[4][4];
#pragma unroll
  for (int nb = 0; nb < 4; ++nb)
#pragma unroll
    for (int r = 0; r < 4; ++r)
      bc[nb][r] = slope2 * (float)(ibase + 16 * nb + r);

  int nt = (int)ceilf(40.0f / (64.0f * slope2)) + 1;
  if (nt > 32) nt = 32;
  const int nsp = (nt + 11) / 12;
  const int ktmin = 32 - nt;
  const int hi = 31 - j * 12;
  int lo = hi - 11;
  if (lo < ktmin) lo = ktmin;

  float m = -1e30f;
  f32x4 lacc = (f32x4){0.f, 0.f, 0.f, 0.f};
  f32x4 accO[4];
#pragma unroll
  for (int nd = 0; nd < 4; ++nd) accO[nd] = (f32x4){0.f, 0.f, 0.f, 0.f};
  const short8 vones = {(short)0x3F80, (short)0x3F80, (short)0x3F80, (short)0x3F80,
                        (short)0x3F80, (short)0x3F80, (short)0x3F80, (short)0x3F80};

  const int srow = tid >> 3;
  const int sc8 = (tid & 7) * 8;
  const int swo = srow * 128 + ((sc8 * 2) ^ ((srow & 7) << 4));
  short8 kreg[2], vreg[2];
#define STAGE_LOAD(KT)                                                              \
  {                                                                                 \
    kreg[0] = *(const short8*)(kbase + (size_t)((KT)*64 + srow) * RS + sc8);        \
    kreg[1] = *(const short8*)(kbase + (size_t)((KT)*64 + srow + 32) * RS + sc8);   \
    vreg[0] = *(const short8*)(vtb + (size_t)srow * S_LEN + (KT)*64 + sc8);         \
    vreg[1] = *(const short8*)(vtb + (size_t)(srow + 32) * S_LEN + (KT)*64 + sc8);  \
  }
#define STAGE_WRITE(B)                                   \
  {                                                      \
    *(short8*)((char*)Kt[B] + swo) = kreg[0];            \
    *(short8*)((char*)Kt[B] + swo + 4096) = kreg[1];     \
    *(short8*)((char*)Vt[B] + swo) = vreg[0];            \
    *(short8*)((char*)Vt[B] + swo + 4096) = vreg[1];     \
  }

  STAGE_LOAD(hi);
  STAGE_WRITE(0);
  __syncthreads();
  int cur = 0;
  float ktoff = slope2 * 64.0f * (float)hi;
  const float dko = slope2 * 64.0f;

  for (int kt = hi; kt >= lo; --kt) {
    if (kt > lo) STAGE_LOAD(kt - 1);
    const char* Kc = (const char*)Kt[cur];
    const char* Vc = (const char*)Vt[cur];

    f32x4 sacc[4];
#pragma unroll
    for (int nb = 0; nb < 4; ++nb) sacc[nb] = (f32x4){0.f, 0.f, 0.f, 0.f};
    __builtin_amdgcn_s_setprio(1);
#pragma unroll
    for (int ks = 0; ks < 2; ++ks)
#pragma unroll
      for (int nb = 0; nb < 4; ++nb) {
        short8 kf = *(const short8*)(Kc + koff[nb][ks]);
        sacc[nb] = __builtin_amdgcn_mfma_f32_16x16x32_bf16(kf, qf[ks], sacc[nb], 0, 0, 0);
      }
    __builtin_amdgcn_s_setprio(0);

    // t = score without ktoff; full score = t + ktoff
    float p[4][4];
#pragma unroll
    for (int nb = 0; nb < 4; ++nb)
#pragma unroll
      for (int r = 0; r < 4; ++r)
        p[nb][r] = fmaf(sacc[nb][r], scale2, bc[nb][r]);

    float mx0 = fmaxf(fmaxf(p[0][0], p[0][1]), fmaxf(p[0][2], p[0][3]));
    float mx1 = fmaxf(fmaxf(p[1][0], p[1][1]), fmaxf(p[1][2], p[1][3]));
    float mx2 = fmaxf(fmaxf(p[2][0], p[2][1]), fmaxf(p[2][2], p[2][3]));
    float mx3 = fmaxf(fmaxf(p[3][0], p[3][1]), fmaxf(p[3][2], p[3][3]));
    float tm = fmaxf(fmaxf(mx0, mx1), fmaxf(mx2, mx3));
    tm = fmaxf(tm, __shfl_xor(tm, 16));
    tm = fmaxf(tm, __shfl_xor(tm, 32));

    float mm = m - ktoff;
    if (__any(tm > mm)) {
      float mn = fmaxf(mm, tm);
      float corr = exp2f(mm - mn);
      m = mn + ktoff;
      mm = mn;
      float cb[4];
#pragma unroll
      for (int r = 0; r < 4; ++r)
        cb[r] = __shfl(corr, (lane & 48) | (lh * 4 + r));
#pragma unroll
      for (int nd = 0; nd < 4; ++nd)
#pragma unroll
        for (int r = 0; r < 4; ++r) accO[nd][r] *= cb[r];
#pragma unroll
      for (int r = 0; r < 4; ++r) lacc[r] *= cb[r];
    }

#pragma unroll
    for (int nb = 0; nb < 4; ++nb)
#pragma unroll
      for (int r = 0; r < 4; ++r) p[nb][r] = exp2f(p[nb][r] - mm);

#pragma unroll
    for (int nb = 0; nb < 4; ++nb) {
      uint32_t w0 = pack_bf2(p[nb][0], p[nb][1]);
      uint32_t w1 = pack_bf2(p[nb][2], p[nb][3]);
      *(uint2*)(PtW + pwoff[nb]) = make_uint2(w0, w1);
    }
    asm volatile("s_waitcnt lgkmcnt(0)" ::: "memory");

    __builtin_amdgcn_s_setprio(1);
#pragma unroll
    for (int ks = 0; ks < 2; ++ks) {
      short8 pf = *(const short8*)(PtW + poff[ks]);
      lacc = __builtin_amdgcn_mfma_f32_16x16x32_bf16(pf, vones, lacc, 0, 0, 0);
#pragma unroll
      for (int nd = 0; nd < 4; ++nd) {
        short8 vf = *(const short8*)(Vc + koff[nd][ks]);
        accO[nd] = __builtin_amdgcn_mfma_f32_16x16x32_bf16(pf, vf, accO[nd], 0, 0, 0);
      }
    }
    __builtin_amdgcn_s_setprio(0);

    if (kt > lo) STAGE_WRITE(cur ^ 1);
    __syncthreads();
    cur ^= 1;
    ktoff -= dko;
  }

  if (nsp == 1) {
    float ib[4];
#pragma unroll
    for (int r = 0; r < 4; ++r) ib[r] = 1.0f / lacc[r];
    u16* aop = ao + ((size_t)(b * S_LEN + qt * 64 + wid * 16 + lh * 4)) * D_DIM + h * HDIM;
#pragma unroll
    for (int nd = 0; nd < 4; ++nd)
#pragma unroll
      for (int r = 0; r < 4; ++r)
        aop[(size_t)r * D_DIM + nd * 16 + l4] = f2bf(accO[nd][r] * ib[r]);
  } else {
    const int sbase = (h <= 10) ? (h - 9) * 2 : 4 + (h - 11) * 3;
    const int pidx = sub * 19 + sbase + j;
    float* Op = pO + (size_t)pidx * 4096;
#pragma unroll
    for (int nd = 0; nd < 4; ++nd)
#pragma unroll
      for (int r = 0; r < 4; ++r)
        Op[(wid * 16 + lh * 4 + r) * 64 + nd * 16 + l4] = accO[nd][r];
    float mq[4];
#pragma unroll
    for (int r = 0; r < 4; ++r)
      mq[r] = __shfl(m, (lane & 48) | (lh * 4 + r));
    if (l4 == 0) {
      float* mlp = pML + (size_t)pidx * 128 + (wid * 16 + lh * 4) * 2;
#pragma unroll
      for (int r = 0; r < 4; ++r) {
        mlp[r * 2] = mq[r];
        mlp[r * 2 + 1] = lacc[r];
      }
    }
  }
#undef STAGE_LOAD
#undef STAGE_WRITE
}

// ---------------- combine partials for split heads (h>=9) ----------------
__global__ __launch_bounds__(256) void attn_combine(const float* __restrict__ pO,
                                                    const float* __restrict__ pML,
                                                    u16* __restrict__ ao) {
  const int g = blockIdx.x;        // 448 = 64 subs x 7 heads
  const int sub = g & 63;
  const int h = 9 + (g >> 6);
  const int b = sub >> 5, qt = sub & 31;
  const int nsp = (h <= 10) ? 2 : 3;
  const int sbase = (h <= 10) ? (h - 9) * 2 : 4 + (h - 11) * 3;
  const int pidx0 = sub * 19 + sbase;
  const int tid = threadIdx.x;
  const int row = tid >> 2;
  const int d0 = (tid & 3) * 16;

  float mj[3], lj[3];
#pragma unroll
  for (int k = 0; k < 3; ++k) { mj[k] = -1e30f; lj[k] = 0.f; }
  for (int k = 0; k < nsp; ++k) {
    mj[k] = pML[(size_t)(pidx0 + k) * 128 + row * 2];
    lj[k] = pML[(size_t)(pidx0 + k) * 128 + row * 2 + 1];
  }
  float ms = fmaxf(mj[0], fmaxf(mj[1], mj[2]));
  float w[3];
  float lsum = 0.f;
#pragma unroll
  for (int k = 0; k < 3; ++k) {
    w[k] = exp2f(mj[k] - ms);
    lsum += w[k] * lj[k];
  }
  float inv = 1.0f / lsum;

  u16* aop = ao + ((size_t)(b * S_LEN + qt * 64 + row)) * D_DIM + h * HDIM + d0;
#pragma unroll
  for (int c = 0; c < 4; ++c) {
    float4 o = {0.f, 0.f, 0.f, 0.f};
    for (int k = 0; k < nsp; ++k) {
      const float4 v = *(const float4*)(pO + (size_t)(pidx0 + k) * 4096 + row * 64 + d0 + c * 4);
      o.x += w[k] * v.x; o.y += w[k] * v.y; o.z += w[k] * v.z; o.w += w[k] * v.w;
    }
    ushort4 u4 = make_ushort4(f2bf(o.x * inv), f2bf(o.y * inv), f2bf(o.z * inv), f2bf(o.w * inv));
    *(ushort4*)(aop + c * 4) = u4;
  }
}

extern "C" void kernel_launch(void* const* d_in, const int* in_sizes, int n_in,
                              void* d_out, int out_size, void* d_ws, size_t ws_size,
                              hipStream_t stream) {
  const float* x   = (const float*)d_in[0];
  const float* Wq  = (const float*)d_in[1];
  const float* Wk  = (const float*)d_in[2];
  const float* Wv  = (const float*)d_in[3];
  const float* Wo  = (const float*)d_in[4];
  const float* bo  = (const float*)d_in[5];
  const float* W1  = (const float*)d_in[6];
  const float* b1  = (const float*)d_in[7];
  const float* W2  = (const float*)d_in[8];
  const float* b2  = (const float*)d_in[9];
  const float* g1  = (const float*)d_in[10];
  const float* be1 = (const float*)d_in[11];
  const float* g2  = (const float*)d_in[12];
  const float* be2 = (const float*)d_in[13];

  char* p = (char*)d_ws;
  u16* wqkv = (u16*)p; p += (size_t)3072 * 1024 * 2;
  u16* wo   = (u16*)p; p += (size_t)1024 * 1024 * 2;
  u16* w1   = (u16*)p; p += (size_t)4096 * 1024 * 2;
  u16* w2   = (u16*)p; p += (size_t)4096 * 1024 * 2;
  u16* hb   = (u16*)p; p += (size_t)4096 * 1024 * 2;
  u16* qkvb = (u16*)p; p += (size_t)4096 * 3072 * 2;
  u16* aob  = (u16*)p; p += (size_t)4096 * 1024 * 2;
  float* x1 = (float*)p; p += (size_t)4096 * 1024 * 4;
  u16* h2b  = (u16*)p; p += (size_t)4096 * 1024 * 2;
  u16* ff1  = (u16*)p; p += (size_t)4096 * 4096 * 2;
  u16* vt   = ff1;                                        // 8MB, dead before FFN1
  float* pO = (float*)(ff1 + (size_t)4 * 1024 * 1024);    // 19.9MB partial O
  float* pML = pO + (size_t)1216 * 4096;                  // 0.62MB partial m,l
  float* pk = (float*)hb;                                 // split-K partials

  cast_all<<<12288, 256, 0, stream>>>(Wq, Wk, Wv, Wo, W1, W2, wqkv, wo, w1, w2);

  ln_kernel<<<4096, 256, 0, stream>>>(x, g1, be1, hb);
  gemm_bt2<0><<<16 * 12, 512, 0, stream>>>(hb, wqkv, qkvb, nullptr, 4096, 3072, 1024);
  transpose_v<<<256, 256, 0, stream>>>(qkvb, vt);
  attn_kernel<<<1792, 256, 0, stream>>>(qkvb, vt, aob, pO, pML);
  attn_combine<<<448, 256, 0, stream>>>(pO, pML, aob);
  gemm_bt<1><<<32 * 8, 256, 0, stream>>>(aob, wo, x1, bo, x, 4096, 1024, 1024, 1);
  ln_kernel<<<4096, 256, 0, stream>>>(x1, g2, be2, h2b);
  gemm_bt2<2><<<16 * 16, 512, 0, stream>>>(h2b, w1, ff1, b1, 4096, 4096, 1024);
  gemm_bt<3><<<2 * 32 * 8, 256, 0, stream>>>(ff1, w2, pk, nullptr, nullptr, 4096, 1024, 4096, 2);
  reduce2_kernel<<<2048, 256, 0, stream>>>(pk, pk + (size_t)4096 * 1024, x1, b2, (float*)d_out);
}

// Round 9
// 234.677 us; speedup vs baseline: 1.7841x; 1.0071x over previous
//
#include <hip/hip_runtime.h>
#include <hip/hip_bf16.h>
#include <stdint.h>

typedef unsigned short u16;
typedef __attribute__((ext_vector_type(8))) short short8;
typedef __attribute__((ext_vector_type(4))) float f32x4;

#define S_LEN 2048
#define D_DIM 1024
#define NHEAD 16
#define HDIM 64
#define NROWS 4096

__device__ __forceinline__ u16 f2bf(float f) {
  union { float f; uint32_t u; } c; c.f = f;
  uint32_t r = (c.u + 0x7fffu + ((c.u >> 16) & 1u)) >> 16;
  return (u16)r;
}

__device__ __forceinline__ uint32_t pack_bf2(float a, float b) {
  __hip_bfloat162 h = __float22bfloat162_rn(float2{a, b});
  union { __hip_bfloat162 h; uint32_t u; } c; c.h = h;
  return c.u;
}

__device__ __forceinline__ void gload_lds16(const void* g, void* l) {
  typedef const __attribute__((address_space(1))) unsigned int gq_t;
  typedef __attribute__((address_space(3))) unsigned int lq_t;
  __builtin_amdgcn_global_load_lds((gq_t*)(uintptr_t)g,
                                   (lq_t*)(uint32_t)(uintptr_t)l, 16, 0, 0);
}

// ---------------- all weight casts fused (fp32 -> bf16) ----------------
__global__ __launch_bounds__(256) void cast_all(const float* __restrict__ Wq,
                                                const float* __restrict__ Wk,
                                                const float* __restrict__ Wv,
                                                const float* __restrict__ Wo,
                                                const float* __restrict__ W1,
                                                const float* __restrict__ W2,
                                                u16* __restrict__ wqkv,
                                                u16* __restrict__ wo,
                                                u16* __restrict__ w1,
                                                u16* __restrict__ w2) {
  int i = blockIdx.x * 256 + threadIdx.x;  // 0..3145727
  const float* src;
  u16* dst;
  int rel;
  if (i < 786432) {
    int ws = i / 262144;
    rel = i - ws * 262144;
    src = (ws == 0) ? Wq : ((ws == 1) ? Wk : Wv);
    dst = wqkv + (size_t)ws * 1048576;
  } else if (i < 1048576) {
    rel = i - 786432; src = Wo; dst = wo;
  } else if (i < 2097152) {
    rel = i - 1048576; src = W1; dst = w1;
  } else {
    rel = i - 2097152; src = W2; dst = w2;
  }
  float4 v = ((const float4*)src)[rel];
  ((ushort4*)dst)[rel] = make_ushort4(f2bf(v.x), f2bf(v.y), f2bf(v.z), f2bf(v.w));
}

// ---------------- LayerNorm fp32 -> bf16 ----------------
__global__ __launch_bounds__(256) void ln_kernel(const float* __restrict__ x,
                                                 const float* __restrict__ g,
                                                 const float* __restrict__ be,
                                                 u16* __restrict__ out) {
  int row = blockIdx.x;
  int tid = threadIdx.x;
  const float4 v = ((const float4*)(x + (size_t)row * D_DIM))[tid];
  float s = v.x + v.y + v.z + v.w;
  float s2 = v.x * v.x + v.y * v.y + v.z * v.z + v.w * v.w;
#pragma unroll
  for (int off = 1; off < 64; off <<= 1) {
    s += __shfl_xor(s, off);
    s2 += __shfl_xor(s2, off);
  }
  __shared__ float ss[4], ss2[4];
  if ((tid & 63) == 0) { ss[tid >> 6] = s; ss2[tid >> 6] = s2; }
  __syncthreads();
  s = ss[0] + ss[1] + ss[2] + ss[3];
  s2 = ss2[0] + ss2[1] + ss2[2] + ss2[3];
  float mu = s * (1.0f / D_DIM);
  float var = s2 * (1.0f / D_DIM) - mu * mu;
  float rs = rsqrtf(var + 1e-5f);
  float4 gv = ((const float4*)g)[tid];
  float4 bv = ((const float4*)be)[tid];
  ushort4 o = make_ushort4(f2bf((v.x - mu) * rs * gv.x + bv.x),
                           f2bf((v.y - mu) * rs * gv.y + bv.y),
                           f2bf((v.z - mu) * rs * gv.z + bv.z),
                           f2bf((v.w - mu) * rs * gv.w + bv.w));
  ((ushort4*)(out + (size_t)row * D_DIM))[tid] = o;
}

// ====== 256x256 BK=32 deep-pipe NT GEMM (QKV / FFN1) ======
template <int EPI>
__global__ __launch_bounds__(512, 2) void gemm_bt2(const u16* __restrict__ A,
                                                   const u16* __restrict__ Bw,
                                                   void* __restrict__ Cout,
                                                   const float* __restrict__ bias,
                                                   int M, int N, int K) {
  __shared__ u16 lsA[2][256 * 32];
  __shared__ u16 lsB[2][256 * 32];
  const int tid = threadIdx.x;
  const int wid = tid >> 6, lane = tid & 63;
  const int l4 = lane & 15, lh = lane >> 4;
  const int wr = wid >> 2, wc = wid & 3;
  const int nbn = N >> 8;
  const int nwg = (M >> 8) * nbn;
  const int t0 = (blockIdx.x & 7) * (nwg >> 3) + (blockIdx.x >> 3);
  const int bm = t0 / nbn, bn = t0 % nbn;

  f32x4 acc[8][4];
#pragma unroll
  for (int i = 0; i < 8; ++i)
#pragma unroll
    for (int j = 0; j < 4; ++j) acc[i][j] = (f32x4){0.f, 0.f, 0.f, 0.f};

  const int srow = lane >> 2;
  const int sblk = (lane & 3) ^ ((lane >> 3) & 3);
  const u16* Abase = A + ((size_t)bm * 256 + wid * 32 + srow) * K + sblk * 8;
  const u16* Bbase = Bw + ((size_t)bn * 256 + wid * 32 + srow) * K + sblk * 8;
  const size_t r16 = (size_t)16 * K;
#define STAGE(BUF, KT)                                              \
  {                                                                 \
    int ko = (KT) * 32;                                             \
    gload_lds16(Abase + ko, (char*)lsA[BUF] + wid * 2048);          \
    gload_lds16(Abase + r16 + ko, (char*)lsA[BUF] + wid * 2048 + 1024); \
    gload_lds16(Bbase + ko, (char*)lsB[BUF] + wid * 2048);          \
    gload_lds16(Bbase + r16 + ko, (char*)lsB[BUF] + wid * 2048 + 1024); \
  }

  const int swz = (lh ^ ((l4 >> 1) & 3)) << 4;
  int aoff[8], boff[4];
#pragma unroll
  for (int m = 0; m < 8; ++m) aoff[m] = (wr * 128 + m * 16 + l4) * 64 + swz;
#pragma unroll
  for (int n = 0; n < 4; ++n) boff[n] = (wc * 64 + n * 16 + l4) * 64 + swz;

  STAGE(0, 0);
  __syncthreads();
  int cur = 0;
  const int NT = K >> 5;

  for (int t = 0; t < NT; ++t) {
    if (t + 1 < NT) STAGE(cur ^ 1, t + 1);
    const char* La = (const char*)lsA[cur];
    const char* Lb = (const char*)lsB[cur];
    short8 aF[4], bF[4], aG[4];
#pragma unroll
    for (int m = 0; m < 4; ++m) aF[m] = *(const short8*)(La + aoff[m]);
#pragma unroll
    for (int n = 0; n < 4; ++n) bF[n] = *(const short8*)(Lb + boff[n]);
    __builtin_amdgcn_s_setprio(1);
#pragma unroll
    for (int m = 0; m < 4; ++m)
#pragma unroll
      for (int n = 0; n < 4; ++n)
        acc[m][n] = __builtin_amdgcn_mfma_f32_16x16x32_bf16(aF[m], bF[n], acc[m][n], 0, 0, 0);
    __builtin_amdgcn_s_setprio(0);
#pragma unroll
    for (int m = 0; m < 4; ++m) aG[m] = *(const short8*)(La + aoff[m + 4]);
    __builtin_amdgcn_s_setprio(1);
#pragma unroll
    for (int m = 0; m < 4; ++m)
#pragma unroll
      for (int n = 0; n < 4; ++n)
        acc[m + 4][n] = __builtin_amdgcn_mfma_f32_16x16x32_bf16(aG[m], bF[n], acc[m + 4][n], 0, 0, 0);
    __builtin_amdgcn_s_setprio(0);
    if (t + 1 < NT) __syncthreads();
    cur ^= 1;
  }

  const int row0 = bm * 256 + wr * 128 + lh * 4;
  const int col0 = bn * 256 + wc * 64 + l4;
#pragma unroll
  for (int m = 0; m < 8; ++m) {
#pragma unroll
    for (int n = 0; n < 4; ++n) {
      int col = col0 + n * 16;
#pragma unroll
      for (int r = 0; r < 4; ++r) {
        size_t idx = (size_t)(row0 + m * 16 + r) * N + col;
        float v = acc[m][n][r];
        if (EPI == 0) {
          ((u16*)Cout)[idx] = f2bf(v);
        } else {
          v += bias[col];
          ((u16*)Cout)[idx] = f2bf(v > 0.f ? v : 0.f);
        }
      }
    }
  }
#undef STAGE
}

// ====== 256x128 BK=32 deep-pipe NT GEMM (FFN2 split-K) ======
// 8 waves as 4Mx2N, per-wave 64x64 out. LDS 48KB double-buffered.
// EPI 3: f32 partial (slice-offset). EPI 1: f32 = acc + bias + resid.
template <int EPI>
__global__ __launch_bounds__(512, 2) void gemm_bt3(const u16* __restrict__ A,
                                                   const u16* __restrict__ Bw,
                                                   void* __restrict__ Cout,
                                                   const float* __restrict__ bias,
                                                   const float* __restrict__ resid,
                                                   int M, int N, int K, int ksl) {
  __shared__ u16 lsA[2][256 * 32];
  __shared__ u16 lsB[2][128 * 32];
  const int tid = threadIdx.x;
  const int wid = tid >> 6, lane = tid & 63;
  const int l4 = lane & 15, lh = lane >> 4;
  const int wr = wid >> 1, wc = wid & 1;
  const int nbn = N >> 7;
  const int nwgs = (M >> 8) * nbn;
  const int slice = blockIdx.x / nwgs;
  const int id0 = blockIdx.x % nwgs;
  const int t0 = (id0 & 7) * (nwgs >> 3) + (id0 >> 3);
  const int bm = t0 / nbn, bn = t0 % nbn;
  const int Ks = K / ksl;

  f32x4 acc[4][4];
#pragma unroll
  for (int i = 0; i < 4; ++i)
#pragma unroll
    for (int j = 0; j < 4; ++j) acc[i][j] = (f32x4){0.f, 0.f, 0.f, 0.f};

  const int srow = lane >> 2;
  const int sblk = (lane & 3) ^ ((lane >> 3) & 3);
  const u16* Abase = A + ((size_t)bm * 256 + wid * 16 + srow) * K + (size_t)slice * Ks + sblk * 8;
  const u16* Bbase = Bw + ((size_t)bn * 128 + wid * 16 + srow) * K + (size_t)slice * Ks + sblk * 8;
  const size_t r128 = (size_t)128 * K;
#define STAGE(BUF, KT)                                               \
  {                                                                  \
    int ko = (KT) * 32;                                              \
    gload_lds16(Abase + ko, (char*)lsA[BUF] + wid * 1024);           \
    gload_lds16(Abase + r128 + ko, (char*)lsA[BUF] + 8192 + wid * 1024); \
    gload_lds16(Bbase + ko, (char*)lsB[BUF] + wid * 1024);           \
  }

  const int swz = (lh ^ ((l4 >> 1) & 3)) << 4;
  int aoff[4], boff[4];
#pragma unroll
  for (int m = 0; m < 4; ++m) aoff[m] = (wr * 64 + m * 16 + l4) * 64 + swz;
#pragma unroll
  for (int n = 0; n < 4; ++n) boff[n] = (wc * 64 + n * 16 + l4) * 64 + swz;

  STAGE(0, 0);
  __syncthreads();
  int cur = 0;
  const int NT = Ks >> 5;

  for (int t = 0; t < NT; ++t) {
    if (t + 1 < NT) STAGE(cur ^ 1, t + 1);
    const char* La = (const char*)lsA[cur];
    const char* Lb = (const char*)lsB[cur];
    short8 aF[4], bF[4];
#pragma unroll
    for (int m = 0; m < 4; ++m) aF[m] = *(const short8*)(La + aoff[m]);
#pragma unroll
    for (int n = 0; n < 4; ++n) bF[n] = *(const short8*)(Lb + boff[n]);
    __builtin_amdgcn_s_setprio(1);
#pragma unroll
    for (int m = 0; m < 4; ++m)
#pragma unroll
      for (int n = 0; n < 4; ++n)
        acc[m][n] = __builtin_amdgcn_mfma_f32_16x16x32_bf16(aF[m], bF[n], acc[m][n], 0, 0, 0);
    __builtin_amdgcn_s_setprio(0);
    if (t + 1 < NT) __syncthreads();
    cur ^= 1;
  }

  const int row0 = bm * 256 + wr * 64 + lh * 4;
  const int col0 = bn * 128 + wc * 64 + l4;
  float* Cp = (float*)Cout + (size_t)slice * M * N;
#pragma unroll
  for (int m = 0; m < 4; ++m) {
#pragma unroll
    for (int n = 0; n < 4; ++n) {
      int col = col0 + n * 16;
#pragma unroll
      for (int r = 0; r < 4; ++r) {
        size_t idx = (size_t)(row0 + m * 16 + r) * N + col;
        float v = acc[m][n][r];
        if (EPI == 1) {
          ((float*)Cout)[idx] = v + bias[col] + resid[idx];
        } else {
          Cp[idx] = v;
        }
      }
    }
  }
#undef STAGE
}

// ---------------- 128x128 NT GEMM (O-proj) ----------
template <int EPI>
__global__ __launch_bounds__(256) void gemm_bt(const u16* __restrict__ A,
                                               const u16* __restrict__ Bw,
                                               void* __restrict__ Cout,
                                               const float* __restrict__ bias,
                                               const float* __restrict__ resid,
                                               int M, int N, int K, int ksl) {
  __shared__ u16 lsA[128 * 64];
  __shared__ u16 lsB[128 * 64];
  const int tid = threadIdx.x;
  const int wid = tid >> 6, lane = tid & 63;
  const int l4 = lane & 15, lh = lane >> 4;
  const int nbn = N >> 7;
  const int nwgs = (M >> 7) * nbn;
  const int slice = blockIdx.x / nwgs;
  const int id0 = blockIdx.x % nwgs;
  const int t = (id0 & 7) * (nwgs >> 3) + (id0 >> 3);
  const int bm = t / nbn, bn = t % nbn;
  const int wr = wid >> 1, wc = wid & 1;
  const int Ks = K / ksl;

  f32x4 acc[4][4];
#pragma unroll
  for (int i = 0; i < 4; ++i)
#pragma unroll
    for (int j = 0; j < 4; ++j) acc[i][j] = (f32x4){0.f, 0.f, 0.f, 0.f};

  const u16* Ab = A + (size_t)bm * 128 * K + (size_t)slice * Ks;
  const u16* Bb = Bw + (size_t)bn * 128 * K + (size_t)slice * Ks;
  const int srow = (lane >> 3);
  const int scol = (lane & 7) * 8;

  for (int k0 = 0; k0 < Ks; k0 += 64) {
#pragma unroll
    for (int c = 0; c < 4; ++c) {
      int ch = wid * 4 + c;
      int row = ch * 8 + srow;
      gload_lds16(Ab + (size_t)row * K + k0 + scol, &lsA[ch * 512]);
      gload_lds16(Bb + (size_t)row * K + k0 + scol, &lsB[ch * 512]);
    }
    __syncthreads();
#pragma unroll
    for (int ks = 0; ks < 2; ++ks) {
      short8 af[4], bf[4];
#pragma unroll
      for (int i = 0; i < 4; ++i) {
        af[i] = *(const short8*)&lsA[(wr * 64 + i * 16 + l4) * 64 + ks * 32 + lh * 8];
        bf[i] = *(const short8*)&lsB[(wc * 64 + i * 16 + l4) * 64 + ks * 32 + lh * 8];
      }
#pragma unroll
      for (int i = 0; i < 4; ++i)
#pragma unroll
        for (int j = 0; j < 4; ++j)
          acc[i][j] = __builtin_amdgcn_mfma_f32_16x16x32_bf16(af[i], bf[j], acc[i][j], 0, 0, 0);
    }
    __syncthreads();
  }

  const int row0 = bm * 128 + wr * 64;
  const int col0 = bn * 128 + wc * 64;
  float* Cp = (float*)Cout + (size_t)slice * M * N;
#pragma unroll
  for (int i = 0; i < 4; ++i) {
#pragma unroll
    for (int j = 0; j < 4; ++j) {
      int col = col0 + j * 16 + l4;
#pragma unroll
      for (int r = 0; r < 4; ++r) {
        int row = row0 + i * 16 + lh * 4 + r;
        size_t idx = (size_t)row * N + col;
        float v = acc[i][j][r];
        if (EPI == 1) {
          ((float*)Cout)[idx] = v + bias[col] + resid[idx];
        } else {
          Cp[idx] = v;
        }
      }
    }
  }
}

// ---------------- split-K reduce ----------------
__global__ __launch_bounds__(256) void reduce2_kernel(const float* __restrict__ p0,
                                                      const float* __restrict__ p1,
                                                      const float* __restrict__ resid,
                                                      const float* __restrict__ bias,
                                                      float* __restrict__ out) {
  for (int i = blockIdx.x * 256 + threadIdx.x; i < (NROWS * D_DIM) / 4;
       i += gridDim.x * 256) {
    float4 a = ((const float4*)p0)[i];
    float4 b = ((const float4*)p1)[i];
    float4 r = ((const float4*)resid)[i];
    float4 bb = ((const float4*)bias)[i & 255];
    float4 o;
    o.x = a.x + b.x + r.x + bb.x;
    o.y = a.y + b.y + r.y + bb.y;
    o.z = a.z + b.z + r.z + bb.z;
    o.w = a.w + b.w + r.w + bb.w;
    ((float4*)out)[i] = o;
  }
}

// ---------------- V transpose ----------------
__global__ __launch_bounds__(256) void transpose_v(const u16* __restrict__ qkv,
                                                   u16* __restrict__ vt) {
  const int gw = blockIdx.x * 4 + (threadIdx.x >> 6);
  const int lane = threadIdx.x & 63;
  const int bh = gw >> 5;
  const int st = gw & 31;
  const int b = bh >> 4, h = bh & 15;
  const u16* src = qkv + (size_t)(b * S_LEN + st * 64) * 3072 + 2048 + h * 64 + lane;
  short8 acc8[8];
#pragma unroll
  for (int o = 0; o < 8; ++o)
#pragma unroll
    for (int i = 0; i < 8; ++i)
      acc8[o][i] = (short)src[(size_t)(o * 8 + i) * 3072];
  u16* dst = vt + ((size_t)bh * 64 + lane) * S_LEN + st * 64;
#pragma unroll
  for (int o = 0; o < 8; ++o) *(short8*)(dst + o * 8) = acc8[o];
}

// ---------------- Flash attention with ALiBi (KV-split flash-decode) --------
__global__ __launch_bounds__(256, 4) void attn_kernel(const u16* __restrict__ qkv,
                                                      const u16* __restrict__ vt,
                                                      u16* __restrict__ ao,
                                                      float* __restrict__ pO,
                                                      float* __restrict__ pML) {
  const int id = blockIdx.x;
  const int sub = id & 63;   // (b,qt)
  const int ugrp = id >> 6;  // 0..27
  int h, j;
  if (ugrp < 15) { h = 15 - ugrp / 3; j = ugrp % 3; }
  else if (ugrp < 19) { h = 10 - ((ugrp - 15) >> 1); j = (ugrp - 15) & 1; }
  else { h = 27 - ugrp; j = 0; }
  const int b = sub >> 5, qt = sub & 31;
  const int bh = b * 16 + h;
  const int tid = threadIdx.x;
  const int wid = tid >> 6, lane = tid & 63;
  const int l4 = lane & 15, lh = lane >> 4;

  __shared__ u16 Kt[2][64 * 64];
  __shared__ u16 Vt[2][64 * 64];
  __shared__ u16 Pt[4][16 * 64];

  const size_t RS = 3 * D_DIM;
  const u16* base = qkv + (size_t)b * S_LEN * RS + h * HDIM;
  const u16* kbase = base + D_DIM;
  const u16* vtb = vt + (size_t)bh * HDIM * S_LEN;
  char* PtW = (char*)Pt[wid];

  short8 qf[2];
  {
    const u16* qp = base + (size_t)(qt * 64 + wid * 16 + l4) * RS + lh * 8;
    qf[0] = *(const short8*)qp;
    qf[1] = *(const short8*)(qp + 32);
  }

  int koff[4][2];
#pragma unroll
  for (int nb = 0; nb < 4; ++nb)
#pragma unroll
    for (int ks = 0; ks < 2; ++ks) {
      int row = nb * 16 + l4;
      koff[nb][ks] = row * 128 + (((ks * 32 + lh * 8) * 2) ^ ((row & 7) << 4));
    }
  int poff[2];
#pragma unroll
  for (int ks = 0; ks < 2; ++ks)
    poff[ks] = l4 * 128 + (((ks * 64 + lh * 16)) ^ ((l4 & 7) << 4));
  int pwoff[4];
#pragma unroll
  for (int nb = 0; nb < 4; ++nb)
    pwoff[nb] = l4 * 128 + (((lh * 8 + nb * 32)) ^ ((l4 & 7) << 4));

  const float slope2 = exp2f(-0.5f * (float)(h + 1)) * 1.44269504088896f;
  const float scale2 = 0.125f * 1.44269504088896f;
  const int ibase = lh * 4 - (qt * 64 + wid * 16 + l4);
  float bc[4][4];
#pragma unroll
  for (int nb = 0; nb < 4; ++nb)
#pragma unroll
    for (int r = 0; r < 4; ++r)
      bc[nb][r] = slope2 * (float)(ibase + 16 * nb + r);

  int nt = (int)ceilf(40.0f / (64.0f * slope2)) + 1;
  if (nt > 32) nt = 32;
  const int nsp = (nt + 11) / 12;
  const int ktmin = 32 - nt;
  const int hi = 31 - j * 12;
  int lo = hi - 11;
  if (lo < ktmin) lo = ktmin;

  float m = -1e30f;
  f32x4 lacc = (f32x4){0.f, 0.f, 0.f, 0.f};
  f32x4 accO[4];
#pragma unroll
  for (int nd = 0; nd < 4; ++nd) accO[nd] = (f32x4){0.f, 0.f, 0.f, 0.f};
  const short8 vones = {(short)0x3F80, (short)0x3F80, (short)0x3F80, (short)0x3F80,
                        (short)0x3F80, (short)0x3F80, (short)0x3F80, (short)0x3F80};

  const int srow = tid >> 3;
  const int sc8 = (tid & 7) * 8;
  const int swo = srow * 128 + ((sc8 * 2) ^ ((srow & 7) << 4));
  short8 kreg[2], vreg[2];
#define STAGE_LOAD(KT)                                                              \
  {                                                                                 \
    kreg[0] = *(const short8*)(kbase + (size_t)((KT)*64 + srow) * RS + sc8);        \
    kreg[1] = *(const short8*)(kbase + (size_t)((KT)*64 + srow + 32) * RS + sc8);   \
    vreg[0] = *(const short8*)(vtb + (size_t)srow * S_LEN + (KT)*64 + sc8);         \
    vreg[1] = *(const short8*)(vtb + (size_t)(srow + 32) * S_LEN + (KT)*64 + sc8);  \
  }
#define STAGE_WRITE(B)                                   \
  {                                                      \
    *(short8*)((char*)Kt[B] + swo) = kreg[0];            \
    *(short8*)((char*)Kt[B] + swo + 4096) = kreg[1];     \
    *(short8*)((char*)Vt[B] + swo) = vreg[0];            \
    *(short8*)((char*)Vt[B] + swo + 4096) = vreg[1];     \
  }

  STAGE_LOAD(hi);
  STAGE_WRITE(0);
  __syncthreads();
  int cur = 0;
  float ktoff = slope2 * 64.0f * (float)hi;
  const float dko = slope2 * 64.0f;

  for (int kt = hi; kt >= lo; --kt) {
    if (kt > lo) STAGE_LOAD(kt - 1);
    const char* Kc = (const char*)Kt[cur];
    const char* Vc = (const char*)Vt[cur];

    f32x4 sacc[4];
#pragma unroll
    for (int nb = 0; nb < 4; ++nb) sacc[nb] = (f32x4){0.f, 0.f, 0.f, 0.f};
    __builtin_amdgcn_s_setprio(1);
#pragma unroll
    for (int ks = 0; ks < 2; ++ks)
#pragma unroll
      for (int nb = 0; nb < 4; ++nb) {
        short8 kf = *(const short8*)(Kc + koff[nb][ks]);
        sacc[nb] = __builtin_amdgcn_mfma_f32_16x16x32_bf16(kf, qf[ks], sacc[nb], 0, 0, 0);
      }
    __builtin_amdgcn_s_setprio(0);

    float p[4][4];
#pragma unroll
    for (int nb = 0; nb < 4; ++nb)
#pragma unroll
      for (int r = 0; r < 4; ++r)
        p[nb][r] = fmaf(sacc[nb][r], scale2, bc[nb][r]);

    float mx0 = fmaxf(fmaxf(p[0][0], p[0][1]), fmaxf(p[0][2], p[0][3]));
    float mx1 = fmaxf(fmaxf(p[1][0], p[1][1]), fmaxf(p[1][2], p[1][3]));
    float mx2 = fmaxf(fmaxf(p[2][0], p[2][1]), fmaxf(p[2][2], p[2][3]));
    float mx3 = fmaxf(fmaxf(p[3][0], p[3][1]), fmaxf(p[3][2], p[3][3]));
    float tm = fmaxf(fmaxf(mx0, mx1), fmaxf(mx2, mx3));
    tm = fmaxf(tm, __shfl_xor(tm, 16));
    tm = fmaxf(tm, __shfl_xor(tm, 32));

    float mm = m - ktoff;
    if (__any(tm > mm)) {
      float mn = fmaxf(mm, tm);
      float corr = exp2f(mm - mn);
      m = mn + ktoff;
      mm = mn;
      float cb[4];
#pragma unroll
      for (int r = 0; r < 4; ++r)
        cb[r] = __shfl(corr, (lane & 48) | (lh * 4 + r));
#pragma unroll
      for (int nd = 0; nd < 4; ++nd)
#pragma unroll
        for (int r = 0; r < 4; ++r) accO[nd][r] *= cb[r];
#pragma unroll
      for (int r = 0; r < 4; ++r) lacc[r] *= cb[r];
    }

#pragma unroll
    for (int nb = 0; nb < 4; ++nb)
#pragma unroll
      for (int r = 0; r < 4; ++r) p[nb][r] = exp2f(p[nb][r] - mm);

#pragma unroll
    for (int nb = 0; nb < 4; ++nb) {
      uint32_t w0 = pack_bf2(p[nb][0], p[nb][1]);
      uint32_t w1 = pack_bf2(p[nb][2], p[nb][3]);
      *(uint2*)(PtW + pwoff[nb]) = make_uint2(w0, w1);
    }
    asm volatile("s_waitcnt lgkmcnt(0)" ::: "memory");

    __builtin_amdgcn_s_setprio(1);
#pragma unroll
    for (int ks = 0; ks < 2; ++ks) {
      short8 pf = *(const short8*)(PtW + poff[ks]);
      lacc = __builtin_amdgcn_mfma_f32_16x16x32_bf16(pf, vones, lacc, 0, 0, 0);
#pragma unroll
      for (int nd = 0; nd < 4; ++nd) {
        short8 vf = *(const short8*)(Vc + koff[nd][ks]);
        accO[nd] = __builtin_amdgcn_mfma_f32_16x16x32_bf16(pf, vf, accO[nd], 0, 0, 0);
      }
    }
    __builtin_amdgcn_s_setprio(0);

    if (kt > lo) STAGE_WRITE(cur ^ 1);
    __syncthreads();
    cur ^= 1;
    ktoff -= dko;
  }

  if (nsp == 1) {
    float ib[4];
#pragma unroll
    for (int r = 0; r < 4; ++r) ib[r] = 1.0f / lacc[r];
    u16* aop = ao + ((size_t)(b * S_LEN + qt * 64 + wid * 16 + lh * 4)) * D_DIM + h * HDIM;
#pragma unroll
    for (int nd = 0; nd < 4; ++nd)
#pragma unroll
      for (int r = 0; r < 4; ++r)
        aop[(size_t)r * D_DIM + nd * 16 + l4] = f2bf(accO[nd][r] * ib[r]);
  } else {
    const int sbase = (h <= 10) ? (h - 9) * 2 : 4 + (h - 11) * 3;
    const int pidx = sub * 19 + sbase + j;
    float* Op = pO + (size_t)pidx * 4096;
#pragma unroll
    for (int nd = 0; nd < 4; ++nd)
#pragma unroll
      for (int r = 0; r < 4; ++r)
        Op[(wid * 16 + lh * 4 + r) * 64 + nd * 16 + l4] = accO[nd][r];
    float mq[4];
#pragma unroll
    for (int r = 0; r < 4; ++r)
      mq[r] = __shfl(m, (lane & 48) | (lh * 4 + r));
    if (l4 == 0) {
      float* mlp = pML + (size_t)pidx * 128 + (wid * 16 + lh * 4) * 2;
#pragma unroll
      for (int r = 0; r < 4; ++r) {
        mlp[r * 2] = mq[r];
        mlp[r * 2 + 1] = lacc[r];
      }
    }
  }
#undef STAGE_LOAD
#undef STAGE_WRITE
}

// ---------------- combine partials for split heads (h>=9) ----------------
__global__ __launch_bounds__(256) void attn_combine(const float* __restrict__ pO,
                                                    const float* __restrict__ pML,
                                                    u16* __restrict__ ao) {
  const int g = blockIdx.x;        // 448 = 64 subs x 7 heads
  const int sub = g & 63;
  const int h = 9 + (g >> 6);
  const int b = sub >> 5, qt = sub & 31;
  const int nsp = (h <= 10) ? 2 : 3;
  const int sbase = (h <= 10) ? (h - 9) * 2 : 4 + (h - 11) * 3;
  const int pidx0 = sub * 19 + sbase;
  const int tid = threadIdx.x;
  const int row = tid >> 2;
  const int d0 = (tid & 3) * 16;

  float mj[3], lj[3];
#pragma unroll
  for (int k = 0; k < 3; ++k) { mj[k] = -1e30f; lj[k] = 0.f; }
  for (int k = 0; k < nsp; ++k) {
    mj[k] = pML[(size_t)(pidx0 + k) * 128 + row * 2];
    lj[k] = pML[(size_t)(pidx0 + k) * 128 + row * 2 + 1];
  }
  float ms = fmaxf(mj[0], fmaxf(mj[1], mj[2]));
  float w[3];
  float lsum = 0.f;
#pragma unroll
  for (int k = 0; k < 3; ++k) {
    w[k] = exp2f(mj[k] - ms);
    lsum += w[k] * lj[k];
  }
  float inv = 1.0f / lsum;

  u16* aop = ao + ((size_t)(b * S_LEN + qt * 64 + row)) * D_DIM + h * HDIM + d0;
#pragma unroll
  for (int c = 0; c < 4; ++c) {
    float4 o = {0.f, 0.f, 0.f, 0.f};
    for (int k = 0; k < nsp; ++k) {
      const float4 v = *(const float4*)(pO + (size_t)(pidx0 + k) * 4096 + row * 64 + d0 + c * 4);
      o.x += w[k] * v.x; o.y += w[k] * v.y; o.z += w[k] * v.z; o.w += w[k] * v.w;
    }
    ushort4 u4 = make_ushort4(f2bf(o.x * inv), f2bf(o.y * inv), f2bf(o.z * inv), f2bf(o.w * inv));
    *(ushort4*)(aop + c * 4) = u4;
  }
}

extern "C" void kernel_launch(void* const* d_in, const int* in_sizes, int n_in,
                              void* d_out, int out_size, void* d_ws, size_t ws_size,
                              hipStream_t stream) {
  const float* x   = (const float*)d_in[0];
  const float* Wq  = (const float*)d_in[1];
  const float* Wk  = (const float*)d_in[2];
  const float* Wv  = (const float*)d_in[3];
  const float* Wo  = (const float*)d_in[4];
  const float* bo  = (const float*)d_in[5];
  const float* W1  = (const float*)d_in[6];
  const float* b1  = (const float*)d_in[7];
  const float* W2  = (const float*)d_in[8];
  const float* b2  = (const float*)d_in[9];
  const float* g1  = (const float*)d_in[10];
  const float* be1 = (const float*)d_in[11];
  const float* g2  = (const float*)d_in[12];
  const float* be2 = (const float*)d_in[13];

  char* p = (char*)d_ws;
  u16* wqkv = (u16*)p; p += (size_t)3072 * 1024 * 2;
  u16* wo   = (u16*)p; p += (size_t)1024 * 1024 * 2;
  u16* w1   = (u16*)p; p += (size_t)4096 * 1024 * 2;
  u16* w2   = (u16*)p; p += (size_t)4096 * 1024 * 2;
  u16* hb   = (u16*)p; p += (size_t)4096 * 1024 * 2;
  u16* qkvb = (u16*)p; p += (size_t)4096 * 3072 * 2;
  u16* aob  = (u16*)p; p += (size_t)4096 * 1024 * 2;
  float* x1 = (float*)p; p += (size_t)4096 * 1024 * 4;
  u16* h2b  = (u16*)p; p += (size_t)4096 * 1024 * 2;
  u16* ff1  = (u16*)p; p += (size_t)4096 * 4096 * 2;
  u16* vt   = ff1;                                        // 8MB, dead before FFN1
  float* pO = (float*)(ff1 + (size_t)4 * 1024 * 1024);    // partial O (inside ff1, dead before FFN1)
  float* pML = pO + (size_t)1216 * 4096;                  // partial m,l
  float* pk = (float*)hb;                                 // FFN2 split-K partials (hb+qkvb, 32MB)

  cast_all<<<12288, 256, 0, stream>>>(Wq, Wk, Wv, Wo, W1, W2, wqkv, wo, w1, w2);

  ln_kernel<<<4096, 256, 0, stream>>>(x, g1, be1, hb);
  gemm_bt2<0><<<16 * 12, 512, 0, stream>>>(hb, wqkv, qkvb, nullptr, 4096, 3072, 1024);
  transpose_v<<<256, 256, 0, stream>>>(qkvb, vt);
  attn_kernel<<<1792, 256, 0, stream>>>(qkvb, vt, aob, pO, pML);
  attn_combine<<<448, 256, 0, stream>>>(pO, pML, aob);
  gemm_bt<1><<<32 * 8, 256, 0, stream>>>(aob, wo, x1, bo, x, 4096, 1024, 1024, 1);
  ln_kernel<<<4096, 256, 0, stream>>>(x1, g2, be2, h2b);
  gemm_bt2<2><<<16 * 16, 512, 0, stream>>>(h2b, w1, ff1, b1, 4096, 4096, 1024);
  // FFN2: 256x128 deep-pipe, split-K=2 -> f32 partials -> fused reduce
  gemm_bt3<3><<<2 * 16 * 8, 512, 0, stream>>>(ff1, w2, pk, nullptr, nullptr, 4096, 1024, 4096, 2);
  reduce2_kernel<<<2048, 256, 0, stream>>>(pk, pk + (size_t)4096 * 1024, x1, b2, (float*)d_out);
}

// Round 10
// 229.925 us; speedup vs baseline: 1.8210x; 1.0207x over previous
//
#include <hip/hip_runtime.h>
#include <hip/hip_bf16.h>
#include <stdint.h>

typedef unsigned short u16;
typedef __attribute__((ext_vector_type(8))) short short8;
typedef __attribute__((ext_vector_type(4))) float f32x4;

#define S_LEN 2048
#define D_DIM 1024
#define NHEAD 16
#define HDIM 64
#define NROWS 4096

__device__ __forceinline__ u16 f2bf(float f) {
  union { float f; uint32_t u; } c; c.f = f;
  uint32_t r = (c.u + 0x7fffu + ((c.u >> 16) & 1u)) >> 16;
  return (u16)r;
}

__device__ __forceinline__ float bf2f(u16 v) {
  union { uint32_t u; float f; } c; c.u = ((uint32_t)v) << 16;
  return c.f;
}

__device__ __forceinline__ uint32_t pack_bf2(float a, float b) {
  __hip_bfloat162 h = __float22bfloat162_rn(float2{a, b});
  union { __hip_bfloat162 h; uint32_t u; } c; c.h = h;
  return c.u;
}

__device__ __forceinline__ void gload_lds16(const void* g, void* l) {
  typedef const __attribute__((address_space(1))) unsigned int gq_t;
  typedef __attribute__((address_space(3))) unsigned int lq_t;
  __builtin_amdgcn_global_load_lds((gq_t*)(uintptr_t)g,
                                   (lq_t*)(uint32_t)(uintptr_t)l, 16, 0, 0);
}

// ---------------- all weight casts fused (fp32 -> bf16) ----------------
__global__ __launch_bounds__(256) void cast_all(const float* __restrict__ Wq,
                                                const float* __restrict__ Wk,
                                                const float* __restrict__ Wv,
                                                const float* __restrict__ Wo,
                                                const float* __restrict__ W1,
                                                const float* __restrict__ W2,
                                                u16* __restrict__ wqkv,
                                                u16* __restrict__ wo,
                                                u16* __restrict__ w1,
                                                u16* __restrict__ w2) {
  int i = blockIdx.x * 256 + threadIdx.x;  // 0..3145727
  const float* src;
  u16* dst;
  int rel;
  if (i < 786432) {
    int ws = i / 262144;
    rel = i - ws * 262144;
    src = (ws == 0) ? Wq : ((ws == 1) ? Wk : Wv);
    dst = wqkv + (size_t)ws * 1048576;
  } else if (i < 1048576) {
    rel = i - 786432; src = Wo; dst = wo;
  } else if (i < 2097152) {
    rel = i - 1048576; src = W1; dst = w1;
  } else {
    rel = i - 2097152; src = W2; dst = w2;
  }
  float4 v = ((const float4*)src)[rel];
  ((ushort4*)dst)[rel] = make_ushort4(f2bf(v.x), f2bf(v.y), f2bf(v.z), f2bf(v.w));
}

// ---------------- LayerNorm fp32 -> bf16 ----------------
__global__ __launch_bounds__(256) void ln_kernel(const float* __restrict__ x,
                                                 const float* __restrict__ g,
                                                 const float* __restrict__ be,
                                                 u16* __restrict__ out) {
  int row = blockIdx.x;
  int tid = threadIdx.x;
  const float4 v = ((const float4*)(x + (size_t)row * D_DIM))[tid];
  float s = v.x + v.y + v.z + v.w;
  float s2 = v.x * v.x + v.y * v.y + v.z * v.z + v.w * v.w;
#pragma unroll
  for (int off = 1; off < 64; off <<= 1) {
    s += __shfl_xor(s, off);
    s2 += __shfl_xor(s2, off);
  }
  __shared__ float ss[4], ss2[4];
  if ((tid & 63) == 0) { ss[tid >> 6] = s; ss2[tid >> 6] = s2; }
  __syncthreads();
  s = ss[0] + ss[1] + ss[2] + ss[3];
  s2 = ss2[0] + ss2[1] + ss2[2] + ss2[3];
  float mu = s * (1.0f / D_DIM);
  float var = s2 * (1.0f / D_DIM) - mu * mu;
  float rs = rsqrtf(var + 1e-5f);
  float4 gv = ((const float4*)g)[tid];
  float4 bv = ((const float4*)be)[tid];
  ushort4 o = make_ushort4(f2bf((v.x - mu) * rs * gv.x + bv.x),
                           f2bf((v.y - mu) * rs * gv.y + bv.y),
                           f2bf((v.z - mu) * rs * gv.z + bv.z),
                           f2bf((v.w - mu) * rs * gv.w + bv.w));
  ((ushort4*)(out + (size_t)row * D_DIM))[tid] = o;
}

// ====== 256x256 BK=32 deep-pipe NT GEMM (QKV / FFN1) ======
template <int EPI>
__global__ __launch_bounds__(512, 2) void gemm_bt2(const u16* __restrict__ A,
                                                   const u16* __restrict__ Bw,
                                                   void* __restrict__ Cout,
                                                   const float* __restrict__ bias,
                                                   int M, int N, int K) {
  __shared__ u16 lsA[2][256 * 32];
  __shared__ u16 lsB[2][256 * 32];
  const int tid = threadIdx.x;
  const int wid = tid >> 6, lane = tid & 63;
  const int l4 = lane & 15, lh = lane >> 4;
  const int wr = wid >> 2, wc = wid & 3;
  const int nbn = N >> 8;
  const int nwg = (M >> 8) * nbn;
  const int t0 = (blockIdx.x & 7) * (nwg >> 3) + (blockIdx.x >> 3);
  const int bm = t0 / nbn, bn = t0 % nbn;

  f32x4 acc[8][4];
#pragma unroll
  for (int i = 0; i < 8; ++i)
#pragma unroll
    for (int j = 0; j < 4; ++j) acc[i][j] = (f32x4){0.f, 0.f, 0.f, 0.f};

  const int srow = lane >> 2;
  const int sblk = (lane & 3) ^ ((lane >> 3) & 3);
  const u16* Abase = A + ((size_t)bm * 256 + wid * 32 + srow) * K + sblk * 8;
  const u16* Bbase = Bw + ((size_t)bn * 256 + wid * 32 + srow) * K + sblk * 8;
  const size_t r16 = (size_t)16 * K;
#define STAGE(BUF, KT)                                              \
  {                                                                 \
    int ko = (KT) * 32;                                             \
    gload_lds16(Abase + ko, (char*)lsA[BUF] + wid * 2048);          \
    gload_lds16(Abase + r16 + ko, (char*)lsA[BUF] + wid * 2048 + 1024); \
    gload_lds16(Bbase + ko, (char*)lsB[BUF] + wid * 2048);          \
    gload_lds16(Bbase + r16 + ko, (char*)lsB[BUF] + wid * 2048 + 1024); \
  }

  const int swz = (lh ^ ((l4 >> 1) & 3)) << 4;
  int aoff[8], boff[4];
#pragma unroll
  for (int m = 0; m < 8; ++m) aoff[m] = (wr * 128 + m * 16 + l4) * 64 + swz;
#pragma unroll
  for (int n = 0; n < 4; ++n) boff[n] = (wc * 64 + n * 16 + l4) * 64 + swz;

  STAGE(0, 0);
  __syncthreads();
  int cur = 0;
  const int NT = K >> 5;

  for (int t = 0; t < NT; ++t) {
    if (t + 1 < NT) STAGE(cur ^ 1, t + 1);
    const char* La = (const char*)lsA[cur];
    const char* Lb = (const char*)lsB[cur];
    short8 aF[4], bF[4], aG[4];
#pragma unroll
    for (int m = 0; m < 4; ++m) aF[m] = *(const short8*)(La + aoff[m]);
#pragma unroll
    for (int n = 0; n < 4; ++n) bF[n] = *(const short8*)(Lb + boff[n]);
    __builtin_amdgcn_s_setprio(1);
#pragma unroll
    for (int m = 0; m < 4; ++m)
#pragma unroll
      for (int n = 0; n < 4; ++n)
        acc[m][n] = __builtin_amdgcn_mfma_f32_16x16x32_bf16(aF[m], bF[n], acc[m][n], 0, 0, 0);
    __builtin_amdgcn_s_setprio(0);
#pragma unroll
    for (int m = 0; m < 4; ++m) aG[m] = *(const short8*)(La + aoff[m + 4]);
    __builtin_amdgcn_s_setprio(1);
#pragma unroll
    for (int m = 0; m < 4; ++m)
#pragma unroll
      for (int n = 0; n < 4; ++n)
        acc[m + 4][n] = __builtin_amdgcn_mfma_f32_16x16x32_bf16(aG[m], bF[n], acc[m + 4][n], 0, 0, 0);
    __builtin_amdgcn_s_setprio(0);
    if (t + 1 < NT) __syncthreads();
    cur ^= 1;
  }

  const int row0 = bm * 256 + wr * 128 + lh * 4;
  const int col0 = bn * 256 + wc * 64 + l4;
#pragma unroll
  for (int m = 0; m < 8; ++m) {
#pragma unroll
    for (int n = 0; n < 4; ++n) {
      int col = col0 + n * 16;
#pragma unroll
      for (int r = 0; r < 4; ++r) {
        size_t idx = (size_t)(row0 + m * 16 + r) * N + col;
        float v = acc[m][n][r];
        if (EPI == 0) {
          ((u16*)Cout)[idx] = f2bf(v);
        } else {
          v += bias[col];
          ((u16*)Cout)[idx] = f2bf(v > 0.f ? v : 0.f);
        }
      }
    }
  }
#undef STAGE
}

// ====== 512x128 BK=32 deep-pipe NT GEMM (FFN2 split-K, bf16 partials) ======
// 8 waves as 4Mx2N, per-wave 128x64 out (same 32 MFMA : 12 ds_read rhythm as
// gemm_bt2). LDS 80KB double-buffered. Partials written as bf16.
__global__ __launch_bounds__(512, 2) void gemm_bt4(const u16* __restrict__ A,
                                                   const u16* __restrict__ Bw,
                                                   u16* __restrict__ Cpk,
                                                   int M, int N, int K, int ksl) {
  __shared__ u16 lsA[2][512 * 32];
  __shared__ u16 lsB[2][128 * 32];
  const int tid = threadIdx.x;
  const int wid = tid >> 6, lane = tid & 63;
  const int l4 = lane & 15, lh = lane >> 4;
  const int wr = wid >> 1, wc = wid & 1;
  const int nbn = N >> 7;
  const int nwgs = (M >> 9) * nbn;
  const int slice = blockIdx.x / nwgs;
  const int id0 = blockIdx.x % nwgs;
  const int t0 = (id0 & 7) * (nwgs >> 3) + (id0 >> 3);
  const int bm = t0 / nbn, bn = t0 % nbn;
  const int Ks = K / ksl;

  f32x4 acc[8][4];
#pragma unroll
  for (int i = 0; i < 8; ++i)
#pragma unroll
    for (int j = 0; j < 4; ++j) acc[i][j] = (f32x4){0.f, 0.f, 0.f, 0.f};

  const int srow = lane >> 2;
  const int sblk = (lane & 3) ^ ((lane >> 3) & 3);
  const u16* Abase = A + ((size_t)bm * 512 + wid * 64 + srow) * K + (size_t)slice * Ks + sblk * 8;
  const u16* Bbase = Bw + ((size_t)bn * 128 + wid * 16 + srow) * K + (size_t)slice * Ks + sblk * 8;
  const size_t r16 = (size_t)16 * K;
#define STAGE(BUF, KT)                                                   \
  {                                                                      \
    int ko = (KT) * 32;                                                  \
    gload_lds16(Abase + ko, (char*)lsA[BUF] + wid * 4096);               \
    gload_lds16(Abase + r16 + ko, (char*)lsA[BUF] + wid * 4096 + 1024);  \
    gload_lds16(Abase + 2 * r16 + ko, (char*)lsA[BUF] + wid * 4096 + 2048); \
    gload_lds16(Abase + 3 * r16 + ko, (char*)lsA[BUF] + wid * 4096 + 3072); \
    gload_lds16(Bbase + ko, (char*)lsB[BUF] + wid * 1024);               \
  }

  const int swz = (lh ^ ((l4 >> 1) & 3)) << 4;
  int aoff[8], boff[4];
#pragma unroll
  for (int m = 0; m < 8; ++m) aoff[m] = (wr * 128 + m * 16 + l4) * 64 + swz;
#pragma unroll
  for (int n = 0; n < 4; ++n) boff[n] = (wc * 64 + n * 16 + l4) * 64 + swz;

  STAGE(0, 0);
  __syncthreads();
  int cur = 0;
  const int NT = Ks >> 5;

  for (int t = 0; t < NT; ++t) {
    if (t + 1 < NT) STAGE(cur ^ 1, t + 1);
    const char* La = (const char*)lsA[cur];
    const char* Lb = (const char*)lsB[cur];
    short8 aF[4], bF[4], aG[4];
#pragma unroll
    for (int m = 0; m < 4; ++m) aF[m] = *(const short8*)(La + aoff[m]);
#pragma unroll
    for (int n = 0; n < 4; ++n) bF[n] = *(const short8*)(Lb + boff[n]);
    __builtin_amdgcn_s_setprio(1);
#pragma unroll
    for (int m = 0; m < 4; ++m)
#pragma unroll
      for (int n = 0; n < 4; ++n)
        acc[m][n] = __builtin_amdgcn_mfma_f32_16x16x32_bf16(aF[m], bF[n], acc[m][n], 0, 0, 0);
    __builtin_amdgcn_s_setprio(0);
#pragma unroll
    for (int m = 0; m < 4; ++m) aG[m] = *(const short8*)(La + aoff[m + 4]);
    __builtin_amdgcn_s_setprio(1);
#pragma unroll
    for (int m = 0; m < 4; ++m)
#pragma unroll
      for (int n = 0; n < 4; ++n)
        acc[m + 4][n] = __builtin_amdgcn_mfma_f32_16x16x32_bf16(aG[m], bF[n], acc[m + 4][n], 0, 0, 0);
    __builtin_amdgcn_s_setprio(0);
    if (t + 1 < NT) __syncthreads();
    cur ^= 1;
  }

  const int row0 = bm * 512 + wr * 128 + lh * 4;
  const int col0 = bn * 128 + wc * 64 + l4;
  u16* Cp = Cpk + (size_t)slice * M * N;
#pragma unroll
  for (int m = 0; m < 8; ++m) {
#pragma unroll
    for (int n = 0; n < 4; ++n) {
      int col = col0 + n * 16;
#pragma unroll
      for (int r = 0; r < 4; ++r) {
        size_t idx = (size_t)(row0 + m * 16 + r) * N + col;
        Cp[idx] = f2bf(acc[m][n][r]);
      }
    }
  }
#undef STAGE
}

// ---------------- 128x128 NT GEMM (O-proj) ----------
template <int EPI>
__global__ __launch_bounds__(256) void gemm_bt(const u16* __restrict__ A,
                                               const u16* __restrict__ Bw,
                                               void* __restrict__ Cout,
                                               const float* __restrict__ bias,
                                               const float* __restrict__ resid,
                                               int M, int N, int K, int ksl) {
  __shared__ u16 lsA[128 * 64];
  __shared__ u16 lsB[128 * 64];
  const int tid = threadIdx.x;
  const int wid = tid >> 6, lane = tid & 63;
  const int l4 = lane & 15, lh = lane >> 4;
  const int nbn = N >> 7;
  const int nwgs = (M >> 7) * nbn;
  const int slice = blockIdx.x / nwgs;
  const int id0 = blockIdx.x % nwgs;
  const int t = (id0 & 7) * (nwgs >> 3) + (id0 >> 3);
  const int bm = t / nbn, bn = t % nbn;
  const int wr = wid >> 1, wc = wid & 1;
  const int Ks = K / ksl;

  f32x4 acc[4][4];
#pragma unroll
  for (int i = 0; i < 4; ++i)
#pragma unroll
    for (int j = 0; j < 4; ++j) acc[i][j] = (f32x4){0.f, 0.f, 0.f, 0.f};

  const u16* Ab = A + (size_t)bm * 128 * K + (size_t)slice * Ks;
  const u16* Bb = Bw + (size_t)bn * 128 * K + (size_t)slice * Ks;
  const int srow = (lane >> 3);
  const int scol = (lane & 7) * 8;

  for (int k0 = 0; k0 < Ks; k0 += 64) {
#pragma unroll
    for (int c = 0; c < 4; ++c) {
      int ch = wid * 4 + c;
      int row = ch * 8 + srow;
      gload_lds16(Ab + (size_t)row * K + k0 + scol, &lsA[ch * 512]);
      gload_lds16(Bb + (size_t)row * K + k0 + scol, &lsB[ch * 512]);
    }
    __syncthreads();
#pragma unroll
    for (int ks = 0; ks < 2; ++ks) {
      short8 af[4], bf[4];
#pragma unroll
      for (int i = 0; i < 4; ++i) {
        af[i] = *(const short8*)&lsA[(wr * 64 + i * 16 + l4) * 64 + ks * 32 + lh * 8];
        bf[i] = *(const short8*)&lsB[(wc * 64 + i * 16 + l4) * 64 + ks * 32 + lh * 8];
      }
#pragma unroll
      for (int i = 0; i < 4; ++i)
#pragma unroll
        for (int j = 0; j < 4; ++j)
          acc[i][j] = __builtin_amdgcn_mfma_f32_16x16x32_bf16(af[i], bf[j], acc[i][j], 0, 0, 0);
    }
    __syncthreads();
  }

  const int row0 = bm * 128 + wr * 64;
  const int col0 = bn * 128 + wc * 64;
  float* Cp = (float*)Cout + (size_t)slice * M * N;
#pragma unroll
  for (int i = 0; i < 4; ++i) {
#pragma unroll
    for (int j = 0; j < 4; ++j) {
      int col = col0 + j * 16 + l4;
#pragma unroll
      for (int r = 0; r < 4; ++r) {
        int row = row0 + i * 16 + lh * 4 + r;
        size_t idx = (size_t)row * N + col;
        float v = acc[i][j][r];
        if (EPI == 1) {
          ((float*)Cout)[idx] = v + bias[col] + resid[idx];
        } else {
          Cp[idx] = v;
        }
      }
    }
  }
}

// ------- split-K=4 reduce: out = sum(bf16 partials) + bias + resid -------
__global__ __launch_bounds__(256) void reduce4_kernel(const u16* __restrict__ pk,
                                                      const float* __restrict__ resid,
                                                      const float* __restrict__ bias,
                                                      float* __restrict__ out) {
  const size_t SL = (size_t)NROWS * D_DIM;
  int i = blockIdx.x * 256 + threadIdx.x;  // x8 elements
  short8 p0 = *(const short8*)(pk + (size_t)i * 8);
  short8 p1 = *(const short8*)(pk + SL + (size_t)i * 8);
  short8 p2 = *(const short8*)(pk + 2 * SL + (size_t)i * 8);
  short8 p3 = *(const short8*)(pk + 3 * SL + (size_t)i * 8);
  int col = (i * 8) & (D_DIM - 1);
  float4 b0 = *(const float4*)(bias + col);
  float4 b1 = *(const float4*)(bias + col + 4);
  float4 r0 = ((const float4*)resid)[i * 2];
  float4 r1 = ((const float4*)resid)[i * 2 + 1];
  float o[8];
#pragma unroll
  for (int j = 0; j < 8; ++j)
    o[j] = bf2f((u16)p0[j]) + bf2f((u16)p1[j]) + bf2f((u16)p2[j]) + bf2f((u16)p3[j]);
  float4 w0 = {o[0] + b0.x + r0.x, o[1] + b0.y + r0.y, o[2] + b0.z + r0.z, o[3] + b0.w + r0.w};
  float4 w1 = {o[4] + b1.x + r1.x, o[5] + b1.y + r1.y, o[6] + b1.z + r1.z, o[7] + b1.w + r1.w};
  ((float4*)out)[i * 2] = w0;
  ((float4*)out)[i * 2 + 1] = w1;
}

// ---------------- V transpose ----------------
__global__ __launch_bounds__(256) void transpose_v(const u16* __restrict__ qkv,
                                                   u16* __restrict__ vt) {
  const int gw = blockIdx.x * 4 + (threadIdx.x >> 6);
  const int lane = threadIdx.x & 63;
  const int bh = gw >> 5;
  const int st = gw & 31;
  const int b = bh >> 4, h = bh & 15;
  const u16* src = qkv + (size_t)(b * S_LEN + st * 64) * 3072 + 2048 + h * 64 + lane;
  short8 acc8[8];
#pragma unroll
  for (int o = 0; o < 8; ++o)
#pragma unroll
    for (int i = 0; i < 8; ++i)
      acc8[o][i] = (short)src[(size_t)(o * 8 + i) * 3072];
  u16* dst = vt + ((size_t)bh * 64 + lane) * S_LEN + st * 64;
#pragma unroll
  for (int o = 0; o < 8; ++o) *(short8*)(dst + o * 8) = acc8[o];
}

// ---------------- Flash attention with ALiBi (KV-split flash-decode) --------
__global__ __launch_bounds__(256, 4) void attn_kernel(const u16* __restrict__ qkv,
                                                      const u16* __restrict__ vt,
                                                      u16* __restrict__ ao,
                                                      float* __restrict__ pO,
                                                      float* __restrict__ pML) {
  const int id = blockIdx.x;
  const int sub = id & 63;   // (b,qt)
  const int ugrp = id >> 6;  // 0..27
  int h, j;
  if (ugrp < 15) { h = 15 - ugrp / 3; j = ugrp % 3; }
  else if (ugrp < 19) { h = 10 - ((ugrp - 15) >> 1); j = (ugrp - 15) & 1; }
  else { h = 27 - ugrp; j = 0; }
  const int b = sub >> 5, qt = sub & 31;
  const int bh = b * 16 + h;
  const int tid = threadIdx.x;
  const int wid = tid >> 6, lane = tid & 63;
  const int l4 = lane & 15, lh = lane >> 4;

  __shared__ u16 Kt[2][64 * 64];
  __shared__ u16 Vt[2][64 * 64];
  __shared__ u16 Pt[4][16 * 64];

  const size_t RS = 3 * D_DIM;
  const u16* base = qkv + (size_t)b * S_LEN * RS + h * HDIM;
  const u16* kbase = base + D_DIM;
  const u16* vtb = vt + (size_t)bh * HDIM * S_LEN;
  char* PtW = (char*)Pt[wid];

  short8 qf[2];
  {
    const u16* qp = base + (size_t)(qt * 64 + wid * 16 + l4) * RS + lh * 8;
    qf[0] = *(const short8*)qp;
    qf[1] = *(const short8*)(qp + 32);
  }

  int koff[4][2];
#pragma unroll
  for (int nb = 0; nb < 4; ++nb)
#pragma unroll
    for (int ks = 0; ks < 2; ++ks) {
      int row = nb * 16 + l4;
      koff[nb][ks] = row * 128 + (((ks * 32 + lh * 8) * 2) ^ ((row & 7) << 4));
    }
  int poff[2];
#pragma unroll
  for (int ks = 0; ks < 2; ++ks)
    poff[ks] = l4 * 128 + (((ks * 64 + lh * 16)) ^ ((l4 & 7) << 4));
  int pwoff[4];
#pragma unroll
  for (int nb = 0; nb < 4; ++nb)
    pwoff[nb] = l4 * 128 + (((lh * 8 + nb * 32)) ^ ((l4 & 7) << 4));

  const float slope2 = exp2f(-0.5f * (float)(h + 1)) * 1.44269504088896f;
  const float scale2 = 0.125f * 1.44269504088896f;
  const int ibase = lh * 4 - (qt * 64 + wid * 16 + l4);
  float bc[4][4];
#pragma unroll
  for (int nb = 0; nb < 4; ++nb)
#pragma unroll
    for (int r = 0; r < 4; ++r)
      bc[nb][r] = slope2 * (float)(ibase + 16 * nb + r);

  int nt = (int)ceilf(40.0f / (64.0f * slope2)) + 1;
  if (nt > 32) nt = 32;
  const int nsp = (nt + 11) / 12;
  const int ktmin = 32 - nt;
  const int hi = 31 - j * 12;
  int lo = hi - 11;
  if (lo < ktmin) lo = ktmin;

  float m = -1e30f;
  f32x4 lacc = (f32x4){0.f, 0.f, 0.f, 0.f};
  f32x4 accO[4];
#pragma unroll
  for (int nd = 0; nd < 4; ++nd) accO[nd] = (f32x4){0.f, 0.f, 0.f, 0.f};
  const short8 vones = {(short)0x3F80, (short)0x3F80, (short)0x3F80, (short)0x3F80,
                        (short)0x3F80, (short)0x3F80, (short)0x3F80, (short)0x3F80};

  const int srow = tid >> 3;
  const int sc8 = (tid & 7) * 8;
  const int swo = srow * 128 + ((sc8 * 2) ^ ((srow & 7) << 4));
  short8 kreg[2], vreg[2];
#define STAGE_LOAD(KT)                                                              \
  {                                                                                 \
    kreg[0] = *(const short8*)(kbase + (size_t)((KT)*64 + srow) * RS + sc8);        \
    kreg[1] = *(const short8*)(kbase + (size_t)((KT)*64 + srow + 32) * RS + sc8);   \
    vreg[0] = *(const short8*)(vtb + (size_t)srow * S_LEN + (KT)*64 + sc8);         \
    vreg[1] = *(const short8*)(vtb + (size_t)(srow + 32) * S_LEN + (KT)*64 + sc8);  \
  }
#define STAGE_WRITE(B)                                   \
  {                                                      \
    *(short8*)((char*)Kt[B] + swo) = kreg[0];            \
    *(short8*)((char*)Kt[B] + swo + 4096) = kreg[1];     \
    *(short8*)((char*)Vt[B] + swo) = vreg[0];            \
    *(short8*)((char*)Vt[B] + swo + 4096) = vreg[1];     \
  }

  STAGE_LOAD(hi);
  STAGE_WRITE(0);
  __syncthreads();
  int cur = 0;
  float ktoff = slope2 * 64.0f * (float)hi;
  const float dko = slope2 * 64.0f;

  for (int kt = hi; kt >= lo; --kt) {
    if (kt > lo) STAGE_LOAD(kt - 1);
    const char* Kc = (const char*)Kt[cur];
    const char* Vc = (const char*)Vt[cur];

    f32x4 sacc[4];
#pragma unroll
    for (int nb = 0; nb < 4; ++nb) sacc[nb] = (f32x4){0.f, 0.f, 0.f, 0.f};
    __builtin_amdgcn_s_setprio(1);
#pragma unroll
    for (int ks = 0; ks < 2; ++ks)
#pragma unroll
      for (int nb = 0; nb < 4; ++nb) {
        short8 kf = *(const short8*)(Kc + koff[nb][ks]);
        sacc[nb] = __builtin_amdgcn_mfma_f32_16x16x32_bf16(kf, qf[ks], sacc[nb], 0, 0, 0);
      }
    __builtin_amdgcn_s_setprio(0);

    float p[4][4];
#pragma unroll
    for (int nb = 0; nb < 4; ++nb)
#pragma unroll
      for (int r = 0; r < 4; ++r)
        p[nb][r] = fmaf(sacc[nb][r], scale2, bc[nb][r]);

    float mx0 = fmaxf(fmaxf(p[0][0], p[0][1]), fmaxf(p[0][2], p[0][3]));
    float mx1 = fmaxf(fmaxf(p[1][0], p[1][1]), fmaxf(p[1][2], p[1][3]));
    float mx2 = fmaxf(fmaxf(p[2][0], p[2][1]), fmaxf(p[2][2], p[2][3]));
    float mx3 = fmaxf(fmaxf(p[3][0], p[3][1]), fmaxf(p[3][2], p[3][3]));
    float tm = fmaxf(fmaxf(mx0, mx1), fmaxf(mx2, mx3));
    tm = fmaxf(tm, __shfl_xor(tm, 16));
    tm = fmaxf(tm, __shfl_xor(tm, 32));

    float mm = m - ktoff;
    if (__any(tm > mm)) {
      float mn = fmaxf(mm, tm);
      float corr = exp2f(mm - mn);
      m = mn + ktoff;
      mm = mn;
      float cb[4];
#pragma unroll
      for (int r = 0; r < 4; ++r)
        cb[r] = __shfl(corr, (lane & 48) | (lh * 4 + r));
#pragma unroll
      for (int nd = 0; nd < 4; ++nd)
#pragma unroll
        for (int r = 0; r < 4; ++r) accO[nd][r] *= cb[r];
#pragma unroll
      for (int r = 0; r < 4; ++r) lacc[r] *= cb[r];
    }

#pragma unroll
    for (int nb = 0; nb < 4; ++nb)
#pragma unroll
      for (int r = 0; r < 4; ++r) p[nb][r] = exp2f(p[nb][r] - mm);

#pragma unroll
    for (int nb = 0; nb < 4; ++nb) {
      uint32_t w0 = pack_bf2(p[nb][0], p[nb][1]);
      uint32_t w1 = pack_bf2(p[nb][2], p[nb][3]);
      *(uint2*)(PtW + pwoff[nb]) = make_uint2(w0, w1);
    }
    asm volatile("s_waitcnt lgkmcnt(0)" ::: "memory");

    __builtin_amdgcn_s_setprio(1);
#pragma unroll
    for (int ks = 0; ks < 2; ++ks) {
      short8 pf = *(const short8*)(PtW + poff[ks]);
      lacc = __builtin_amdgcn_mfma_f32_16x16x32_bf16(pf, vones, lacc, 0, 0, 0);
#pragma unroll
      for (int nd = 0; nd < 4; ++nd) {
        short8 vf = *(const short8*)(Vc + koff[nd][ks]);
        accO[nd] = __builtin_amdgcn_mfma_f32_16x16x32_bf16(pf, vf, accO[nd], 0, 0, 0);
      }
    }
    __builtin_amdgcn_s_setprio(0);

    if (kt > lo) STAGE_WRITE(cur ^ 1);
    __syncthreads();
    cur ^= 1;
    ktoff -= dko;
  }

  if (nsp == 1) {
    float ib[4];
#pragma unroll
    for (int r = 0; r < 4; ++r) ib[r] = 1.0f / lacc[r];
    u16* aop = ao + ((size_t)(b * S_LEN + qt * 64 + wid * 16 + lh * 4)) * D_DIM + h * HDIM;
#pragma unroll
    for (int nd = 0; nd < 4; ++nd)
#pragma unroll
      for (int r = 0; r < 4; ++r)
        aop[(size_t)r * D_DIM + nd * 16 + l4] = f2bf(accO[nd][r] * ib[r]);
  } else {
    const int sbase = (h <= 10) ? (h - 9) * 2 : 4 + (h - 11) * 3;
    const int pidx = sub * 19 + sbase + j;
    float* Op = pO + (size_t)pidx * 4096;
#pragma unroll
    for (int nd = 0; nd < 4; ++nd)
#pragma unroll
      for (int r = 0; r < 4; ++r)
        Op[(wid * 16 + lh * 4 + r) * 64 + nd * 16 + l4] = accO[nd][r];
    float mq[4];
#pragma unroll
    for (int r = 0; r < 4; ++r)
      mq[r] = __shfl(m, (lane & 48) | (lh * 4 + r));
    if (l4 == 0) {
      float* mlp = pML + (size_t)pidx * 128 + (wid * 16 + lh * 4) * 2;
#pragma unroll
      for (int r = 0; r < 4; ++r) {
        mlp[r * 2] = mq[r];
        mlp[r * 2 + 1] = lacc[r];
      }
    }
  }
#undef STAGE_LOAD
#undef STAGE_WRITE
}

// ---------------- combine partials for split heads (h>=9) ----------------
__global__ __launch_bounds__(256) void attn_combine(const float* __restrict__ pO,
                                                    const float* __restrict__ pML,
                                                    u16* __restrict__ ao) {
  const int g = blockIdx.x;        // 448 = 64 subs x 7 heads
  const int sub = g & 63;
  const int h = 9 + (g >> 6);
  const int b = sub >> 5, qt = sub & 31;
  const int nsp = (h <= 10) ? 2 : 3;
  const int sbase = (h <= 10) ? (h - 9) * 2 : 4 + (h - 11) * 3;
  const int pidx0 = sub * 19 + sbase;
  const int tid = threadIdx.x;
  const int row = tid >> 2;
  const int d0 = (tid & 3) * 16;

  float mj[3], lj[3];
#pragma unroll
  for (int k = 0; k < 3; ++k) { mj[k] = -1e30f; lj[k] = 0.f; }
  for (int k = 0; k < nsp; ++k) {
    mj[k] = pML[(size_t)(pidx0 + k) * 128 + row * 2];
    lj[k] = pML[(size_t)(pidx0 + k) * 128 + row * 2 + 1];
  }
  float ms = fmaxf(mj[0], fmaxf(mj[1], mj[2]));
  float w[3];
  float lsum = 0.f;
#pragma unroll
  for (int k = 0; k < 3; ++k) {
    w[k] = exp2f(mj[k] - ms);
    lsum += w[k] * lj[k];
  }
  float inv = 1.0f / lsum;

  u16* aop = ao + ((size_t)(b * S_LEN + qt * 64 + row)) * D_DIM + h * HDIM + d0;
#pragma unroll
  for (int c = 0; c < 4; ++c) {
    float4 o = {0.f, 0.f, 0.f, 0.f};
    for (int k = 0; k < nsp; ++k) {
      const float4 v = *(const float4*)(pO + (size_t)(pidx0 + k) * 4096 + row * 64 + d0 + c * 4);
      o.x += w[k] * v.x; o.y += w[k] * v.y; o.z += w[k] * v.z; o.w += w[k] * v.w;
    }
    ushort4 u4 = make_ushort4(f2bf(o.x * inv), f2bf(o.y * inv), f2bf(o.z * inv), f2bf(o.w * inv));
    *(ushort4*)(aop + c * 4) = u4;
  }
}

extern "C" void kernel_launch(void* const* d_in, const int* in_sizes, int n_in,
                              void* d_out, int out_size, void* d_ws, size_t ws_size,
                              hipStream_t stream) {
  const float* x   = (const float*)d_in[0];
  const float* Wq  = (const float*)d_in[1];
  const float* Wk  = (const float*)d_in[2];
  const float* Wv  = (const float*)d_in[3];
  const float* Wo  = (const float*)d_in[4];
  const float* bo  = (const float*)d_in[5];
  const float* W1  = (const float*)d_in[6];
  const float* b1  = (const float*)d_in[7];
  const float* W2  = (const float*)d_in[8];
  const float* b2  = (const float*)d_in[9];
  const float* g1  = (const float*)d_in[10];
  const float* be1 = (const float*)d_in[11];
  const float* g2  = (const float*)d_in[12];
  const float* be2 = (const float*)d_in[13];

  char* p = (char*)d_ws;
  u16* wqkv = (u16*)p; p += (size_t)3072 * 1024 * 2;
  u16* wo   = (u16*)p; p += (size_t)1024 * 1024 * 2;
  u16* w1   = (u16*)p; p += (size_t)4096 * 1024 * 2;
  u16* w2   = (u16*)p; p += (size_t)4096 * 1024 * 2;
  u16* hb   = (u16*)p; p += (size_t)4096 * 1024 * 2;
  u16* qkvb = (u16*)p; p += (size_t)4096 * 3072 * 2;
  u16* aob  = (u16*)p; p += (size_t)4096 * 1024 * 2;
  float* x1 = (float*)p; p += (size_t)4096 * 1024 * 4;
  u16* h2b  = (u16*)p; p += (size_t)4096 * 1024 * 2;
  u16* ff1  = (u16*)p; p += (size_t)4096 * 4096 * 2;
  u16* vt   = ff1;                                        // 8MB, dead before FFN1
  float* pO = (float*)(ff1 + (size_t)4 * 1024 * 1024);    // partial O (inside ff1)
  float* pML = pO + (size_t)1216 * 4096;                  // partial m,l
  u16* pk = hb;   // FFN2 split-K=4 bf16 partials: 4 x 8MB = hb+qkvb (32MB, dead)

  cast_all<<<12288, 256, 0, stream>>>(Wq, Wk, Wv, Wo, W1, W2, wqkv, wo, w1, w2);

  ln_kernel<<<4096, 256, 0, stream>>>(x, g1, be1, hb);
  gemm_bt2<0><<<16 * 12, 512, 0, stream>>>(hb, wqkv, qkvb, nullptr, 4096, 3072, 1024);
  transpose_v<<<256, 256, 0, stream>>>(qkvb, vt);
  attn_kernel<<<1792, 256, 0, stream>>>(qkvb, vt, aob, pO, pML);
  attn_combine<<<448, 256, 0, stream>>>(pO, pML, aob);
  gemm_bt<1><<<32 * 8, 256, 0, stream>>>(aob, wo, x1, bo, x, 4096, 1024, 1024, 1);
  ln_kernel<<<4096, 256, 0, stream>>>(x1, g2, be2, h2b);
  gemm_bt2<2><<<16 * 16, 512, 0, stream>>>(h2b, w1, ff1, b1, 4096, 4096, 1024);
  // FFN2: 512x128 deep-pipe, split-K=4, bf16 partials -> fused reduce
  gemm_bt4<<<4 * 8 * 8, 512, 0, stream>>>(ff1, w2, pk, 4096, 1024, 4096, 4);
  reduce4_kernel<<<2048, 256, 0, stream>>>(pk, x1, b2, (float*)d_out);
}

// Round 11
// 227.525 us; speedup vs baseline: 1.8402x; 1.0105x over previous
//
#include <hip/hip_runtime.h>
#include <hip/hip_bf16.h>
#include <stdint.h>

typedef unsigned short u16;
typedef __attribute__((ext_vector_type(8))) short short8;
typedef __attribute__((ext_vector_type(4))) float f32x4;

#define S_LEN 2048
#define D_DIM 1024
#define NHEAD 16
#define HDIM 64
#define NROWS 4096

__device__ __forceinline__ u16 f2bf(float f) {
  union { float f; uint32_t u; } c; c.f = f;
  uint32_t r = (c.u + 0x7fffu + ((c.u >> 16) & 1u)) >> 16;
  return (u16)r;
}

__device__ __forceinline__ float bf2f(u16 v) {
  union { uint32_t u; float f; } c; c.u = ((uint32_t)v) << 16;
  return c.f;
}

__device__ __forceinline__ uint32_t pack_bf2(float a, float b) {
  __hip_bfloat162 h = __float22bfloat162_rn(float2{a, b});
  union { __hip_bfloat162 h; uint32_t u; } c; c.h = h;
  return c.u;
}

__device__ __forceinline__ void gload_lds16(const void* g, void* l) {
  typedef const __attribute__((address_space(1))) unsigned int gq_t;
  typedef __attribute__((address_space(3))) unsigned int lq_t;
  __builtin_amdgcn_global_load_lds((gq_t*)(uintptr_t)g,
                                   (lq_t*)(uint32_t)(uintptr_t)l, 16, 0, 0);
}

// ---------------- all weight casts fused (fp32 -> bf16) ----------------
__global__ __launch_bounds__(256) void cast_all(const float* __restrict__ Wq,
                                                const float* __restrict__ Wk,
                                                const float* __restrict__ Wv,
                                                const float* __restrict__ Wo,
                                                const float* __restrict__ W1,
                                                const float* __restrict__ W2,
                                                u16* __restrict__ wqkv,
                                                u16* __restrict__ wo,
                                                u16* __restrict__ w1,
                                                u16* __restrict__ w2) {
  int i = blockIdx.x * 256 + threadIdx.x;  // 0..3145727
  const float* src;
  u16* dst;
  int rel;
  if (i < 786432) {
    int ws = i / 262144;
    rel = i - ws * 262144;
    src = (ws == 0) ? Wq : ((ws == 1) ? Wk : Wv);
    dst = wqkv + (size_t)ws * 1048576;
  } else if (i < 1048576) {
    rel = i - 786432; src = Wo; dst = wo;
  } else if (i < 2097152) {
    rel = i - 1048576; src = W1; dst = w1;
  } else {
    rel = i - 2097152; src = W2; dst = w2;
  }
  float4 v = ((const float4*)src)[rel];
  ((ushort4*)dst)[rel] = make_ushort4(f2bf(v.x), f2bf(v.y), f2bf(v.z), f2bf(v.w));
}

// ---------------- LayerNorm fp32 -> bf16 ----------------
__global__ __launch_bounds__(256) void ln_kernel(const float* __restrict__ x,
                                                 const float* __restrict__ g,
                                                 const float* __restrict__ be,
                                                 u16* __restrict__ out) {
  int row = blockIdx.x;
  int tid = threadIdx.x;
  const float4 v = ((const float4*)(x + (size_t)row * D_DIM))[tid];
  float s = v.x + v.y + v.z + v.w;
  float s2 = v.x * v.x + v.y * v.y + v.z * v.z + v.w * v.w;
#pragma unroll
  for (int off = 1; off < 64; off <<= 1) {
    s += __shfl_xor(s, off);
    s2 += __shfl_xor(s2, off);
  }
  __shared__ float ss[4], ss2[4];
  if ((tid & 63) == 0) { ss[tid >> 6] = s; ss2[tid >> 6] = s2; }
  __syncthreads();
  s = ss[0] + ss[1] + ss[2] + ss[3];
  s2 = ss2[0] + ss2[1] + ss2[2] + ss2[3];
  float mu = s * (1.0f / D_DIM);
  float var = s2 * (1.0f / D_DIM) - mu * mu;
  float rs = rsqrtf(var + 1e-5f);
  float4 gv = ((const float4*)g)[tid];
  float4 bv = ((const float4*)be)[tid];
  ushort4 o = make_ushort4(f2bf((v.x - mu) * rs * gv.x + bv.x),
                           f2bf((v.y - mu) * rs * gv.y + bv.y),
                           f2bf((v.z - mu) * rs * gv.z + bv.z),
                           f2bf((v.w - mu) * rs * gv.w + bv.w));
  ((ushort4*)(out + (size_t)row * D_DIM))[tid] = o;
}

// ====== 256x256 BK=32 deep-pipe NT GEMM (QKV / FFN1 / FFN2-splitK) ======
// 8 waves (2Mx4N), per-wave 128x64 out. LDS 64KB double-buffered -> 2 blk/CU.
// EPI 0: bf16 out. EPI 2: bf16 relu(acc+bias). EPI 3: bf16 partial
// (split-K slice ksl>1: Cout + slice*M*N).
template <int EPI>
__global__ __launch_bounds__(512, 2) void gemm_bt2(const u16* __restrict__ A,
                                                   const u16* __restrict__ Bw,
                                                   void* __restrict__ Cout,
                                                   const float* __restrict__ bias,
                                                   int M, int N, int K, int ksl) {
  __shared__ u16 lsA[2][256 * 32];
  __shared__ u16 lsB[2][256 * 32];
  const int tid = threadIdx.x;
  const int wid = tid >> 6, lane = tid & 63;
  const int l4 = lane & 15, lh = lane >> 4;
  const int wr = wid >> 2, wc = wid & 3;
  const int nbn = N >> 8;
  const int nwg = (M >> 8) * nbn;
  const int slice = blockIdx.x / nwg;
  const int id0 = blockIdx.x % nwg;
  const int t0 = (id0 & 7) * (nwg >> 3) + (id0 >> 3);
  const int bm = t0 / nbn, bn = t0 % nbn;
  const int Ks = K / ksl;

  f32x4 acc[8][4];
#pragma unroll
  for (int i = 0; i < 8; ++i)
#pragma unroll
    for (int j = 0; j < 4; ++j) acc[i][j] = (f32x4){0.f, 0.f, 0.f, 0.f};

  const int srow = lane >> 2;
  const int sblk = (lane & 3) ^ ((lane >> 3) & 3);
  const u16* Abase = A + ((size_t)bm * 256 + wid * 32 + srow) * K + (size_t)slice * Ks + sblk * 8;
  const u16* Bbase = Bw + ((size_t)bn * 256 + wid * 32 + srow) * K + (size_t)slice * Ks + sblk * 8;
  const size_t r16 = (size_t)16 * K;
#define STAGE(BUF, KT)                                              \
  {                                                                 \
    int ko = (KT) * 32;                                             \
    gload_lds16(Abase + ko, (char*)lsA[BUF] + wid * 2048);          \
    gload_lds16(Abase + r16 + ko, (char*)lsA[BUF] + wid * 2048 + 1024); \
    gload_lds16(Bbase + ko, (char*)lsB[BUF] + wid * 2048);          \
    gload_lds16(Bbase + r16 + ko, (char*)lsB[BUF] + wid * 2048 + 1024); \
  }

  const int swz = (lh ^ ((l4 >> 1) & 3)) << 4;
  int aoff[8], boff[4];
#pragma unroll
  for (int m = 0; m < 8; ++m) aoff[m] = (wr * 128 + m * 16 + l4) * 64 + swz;
#pragma unroll
  for (int n = 0; n < 4; ++n) boff[n] = (wc * 64 + n * 16 + l4) * 64 + swz;

  STAGE(0, 0);
  __syncthreads();
  int cur = 0;
  const int NT = Ks >> 5;

  for (int t = 0; t < NT; ++t) {
    if (t + 1 < NT) STAGE(cur ^ 1, t + 1);
    const char* La = (const char*)lsA[cur];
    const char* Lb = (const char*)lsB[cur];
    short8 aF[4], bF[4], aG[4];
#pragma unroll
    for (int m = 0; m < 4; ++m) aF[m] = *(const short8*)(La + aoff[m]);
#pragma unroll
    for (int n = 0; n < 4; ++n) bF[n] = *(const short8*)(Lb + boff[n]);
    __builtin_amdgcn_s_setprio(1);
#pragma unroll
    for (int m = 0; m < 4; ++m)
#pragma unroll
      for (int n = 0; n < 4; ++n)
        acc[m][n] = __builtin_amdgcn_mfma_f32_16x16x32_bf16(aF[m], bF[n], acc[m][n], 0, 0, 0);
    __builtin_amdgcn_s_setprio(0);
#pragma unroll
    for (int m = 0; m < 4; ++m) aG[m] = *(const short8*)(La + aoff[m + 4]);
    __builtin_amdgcn_s_setprio(1);
#pragma unroll
    for (int m = 0; m < 4; ++m)
#pragma unroll
      for (int n = 0; n < 4; ++n)
        acc[m + 4][n] = __builtin_amdgcn_mfma_f32_16x16x32_bf16(aG[m], bF[n], acc[m + 4][n], 0, 0, 0);
    __builtin_amdgcn_s_setprio(0);
    if (t + 1 < NT) __syncthreads();
    cur ^= 1;
  }

  const int row0 = bm * 256 + wr * 128 + lh * 4;
  const int col0 = bn * 256 + wc * 64 + l4;
  u16* Cp = (u16*)Cout + (size_t)slice * M * N;
#pragma unroll
  for (int m = 0; m < 8; ++m) {
#pragma unroll
    for (int n = 0; n < 4; ++n) {
      int col = col0 + n * 16;
#pragma unroll
      for (int r = 0; r < 4; ++r) {
        size_t idx = (size_t)(row0 + m * 16 + r) * N + col;
        float v = acc[m][n][r];
        if (EPI == 0) {
          ((u16*)Cout)[idx] = f2bf(v);
        } else if (EPI == 2) {
          v += bias[col];
          ((u16*)Cout)[idx] = f2bf(v > 0.f ? v : 0.f);
        } else {
          Cp[idx] = f2bf(v);
        }
      }
    }
  }
#undef STAGE
}

// ---------------- 128x128 NT GEMM (O-proj) ----------
template <int EPI>
__global__ __launch_bounds__(256) void gemm_bt(const u16* __restrict__ A,
                                               const u16* __restrict__ Bw,
                                               void* __restrict__ Cout,
                                               const float* __restrict__ bias,
                                               const float* __restrict__ resid,
                                               int M, int N, int K, int ksl) {
  __shared__ u16 lsA[128 * 64];
  __shared__ u16 lsB[128 * 64];
  const int tid = threadIdx.x;
  const int wid = tid >> 6, lane = tid & 63;
  const int l4 = lane & 15, lh = lane >> 4;
  const int nbn = N >> 7;
  const int nwgs = (M >> 7) * nbn;
  const int slice = blockIdx.x / nwgs;
  const int id0 = blockIdx.x % nwgs;
  const int t = (id0 & 7) * (nwgs >> 3) + (id0 >> 3);
  const int bm = t / nbn, bn = t % nbn;
  const int wr = wid >> 1, wc = wid & 1;
  const int Ks = K / ksl;

  f32x4 acc[4][4];
#pragma unroll
  for (int i = 0; i < 4; ++i)
#pragma unroll
    for (int j = 0; j < 4; ++j) acc[i][j] = (f32x4){0.f, 0.f, 0.f, 0.f};

  const u16* Ab = A + (size_t)bm * 128 * K + (size_t)slice * Ks;
  const u16* Bb = Bw + (size_t)bn * 128 * K + (size_t)slice * Ks;
  const int srow = (lane >> 3);
  const int scol = (lane & 7) * 8;

  for (int k0 = 0; k0 < Ks; k0 += 64) {
#pragma unroll
    for (int c = 0; c < 4; ++c) {
      int ch = wid * 4 + c;
      int row = ch * 8 + srow;
      gload_lds16(Ab + (size_t)row * K + k0 + scol, &lsA[ch * 512]);
      gload_lds16(Bb + (size_t)row * K + k0 + scol, &lsB[ch * 512]);
    }
    __syncthreads();
#pragma unroll
    for (int ks = 0; ks < 2; ++ks) {
      short8 af[4], bf[4];
#pragma unroll
      for (int i = 0; i < 4; ++i) {
        af[i] = *(const short8*)&lsA[(wr * 64 + i * 16 + l4) * 64 + ks * 32 + lh * 8];
        bf[i] = *(const short8*)&lsB[(wc * 64 + i * 16 + l4) * 64 + ks * 32 + lh * 8];
      }
#pragma unroll
      for (int i = 0; i < 4; ++i)
#pragma unroll
        for (int j = 0; j < 4; ++j)
          acc[i][j] = __builtin_amdgcn_mfma_f32_16x16x32_bf16(af[i], bf[j], acc[i][j], 0, 0, 0);
    }
    __syncthreads();
  }

  const int row0 = bm * 128 + wr * 64;
  const int col0 = bn * 128 + wc * 64;
  float* Cp = (float*)Cout + (size_t)slice * M * N;
#pragma unroll
  for (int i = 0; i < 4; ++i) {
#pragma unroll
    for (int j = 0; j < 4; ++j) {
      int col = col0 + j * 16 + l4;
#pragma unroll
      for (int r = 0; r < 4; ++r) {
        int row = row0 + i * 16 + lh * 4 + r;
        size_t idx = (size_t)row * N + col;
        float v = acc[i][j][r];
        if (EPI == 1) {
          ((float*)Cout)[idx] = v + bias[col] + resid[idx];
        } else {
          Cp[idx] = v;
        }
      }
    }
  }
}

// ------- split-K=4 reduce: out = sum(bf16 partials) + bias + resid -------
__global__ __launch_bounds__(256) void reduce4_kernel(const u16* __restrict__ pk,
                                                      const float* __restrict__ resid,
                                                      const float* __restrict__ bias,
                                                      float* __restrict__ out) {
  const size_t SL = (size_t)NROWS * D_DIM;
  int i = blockIdx.x * 256 + threadIdx.x;  // x8 elements
  short8 p0 = *(const short8*)(pk + (size_t)i * 8);
  short8 p1 = *(const short8*)(pk + SL + (size_t)i * 8);
  short8 p2 = *(const short8*)(pk + 2 * SL + (size_t)i * 8);
  short8 p3 = *(const short8*)(pk + 3 * SL + (size_t)i * 8);
  int col = (i * 8) & (D_DIM - 1);
  float4 b0 = *(const float4*)(bias + col);
  float4 b1 = *(const float4*)(bias + col + 4);
  float4 r0 = ((const float4*)resid)[i * 2];
  float4 r1 = ((const float4*)resid)[i * 2 + 1];
  float o[8];
#pragma unroll
  for (int j = 0; j < 8; ++j)
    o[j] = bf2f((u16)p0[j]) + bf2f((u16)p1[j]) + bf2f((u16)p2[j]) + bf2f((u16)p3[j]);
  float4 w0 = {o[0] + b0.x + r0.x, o[1] + b0.y + r0.y, o[2] + b0.z + r0.z, o[3] + b0.w + r0.w};
  float4 w1 = {o[4] + b1.x + r1.x, o[5] + b1.y + r1.y, o[6] + b1.z + r1.z, o[7] + b1.w + r1.w};
  ((float4*)out)[i * 2] = w0;
  ((float4*)out)[i * 2 + 1] = w1;
}

// ---------------- V transpose ----------------
__global__ __launch_bounds__(256) void transpose_v(const u16* __restrict__ qkv,
                                                   u16* __restrict__ vt) {
  const int gw = blockIdx.x * 4 + (threadIdx.x >> 6);
  const int lane = threadIdx.x & 63;
  const int bh = gw >> 5;
  const int st = gw & 31;
  const int b = bh >> 4, h = bh & 15;
  const u16* src = qkv + (size_t)(b * S_LEN + st * 64) * 3072 + 2048 + h * 64 + lane;
  short8 acc8[8];
#pragma unroll
  for (int o = 0; o < 8; ++o)
#pragma unroll
    for (int i = 0; i < 8; ++i)
      acc8[o][i] = (short)src[(size_t)(o * 8 + i) * 3072];
  u16* dst = vt + ((size_t)bh * 64 + lane) * S_LEN + st * 64;
#pragma unroll
  for (int o = 0; o < 8; ++o) *(short8*)(dst + o * 8) = acc8[o];
}

// ---------------- Flash attention with ALiBi (KV-split flash-decode) --------
__global__ __launch_bounds__(256, 4) void attn_kernel(const u16* __restrict__ qkv,
                                                      const u16* __restrict__ vt,
                                                      u16* __restrict__ ao,
                                                      float* __restrict__ pO,
                                                      float* __restrict__ pML) {
  const int id = blockIdx.x;
  const int sub = id & 63;   // (b,qt)
  const int ugrp = id >> 6;  // 0..27
  int h, j;
  if (ugrp < 15) { h = 15 - ugrp / 3; j = ugrp % 3; }
  else if (ugrp < 19) { h = 10 - ((ugrp - 15) >> 1); j = (ugrp - 15) & 1; }
  else { h = 27 - ugrp; j = 0; }
  const int b = sub >> 5, qt = sub & 31;
  const int bh = b * 16 + h;
  const int tid = threadIdx.x;
  const int wid = tid >> 6, lane = tid & 63;
  const int l4 = lane & 15, lh = lane >> 4;

  __shared__ u16 Kt[2][64 * 64];
  __shared__ u16 Vt[2][64 * 64];
  __shared__ u16 Pt[4][16 * 64];

  const size_t RS = 3 * D_DIM;
  const u16* base = qkv + (size_t)b * S_LEN * RS + h * HDIM;
  const u16* kbase = base + D_DIM;
  const u16* vtb = vt + (size_t)bh * HDIM * S_LEN;
  char* PtW = (char*)Pt[wid];

  short8 qf[2];
  {
    const u16* qp = base + (size_t)(qt * 64 + wid * 16 + l4) * RS + lh * 8;
    qf[0] = *(const short8*)qp;
    qf[1] = *(const short8*)(qp + 32);
  }

  int koff[4][2];
#pragma unroll
  for (int nb = 0; nb < 4; ++nb)
#pragma unroll
    for (int ks = 0; ks < 2; ++ks) {
      int row = nb * 16 + l4;
      koff[nb][ks] = row * 128 + (((ks * 32 + lh * 8) * 2) ^ ((row & 7) << 4));
    }
  int poff[2];
#pragma unroll
  for (int ks = 0; ks < 2; ++ks)
    poff[ks] = l4 * 128 + (((ks * 64 + lh * 16)) ^ ((l4 & 7) << 4));
  int pwoff[4];
#pragma unroll
  for (int nb = 0; nb < 4; ++nb)
    pwoff[nb] = l4 * 128 + (((lh * 8 + nb * 32)) ^ ((l4 & 7) << 4));

  const float slope2 = exp2f(-0.5f * (float)(h + 1)) * 1.44269504088896f;
  const float scale2 = 0.125f * 1.44269504088896f;
  const int ibase = lh * 4 - (qt * 64 + wid * 16 + l4);
  float bc[4][4];
#pragma unroll
  for (int nb = 0; nb < 4; ++nb)
#pragma unroll
    for (int r = 0; r < 4; ++r)
      bc[nb][r] = slope2 * (float)(ibase + 16 * nb + r);

  int nt = (int)ceilf(40.0f / (64.0f * slope2)) + 1;
  if (nt > 32) nt = 32;
  const int nsp = (nt + 11) / 12;
  const int ktmin = 32 - nt;
  const int hi = 31 - j * 12;
  int lo = hi - 11;
  if (lo < ktmin) lo = ktmin;

  float m = -1e30f;
  f32x4 lacc = (f32x4){0.f, 0.f, 0.f, 0.f};
  f32x4 accO[4];
#pragma unroll
  for (int nd = 0; nd < 4; ++nd) accO[nd] = (f32x4){0.f, 0.f, 0.f, 0.f};
  const short8 vones = {(short)0x3F80, (short)0x3F80, (short)0x3F80, (short)0x3F80,
                        (short)0x3F80, (short)0x3F80, (short)0x3F80, (short)0x3F80};

  const int srow = tid >> 3;
  const int sc8 = (tid & 7) * 8;
  const int swo = srow * 128 + ((sc8 * 2) ^ ((srow & 7) << 4));
  short8 kreg[2], vreg[2];
#define STAGE_LOAD(KT)                                                              \
  {                                                                                 \
    kreg[0] = *(const short8*)(kbase + (size_t)((KT)*64 + srow) * RS + sc8);        \
    kreg[1] = *(const short8*)(kbase + (size_t)((KT)*64 + srow + 32) * RS + sc8);   \
    vreg[0] = *(const short8*)(vtb + (size_t)srow * S_LEN + (KT)*64 + sc8);         \
    vreg[1] = *(const short8*)(vtb + (size_t)(srow + 32) * S_LEN + (KT)*64 + sc8);  \
  }
#define STAGE_WRITE(B)                                   \
  {                                                      \
    *(short8*)((char*)Kt[B] + swo) = kreg[0];            \
    *(short8*)((char*)Kt[B] + swo + 4096) = kreg[1];     \
    *(short8*)((char*)Vt[B] + swo) = vreg[0];            \
    *(short8*)((char*)Vt[B] + swo + 4096) = vreg[1];     \
  }

  STAGE_LOAD(hi);
  STAGE_WRITE(0);
  __syncthreads();
  int cur = 0;
  float ktoff = slope2 * 64.0f * (float)hi;
  const float dko = slope2 * 64.0f;

  for (int kt = hi; kt >= lo; --kt) {
    if (kt > lo) STAGE_LOAD(kt - 1);
    const char* Kc = (const char*)Kt[cur];
    const char* Vc = (const char*)Vt[cur];

    f32x4 sacc[4];
#pragma unroll
    for (int nb = 0; nb < 4; ++nb) sacc[nb] = (f32x4){0.f, 0.f, 0.f, 0.f};
    __builtin_amdgcn_s_setprio(1);
#pragma unroll
    for (int ks = 0; ks < 2; ++ks)
#pragma unroll
      for (int nb = 0; nb < 4; ++nb) {
        short8 kf = *(const short8*)(Kc + koff[nb][ks]);
        sacc[nb] = __builtin_amdgcn_mfma_f32_16x16x32_bf16(kf, qf[ks], sacc[nb], 0, 0, 0);
      }
    __builtin_amdgcn_s_setprio(0);

    float p[4][4];
#pragma unroll
    for (int nb = 0; nb < 4; ++nb)
#pragma unroll
      for (int r = 0; r < 4; ++r)
        p[nb][r] = fmaf(sacc[nb][r], scale2, bc[nb][r]);

    float mx0 = fmaxf(fmaxf(p[0][0], p[0][1]), fmaxf(p[0][2], p[0][3]));
    float mx1 = fmaxf(fmaxf(p[1][0], p[1][1]), fmaxf(p[1][2], p[1][3]));
    float mx2 = fmaxf(fmaxf(p[2][0], p[2][1]), fmaxf(p[2][2], p[2][3]));
    float mx3 = fmaxf(fmaxf(p[3][0], p[3][1]), fmaxf(p[3][2], p[3][3]));
    float tm = fmaxf(fmaxf(mx0, mx1), fmaxf(mx2, mx3));
    tm = fmaxf(tm, __shfl_xor(tm, 16));
    tm = fmaxf(tm, __shfl_xor(tm, 32));

    float mm = m - ktoff;
    if (__any(tm > mm)) {
      float mn = fmaxf(mm, tm);
      float corr = exp2f(mm - mn);
      m = mn + ktoff;
      mm = mn;
      float cb[4];
#pragma unroll
      for (int r = 0; r < 4; ++r)
        cb[r] = __shfl(corr, (lane & 48) | (lh * 4 + r));
#pragma unroll
      for (int nd = 0; nd < 4; ++nd)
#pragma unroll
        for (int r = 0; r < 4; ++r) accO[nd][r] *= cb[r];
#pragma unroll
      for (int r = 0; r < 4; ++r) lacc[r] *= cb[r];
    }

#pragma unroll
    for (int nb = 0; nb < 4; ++nb)
#pragma unroll
      for (int r = 0; r < 4; ++r) p[nb][r] = exp2f(p[nb][r] - mm);

#pragma unroll
    for (int nb = 0; nb < 4; ++nb) {
      uint32_t w0 = pack_bf2(p[nb][0], p[nb][1]);
      uint32_t w1 = pack_bf2(p[nb][2], p[nb][3]);
      *(uint2*)(PtW + pwoff[nb]) = make_uint2(w0, w1);
    }
    asm volatile("s_waitcnt lgkmcnt(0)" ::: "memory");

    __builtin_amdgcn_s_setprio(1);
#pragma unroll
    for (int ks = 0; ks < 2; ++ks) {
      short8 pf = *(const short8*)(PtW + poff[ks]);
      lacc = __builtin_amdgcn_mfma_f32_16x16x32_bf16(pf, vones, lacc, 0, 0, 0);
#pragma unroll
      for (int nd = 0; nd < 4; ++nd) {
        short8 vf = *(const short8*)(Vc + koff[nd][ks]);
        accO[nd] = __builtin_amdgcn_mfma_f32_16x16x32_bf16(pf, vf, accO[nd], 0, 0, 0);
      }
    }
    __builtin_amdgcn_s_setprio(0);

    if (kt > lo) STAGE_WRITE(cur ^ 1);
    __syncthreads();
    cur ^= 1;
    ktoff -= dko;
  }

  if (nsp == 1) {
    float ib[4];
#pragma unroll
    for (int r = 0; r < 4; ++r) ib[r] = 1.0f / lacc[r];
    u16* aop = ao + ((size_t)(b * S_LEN + qt * 64 + wid * 16 + lh * 4)) * D_DIM + h * HDIM;
#pragma unroll
    for (int nd = 0; nd < 4; ++nd)
#pragma unroll
      for (int r = 0; r < 4; ++r)
        aop[(size_t)r * D_DIM + nd * 16 + l4] = f2bf(accO[nd][r] * ib[r]);
  } else {
    const int sbase = (h <= 10) ? (h - 9) * 2 : 4 + (h - 11) * 3;
    const int pidx = sub * 19 + sbase + j;
    float* Op = pO + (size_t)pidx * 4096;
#pragma unroll
    for (int nd = 0; nd < 4; ++nd)
#pragma unroll
      for (int r = 0; r < 4; ++r)
        Op[(wid * 16 + lh * 4 + r) * 64 + nd * 16 + l4] = accO[nd][r];
    float mq[4];
#pragma unroll
    for (int r = 0; r < 4; ++r)
      mq[r] = __shfl(m, (lane & 48) | (lh * 4 + r));
    if (l4 == 0) {
      float* mlp = pML + (size_t)pidx * 128 + (wid * 16 + lh * 4) * 2;
#pragma unroll
      for (int r = 0; r < 4; ++r) {
        mlp[r * 2] = mq[r];
        mlp[r * 2 + 1] = lacc[r];
      }
    }
  }
#undef STAGE_LOAD
#undef STAGE_WRITE
}

// ---------------- combine partials for split heads (h>=9) ----------------
__global__ __launch_bounds__(256) void attn_combine(const float* __restrict__ pO,
                                                    const float* __restrict__ pML,
                                                    u16* __restrict__ ao) {
  const int g = blockIdx.x;        // 448 = 64 subs x 7 heads
  const int sub = g & 63;
  const int h = 9 + (g >> 6);
  const int b = sub >> 5, qt = sub & 31;
  const int nsp = (h <= 10) ? 2 : 3;
  const int sbase = (h <= 10) ? (h - 9) * 2 : 4 + (h - 11) * 3;
  const int pidx0 = sub * 19 + sbase;
  const int tid = threadIdx.x;
  const int row = tid >> 2;
  const int d0 = (tid & 3) * 16;

  float mj[3], lj[3];
#pragma unroll
  for (int k = 0; k < 3; ++k) { mj[k] = -1e30f; lj[k] = 0.f; }
  for (int k = 0; k < nsp; ++k) {
    mj[k] = pML[(size_t)(pidx0 + k) * 128 + row * 2];
    lj[k] = pML[(size_t)(pidx0 + k) * 128 + row * 2 + 1];
  }
  float ms = fmaxf(mj[0], fmaxf(mj[1], mj[2]));
  float w[3];
  float lsum = 0.f;
#pragma unroll
  for (int k = 0; k < 3; ++k) {
    w[k] = exp2f(mj[k] - ms);
    lsum += w[k] * lj[k];
  }
  float inv = 1.0f / lsum;

  u16* aop = ao + ((size_t)(b * S_LEN + qt * 64 + row)) * D_DIM + h * HDIM + d0;
#pragma unroll
  for (int c = 0; c < 4; ++c) {
    float4 o = {0.f, 0.f, 0.f, 0.f};
    for (int k = 0; k < nsp; ++k) {
      const float4 v = *(const float4*)(pO + (size_t)(pidx0 + k) * 4096 + row * 64 + d0 + c * 4);
      o.x += w[k] * v.x; o.y += w[k] * v.y; o.z += w[k] * v.z; o.w += w[k] * v.w;
    }
    ushort4 u4 = make_ushort4(f2bf(o.x * inv), f2bf(o.y * inv), f2bf(o.z * inv), f2bf(o.w * inv));
    *(ushort4*)(aop + c * 4) = u4;
  }
}

extern "C" void kernel_launch(void* const* d_in, const int* in_sizes, int n_in,
                              void* d_out, int out_size, void* d_ws, size_t ws_size,
                              hipStream_t stream) {
  const float* x   = (const float*)d_in[0];
  const float* Wq  = (const float*)d_in[1];
  const float* Wk  = (const float*)d_in[2];
  const float* Wv  = (const float*)d_in[3];
  const float* Wo  = (const float*)d_in[4];
  const float* bo  = (const float*)d_in[5];
  const float* W1  = (const float*)d_in[6];
  const float* b1  = (const float*)d_in[7];
  const float* W2  = (const float*)d_in[8];
  const float* b2  = (const float*)d_in[9];
  const float* g1  = (const float*)d_in[10];
  const float* be1 = (const float*)d_in[11];
  const float* g2  = (const float*)d_in[12];
  const float* be2 = (const float*)d_in[13];

  char* p = (char*)d_ws;
  u16* wqkv = (u16*)p; p += (size_t)3072 * 1024 * 2;
  u16* wo   = (u16*)p; p += (size_t)1024 * 1024 * 2;
  u16* w1   = (u16*)p; p += (size_t)4096 * 1024 * 2;
  u16* w2   = (u16*)p; p += (size_t)4096 * 1024 * 2;
  u16* hb   = (u16*)p; p += (size_t)4096 * 1024 * 2;
  u16* qkvb = (u16*)p; p += (size_t)4096 * 3072 * 2;
  u16* aob  = (u16*)p; p += (size_t)4096 * 1024 * 2;
  float* x1 = (float*)p; p += (size_t)4096 * 1024 * 4;
  u16* h2b  = (u16*)p; p += (size_t)4096 * 1024 * 2;
  u16* ff1  = (u16*)p; p += (size_t)4096 * 4096 * 2;
  u16* vt   = ff1;                                        // 8MB, dead before FFN1
  float* pO = (float*)(ff1 + (size_t)4 * 1024 * 1024);    // partial O (inside ff1)
  float* pML = pO + (size_t)1216 * 4096;                  // partial m,l
  u16* pk = hb;   // FFN2 split-K=4 bf16 partials: 4 x 8MB = hb+qkvb (32MB, dead)

  cast_all<<<12288, 256, 0, stream>>>(Wq, Wk, Wv, Wo, W1, W2, wqkv, wo, w1, w2);

  ln_kernel<<<4096, 256, 0, stream>>>(x, g1, be1, hb);
  gemm_bt2<0><<<16 * 12, 512, 0, stream>>>(hb, wqkv, qkvb, nullptr, 4096, 3072, 1024, 1);
  transpose_v<<<256, 256, 0, stream>>>(qkvb, vt);
  attn_kernel<<<1792, 256, 0, stream>>>(qkvb, vt, aob, pO, pML);
  attn_combine<<<448, 256, 0, stream>>>(pO, pML, aob);
  gemm_bt<1><<<32 * 8, 256, 0, stream>>>(aob, wo, x1, bo, x, 4096, 1024, 1024, 1);
  ln_kernel<<<4096, 256, 0, stream>>>(x1, g2, be2, h2b);
  gemm_bt2<2><<<16 * 16, 512, 0, stream>>>(h2b, w1, ff1, b1, 4096, 4096, 1024, 1);
  // FFN2: 256x256 deep-pipe (2 blk/CU), split-K=4, bf16 partials -> reduce
  gemm_bt2<3><<<4 * 64, 512, 0, stream>>>(ff1, w2, pk, nullptr, 4096, 1024, 4096, 4);
  reduce4_kernel<<<2048, 256, 0, stream>>>(pk, x1, b2, (float*)d_out);
}

// Round 12
// 224.217 us; speedup vs baseline: 1.8673x; 1.0148x over previous
//
#include <hip/hip_runtime.h>
#include <hip/hip_bf16.h>
#include <stdint.h>

typedef unsigned short u16;
typedef __attribute__((ext_vector_type(8))) short short8;
typedef __attribute__((ext_vector_type(4))) float f32x4;

#define S_LEN 2048
#define D_DIM 1024
#define NHEAD 16
#define HDIM 64
#define NROWS 4096

__device__ __forceinline__ u16 f2bf(float f) {
  union { float f; uint32_t u; } c; c.f = f;
  uint32_t r = (c.u + 0x7fffu + ((c.u >> 16) & 1u)) >> 16;
  return (u16)r;
}

__device__ __forceinline__ float bf2f(u16 v) {
  union { uint32_t u; float f; } c; c.u = ((uint32_t)v) << 16;
  return c.f;
}

__device__ __forceinline__ uint32_t pack_bf2(float a, float b) {
  __hip_bfloat162 h = __float22bfloat162_rn(float2{a, b});
  union { __hip_bfloat162 h; uint32_t u; } c; c.h = h;
  return c.u;
}

__device__ __forceinline__ void gload_lds16(const void* g, void* l) {
  typedef const __attribute__((address_space(1))) unsigned int gq_t;
  typedef __attribute__((address_space(3))) unsigned int lq_t;
  __builtin_amdgcn_global_load_lds((gq_t*)(uintptr_t)g,
                                   (lq_t*)(uint32_t)(uintptr_t)l, 16, 0, 0);
}

// ---------------- all weight casts fused (fp32 -> bf16) ----------------
__global__ __launch_bounds__(256) void cast_all(const float* __restrict__ Wq,
                                                const float* __restrict__ Wk,
                                                const float* __restrict__ Wv,
                                                const float* __restrict__ Wo,
                                                const float* __restrict__ W1,
                                                const float* __restrict__ W2,
                                                u16* __restrict__ wqkv,
                                                u16* __restrict__ wo,
                                                u16* __restrict__ w1,
                                                u16* __restrict__ w2) {
  int i = blockIdx.x * 256 + threadIdx.x;  // 0..3145727
  const float* src;
  u16* dst;
  int rel;
  if (i < 786432) {
    int ws = i / 262144;
    rel = i - ws * 262144;
    src = (ws == 0) ? Wq : ((ws == 1) ? Wk : Wv);
    dst = wqkv + (size_t)ws * 1048576;
  } else if (i < 1048576) {
    rel = i - 786432; src = Wo; dst = wo;
  } else if (i < 2097152) {
    rel = i - 1048576; src = W1; dst = w1;
  } else {
    rel = i - 2097152; src = W2; dst = w2;
  }
  float4 v = ((const float4*)src)[rel];
  ((ushort4*)dst)[rel] = make_ushort4(f2bf(v.x), f2bf(v.y), f2bf(v.z), f2bf(v.w));
}

// ---------------- LayerNorm fp32 -> bf16 ----------------
__global__ __launch_bounds__(256) void ln_kernel(const float* __restrict__ x,
                                                 const float* __restrict__ g,
                                                 const float* __restrict__ be,
                                                 u16* __restrict__ out) {
  int row = blockIdx.x;
  int tid = threadIdx.x;
  const float4 v = ((const float4*)(x + (size_t)row * D_DIM))[tid];
  float s = v.x + v.y + v.z + v.w;
  float s2 = v.x * v.x + v.y * v.y + v.z * v.z + v.w * v.w;
#pragma unroll
  for (int off = 1; off < 64; off <<= 1) {
    s += __shfl_xor(s, off);
    s2 += __shfl_xor(s2, off);
  }
  __shared__ float ss[4], ss2[4];
  if ((tid & 63) == 0) { ss[tid >> 6] = s; ss2[tid >> 6] = s2; }
  __syncthreads();
  s = ss[0] + ss[1] + ss[2] + ss[3];
  s2 = ss2[0] + ss2[1] + ss2[2] + ss2[3];
  float mu = s * (1.0f / D_DIM);
  float var = s2 * (1.0f / D_DIM) - mu * mu;
  float rs = rsqrtf(var + 1e-5f);
  float4 gv = ((const float4*)g)[tid];
  float4 bv = ((const float4*)be)[tid];
  ushort4 o = make_ushort4(f2bf((v.x - mu) * rs * gv.x + bv.x),
                           f2bf((v.y - mu) * rs * gv.y + bv.y),
                           f2bf((v.z - mu) * rs * gv.z + bv.z),
                           f2bf((v.w - mu) * rs * gv.w + bv.w));
  ((ushort4*)(out + (size_t)row * D_DIM))[tid] = o;
}

// ====== 256x256 BK=32 triple-buffer counted-vmcnt NT GEMM (T3/T4) ======
// 8 waves (2Mx4N), per-wave 128x64 out. LDS 96KB (3 x 32KB ring).
// Prefetch tile t+2 while computing tile t; barrier waits vmcnt(4) so the
// newest 4 loads stay in flight (tile t+1's loads had 2 compute phases).
// EPI 0: bf16 out. EPI 2: bf16 relu(acc+bias). EPI 3: bf16 split-K partial.
template <int EPI>
__global__ __launch_bounds__(512, 2) void gemm_bt2(const u16* __restrict__ A,
                                                   const u16* __restrict__ Bw,
                                                   void* __restrict__ Cout,
                                                   const float* __restrict__ bias,
                                                   int M, int N, int K, int ksl) {
  __shared__ u16 lsA[3][256 * 32];
  __shared__ u16 lsB[3][256 * 32];
  const int tid = threadIdx.x;
  const int wid = tid >> 6, lane = tid & 63;
  const int l4 = lane & 15, lh = lane >> 4;
  const int wr = wid >> 2, wc = wid & 3;
  const int nbn = N >> 8;
  const int nwg = (M >> 8) * nbn;
  const int slice = blockIdx.x / nwg;
  const int id0 = blockIdx.x % nwg;
  const int t0 = (id0 & 7) * (nwg >> 3) + (id0 >> 3);
  const int bm = t0 / nbn, bn = t0 % nbn;
  const int Ks = K / ksl;

  f32x4 acc[8][4];
#pragma unroll
  for (int i = 0; i < 8; ++i)
#pragma unroll
    for (int j = 0; j < 4; ++j) acc[i][j] = (f32x4){0.f, 0.f, 0.f, 0.f};

  const int srow = lane >> 2;
  const int sblk = (lane & 3) ^ ((lane >> 3) & 3);
  const u16* Abase = A + ((size_t)bm * 256 + wid * 32 + srow) * K + (size_t)slice * Ks + sblk * 8;
  const u16* Bbase = Bw + ((size_t)bn * 256 + wid * 32 + srow) * K + (size_t)slice * Ks + sblk * 8;
  const size_t r16 = (size_t)16 * K;
#define STAGE(BUF, KT)                                              \
  {                                                                 \
    int ko = (KT) * 32;                                             \
    gload_lds16(Abase + ko, (char*)lsA[BUF] + wid * 2048);          \
    gload_lds16(Abase + r16 + ko, (char*)lsA[BUF] + wid * 2048 + 1024); \
    gload_lds16(Bbase + ko, (char*)lsB[BUF] + wid * 2048);          \
    gload_lds16(Bbase + r16 + ko, (char*)lsB[BUF] + wid * 2048 + 1024); \
  }

  const int swz = (lh ^ ((l4 >> 1) & 3)) << 4;
  int aoff[8], boff[4];
#pragma unroll
  for (int m = 0; m < 8; ++m) aoff[m] = (wr * 128 + m * 16 + l4) * 64 + swz;
#pragma unroll
  for (int n = 0; n < 4; ++n) boff[n] = (wc * 64 + n * 16 + l4) * 64 + swz;

  const int NT = Ks >> 5;
  STAGE(0, 0);
  STAGE(1, 1);
  asm volatile("s_waitcnt vmcnt(4)" ::: "memory");  // tile0 landed; tile1 in flight
  __builtin_amdgcn_s_barrier();
  int cb = 0, sb = 2;

  for (int t = 0; t < NT; ++t) {
    if (t + 2 < NT) STAGE(sb, t + 2);  // prefetch 2 ahead into ring
    const char* La = (const char*)lsA[cb];
    const char* Lb = (const char*)lsB[cb];
    short8 aF[4], bF[4], aG[4];
#pragma unroll
    for (int m = 0; m < 4; ++m) aF[m] = *(const short8*)(La + aoff[m]);
#pragma unroll
    for (int n = 0; n < 4; ++n) bF[n] = *(const short8*)(Lb + boff[n]);
    __builtin_amdgcn_s_setprio(1);
#pragma unroll
    for (int m = 0; m < 4; ++m)
#pragma unroll
      for (int n = 0; n < 4; ++n)
        acc[m][n] = __builtin_amdgcn_mfma_f32_16x16x32_bf16(aF[m], bF[n], acc[m][n], 0, 0, 0);
    __builtin_amdgcn_s_setprio(0);
#pragma unroll
    for (int m = 0; m < 4; ++m) aG[m] = *(const short8*)(La + aoff[m + 4]);
    __builtin_amdgcn_s_setprio(1);
#pragma unroll
    for (int m = 0; m < 4; ++m)
#pragma unroll
      for (int n = 0; n < 4; ++n)
        acc[m + 4][n] = __builtin_amdgcn_mfma_f32_16x16x32_bf16(aG[m], bF[n], acc[m + 4][n], 0, 0, 0);
    __builtin_amdgcn_s_setprio(0);
    if (t + 1 < NT) {
      // tile t+1's loads (issued last iter) must be done; newest 4 may fly.
      if (t + 2 < NT) {
        asm volatile("s_waitcnt vmcnt(4)" ::: "memory");
      } else {
        asm volatile("s_waitcnt vmcnt(0)" ::: "memory");
      }
      __builtin_amdgcn_s_barrier();
    }
    cb = (cb == 2) ? 0 : cb + 1;
    sb = (sb == 2) ? 0 : sb + 1;
  }

  const int row0 = bm * 256 + wr * 128 + lh * 4;
  const int col0 = bn * 256 + wc * 64 + l4;
  u16* Cp = (u16*)Cout + (size_t)slice * M * N;
#pragma unroll
  for (int m = 0; m < 8; ++m) {
#pragma unroll
    for (int n = 0; n < 4; ++n) {
      int col = col0 + n * 16;
#pragma unroll
      for (int r = 0; r < 4; ++r) {
        size_t idx = (size_t)(row0 + m * 16 + r) * N + col;
        float v = acc[m][n][r];
        if (EPI == 0) {
          ((u16*)Cout)[idx] = f2bf(v);
        } else if (EPI == 2) {
          v += bias[col];
          ((u16*)Cout)[idx] = f2bf(v > 0.f ? v : 0.f);
        } else {
          Cp[idx] = f2bf(v);
        }
      }
    }
  }
#undef STAGE
}

// ---------------- 128x128 NT GEMM (O-proj) ----------
template <int EPI>
__global__ __launch_bounds__(256) void gemm_bt(const u16* __restrict__ A,
                                               const u16* __restrict__ Bw,
                                               void* __restrict__ Cout,
                                               const float* __restrict__ bias,
                                               const float* __restrict__ resid,
                                               int M, int N, int K, int ksl) {
  __shared__ u16 lsA[128 * 64];
  __shared__ u16 lsB[128 * 64];
  const int tid = threadIdx.x;
  const int wid = tid >> 6, lane = tid & 63;
  const int l4 = lane & 15, lh = lane >> 4;
  const int nbn = N >> 7;
  const int nwgs = (M >> 7) * nbn;
  const int slice = blockIdx.x / nwgs;
  const int id0 = blockIdx.x % nwgs;
  const int t = (id0 & 7) * (nwgs >> 3) + (id0 >> 3);
  const int bm = t / nbn, bn = t % nbn;
  const int wr = wid >> 1, wc = wid & 1;
  const int Ks = K / ksl;

  f32x4 acc[4][4];
#pragma unroll
  for (int i = 0; i < 4; ++i)
#pragma unroll
    for (int j = 0; j < 4; ++j) acc[i][j] = (f32x4){0.f, 0.f, 0.f, 0.f};

  const u16* Ab = A + (size_t)bm * 128 * K + (size_t)slice * Ks;
  const u16* Bb = Bw + (size_t)bn * 128 * K + (size_t)slice * Ks;
  const int srow = (lane >> 3);
  const int scol = (lane & 7) * 8;

  for (int k0 = 0; k0 < Ks; k0 += 64) {
#pragma unroll
    for (int c = 0; c < 4; ++c) {
      int ch = wid * 4 + c;
      int row = ch * 8 + srow;
      gload_lds16(Ab + (size_t)row * K + k0 + scol, &lsA[ch * 512]);
      gload_lds16(Bb + (size_t)row * K + k0 + scol, &lsB[ch * 512]);
    }
    __syncthreads();
#pragma unroll
    for (int ks = 0; ks < 2; ++ks) {
      short8 af[4], bf[4];
#pragma unroll
      for (int i = 0; i < 4; ++i) {
        af[i] = *(const short8*)&lsA[(wr * 64 + i * 16 + l4) * 64 + ks * 32 + lh * 8];
        bf[i] = *(const short8*)&lsB[(wc * 64 + i * 16 + l4) * 64 + ks * 32 + lh * 8];
      }
#pragma unroll
      for (int i = 0; i < 4; ++i)
#pragma unroll
        for (int j = 0; j < 4; ++j)
          acc[i][j] = __builtin_amdgcn_mfma_f32_16x16x32_bf16(af[i], bf[j], acc[i][j], 0, 0, 0);
    }
    __syncthreads();
  }

  const int row0 = bm * 128 + wr * 64;
  const int col0 = bn * 128 + wc * 64;
  float* Cp = (float*)Cout + (size_t)slice * M * N;
#pragma unroll
  for (int i = 0; i < 4; ++i) {
#pragma unroll
    for (int j = 0; j < 4; ++j) {
      int col = col0 + j * 16 + l4;
#pragma unroll
      for (int r = 0; r < 4; ++r) {
        int row = row0 + i * 16 + lh * 4 + r;
        size_t idx = (size_t)row * N + col;
        float v = acc[i][j][r];
        if (EPI == 1) {
          ((float*)Cout)[idx] = v + bias[col] + resid[idx];
        } else {
          Cp[idx] = v;
        }
      }
    }
  }
}

// ------- split-K=4 reduce: out = sum(bf16 partials) + bias + resid -------
__global__ __launch_bounds__(256) void reduce4_kernel(const u16* __restrict__ pk,
                                                      const float* __restrict__ resid,
                                                      const float* __restrict__ bias,
                                                      float* __restrict__ out) {
  const size_t SL = (size_t)NROWS * D_DIM;
  int i = blockIdx.x * 256 + threadIdx.x;  // x8 elements
  short8 p0 = *(const short8*)(pk + (size_t)i * 8);
  short8 p1 = *(const short8*)(pk + SL + (size_t)i * 8);
  short8 p2 = *(const short8*)(pk + 2 * SL + (size_t)i * 8);
  short8 p3 = *(const short8*)(pk + 3 * SL + (size_t)i * 8);
  int col = (i * 8) & (D_DIM - 1);
  float4 b0 = *(const float4*)(bias + col);
  float4 b1 = *(const float4*)(bias + col + 4);
  float4 r0 = ((const float4*)resid)[i * 2];
  float4 r1 = ((const float4*)resid)[i * 2 + 1];
  float o[8];
#pragma unroll
  for (int j = 0; j < 8; ++j)
    o[j] = bf2f((u16)p0[j]) + bf2f((u16)p1[j]) + bf2f((u16)p2[j]) + bf2f((u16)p3[j]);
  float4 w0 = {o[0] + b0.x + r0.x, o[1] + b0.y + r0.y, o[2] + b0.z + r0.z, o[3] + b0.w + r0.w};
  float4 w1 = {o[4] + b1.x + r1.x, o[5] + b1.y + r1.y, o[6] + b1.z + r1.z, o[7] + b1.w + r1.w};
  ((float4*)out)[i * 2] = w0;
  ((float4*)out)[i * 2 + 1] = w1;
}

// ---------------- V transpose ----------------
__global__ __launch_bounds__(256) void transpose_v(const u16* __restrict__ qkv,
                                                   u16* __restrict__ vt) {
  const int gw = blockIdx.x * 4 + (threadIdx.x >> 6);
  const int lane = threadIdx.x & 63;
  const int bh = gw >> 5;
  const int st = gw & 31;
  const int b = bh >> 4, h = bh & 15;
  const u16* src = qkv + (size_t)(b * S_LEN + st * 64) * 3072 + 2048 + h * 64 + lane;
  short8 acc8[8];
#pragma unroll
  for (int o = 0; o < 8; ++o)
#pragma unroll
    for (int i = 0; i < 8; ++i)
      acc8[o][i] = (short)src[(size_t)(o * 8 + i) * 3072];
  u16* dst = vt + ((size_t)bh * 64 + lane) * S_LEN + st * 64;
#pragma unroll
  for (int o = 0; o < 8; ++o) *(short8*)(dst + o * 8) = acc8[o];
}

// ---------------- Flash attention with ALiBi (KV-split flash-decode) --------
__global__ __launch_bounds__(256, 4) void attn_kernel(const u16* __restrict__ qkv,
                                                      const u16* __restrict__ vt,
                                                      u16* __restrict__ ao,
                                                      float* __restrict__ pO,
                                                      float* __restrict__ pML) {
  const int id = blockIdx.x;
  const int sub = id & 63;   // (b,qt)
  const int ugrp = id >> 6;  // 0..27
  int h, j;
  if (ugrp < 15) { h = 15 - ugrp / 3; j = ugrp % 3; }
  else if (ugrp < 19) { h = 10 - ((ugrp - 15) >> 1); j = (ugrp - 15) & 1; }
  else { h = 27 - ugrp; j = 0; }
  const int b = sub >> 5, qt = sub & 31;
  const int bh = b * 16 + h;
  const int tid = threadIdx.x;
  const int wid = tid >> 6, lane = tid & 63;
  const int l4 = lane & 15, lh = lane >> 4;

  __shared__ u16 Kt[2][64 * 64];
  __shared__ u16 Vt[2][64 * 64];
  __shared__ u16 Pt[4][16 * 64];

  const size_t RS = 3 * D_DIM;
  const u16* base = qkv + (size_t)b * S_LEN * RS + h * HDIM;
  const u16* kbase = base + D_DIM;
  const u16* vtb = vt + (size_t)bh * HDIM * S_LEN;
  char* PtW = (char*)Pt[wid];

  short8 qf[2];
  {
    const u16* qp = base + (size_t)(qt * 64 + wid * 16 + l4) * RS + lh * 8;
    qf[0] = *(const short8*)qp;
    qf[1] = *(const short8*)(qp + 32);
  }

  int koff[4][2];
#pragma unroll
  for (int nb = 0; nb < 4; ++nb)
#pragma unroll
    for (int ks = 0; ks < 2; ++ks) {
      int row = nb * 16 + l4;
      koff[nb][ks] = row * 128 + (((ks * 32 + lh * 8) * 2) ^ ((row & 7) << 4));
    }
  int poff[2];
#pragma unroll
  for (int ks = 0; ks < 2; ++ks)
    poff[ks] = l4 * 128 + (((ks * 64 + lh * 16)) ^ ((l4 & 7) << 4));
  int pwoff[4];
#pragma unroll
  for (int nb = 0; nb < 4; ++nb)
    pwoff[nb] = l4 * 128 + (((lh * 8 + nb * 32)) ^ ((l4 & 7) << 4));

  const float slope2 = exp2f(-0.5f * (float)(h + 1)) * 1.44269504088896f;
  const float scale2 = 0.125f * 1.44269504088896f;
  const int ibase = lh * 4 - (qt * 64 + wid * 16 + l4);
  float bc[4][4];
#pragma unroll
  for (int nb = 0; nb < 4; ++nb)
#pragma unroll
    for (int r = 0; r < 4; ++r)
      bc[nb][r] = slope2 * (float)(ibase + 16 * nb + r);

  int nt = (int)ceilf(40.0f / (64.0f * slope2)) + 1;
  if (nt > 32) nt = 32;
  const int nsp = (nt + 11) / 12;
  const int ktmin = 32 - nt;
  const int hi = 31 - j * 12;
  int lo = hi - 11;
  if (lo < ktmin) lo = ktmin;

  float m = -1e30f;
  f32x4 lacc = (f32x4){0.f, 0.f, 0.f, 0.f};
  f32x4 accO[4];
#pragma unroll
  for (int nd = 0; nd < 4; ++nd) accO[nd] = (f32x4){0.f, 0.f, 0.f, 0.f};
  const short8 vones = {(short)0x3F80, (short)0x3F80, (short)0x3F80, (short)0x3F80,
                        (short)0x3F80, (short)0x3F80, (short)0x3F80, (short)0x3F80};

  const int srow = tid >> 3;
  const int sc8 = (tid & 7) * 8;
  const int swo = srow * 128 + ((sc8 * 2) ^ ((srow & 7) << 4));
  short8 kreg[2], vreg[2];
#define STAGE_LOAD(KT)                                                              \
  {                                                                                 \
    kreg[0] = *(const short8*)(kbase + (size_t)((KT)*64 + srow) * RS + sc8);        \
    kreg[1] = *(const short8*)(kbase + (size_t)((KT)*64 + srow + 32) * RS + sc8);   \
    vreg[0] = *(const short8*)(vtb + (size_t)srow * S_LEN + (KT)*64 + sc8);         \
    vreg[1] = *(const short8*)(vtb + (size_t)(srow + 32) * S_LEN + (KT)*64 + sc8);  \
  }
#define STAGE_WRITE(B)                                   \
  {                                                      \
    *(short8*)((char*)Kt[B] + swo) = kreg[0];            \
    *(short8*)((char*)Kt[B] + swo + 4096) = kreg[1];     \
    *(short8*)((char*)Vt[B] + swo) = vreg[0];            \
    *(short8*)((char*)Vt[B] + swo + 4096) = vreg[1];     \
  }

  STAGE_LOAD(hi);
  STAGE_WRITE(0);
  __syncthreads();
  int cur = 0;
  float ktoff = slope2 * 64.0f * (float)hi;
  const float dko = slope2 * 64.0f;

  for (int kt = hi; kt >= lo; --kt) {
    if (kt > lo) STAGE_LOAD(kt - 1);
    const char* Kc = (const char*)Kt[cur];
    const char* Vc = (const char*)Vt[cur];

    f32x4 sacc[4];
#pragma unroll
    for (int nb = 0; nb < 4; ++nb) sacc[nb] = (f32x4){0.f, 0.f, 0.f, 0.f};
    __builtin_amdgcn_s_setprio(1);
#pragma unroll
    for (int ks = 0; ks < 2; ++ks)
#pragma unroll
      for (int nb = 0; nb < 4; ++nb) {
        short8 kf = *(const short8*)(Kc + koff[nb][ks]);
        sacc[nb] = __builtin_amdgcn_mfma_f32_16x16x32_bf16(kf, qf[ks], sacc[nb], 0, 0, 0);
      }
    __builtin_amdgcn_s_setprio(0);

    float p[4][4];
#pragma unroll
    for (int nb = 0; nb < 4; ++nb)
#pragma unroll
      for (int r = 0; r < 4; ++r)
        p[nb][r] = fmaf(sacc[nb][r], scale2, bc[nb][r]);

    float mx0 = fmaxf(fmaxf(p[0][0], p[0][1]), fmaxf(p[0][2], p[0][3]));
    float mx1 = fmaxf(fmaxf(p[1][0], p[1][1]), fmaxf(p[1][2], p[1][3]));
    float mx2 = fmaxf(fmaxf(p[2][0], p[2][1]), fmaxf(p[2][2], p[2][3]));
    float mx3 = fmaxf(fmaxf(p[3][0], p[3][1]), fmaxf(p[3][2], p[3][3]));
    float tm = fmaxf(fmaxf(mx0, mx1), fmaxf(mx2, mx3));
    tm = fmaxf(tm, __shfl_xor(tm, 16));
    tm = fmaxf(tm, __shfl_xor(tm, 32));

    float mm = m - ktoff;
    if (__any(tm > mm)) {
      float mn = fmaxf(mm, tm);
      float corr = exp2f(mm - mn);
      m = mn + ktoff;
      mm = mn;
      float cb[4];
#pragma unroll
      for (int r = 0; r < 4; ++r)
        cb[r] = __shfl(corr, (lane & 48) | (lh * 4 + r));
#pragma unroll
      for (int nd = 0; nd < 4; ++nd)
#pragma unroll
        for (int r = 0; r < 4; ++r) accO[nd][r] *= cb[r];
#pragma unroll
      for (int r = 0; r < 4; ++r) lacc[r] *= cb[r];
    }

#pragma unroll
    for (int nb = 0; nb < 4; ++nb)
#pragma unroll
      for (int r = 0; r < 4; ++r) p[nb][r] = exp2f(p[nb][r] - mm);

#pragma unroll
    for (int nb = 0; nb < 4; ++nb) {
      uint32_t w0 = pack_bf2(p[nb][0], p[nb][1]);
      uint32_t w1 = pack_bf2(p[nb][2], p[nb][3]);
      *(uint2*)(PtW + pwoff[nb]) = make_uint2(w0, w1);
    }
    asm volatile("s_waitcnt lgkmcnt(0)" ::: "memory");

    __builtin_amdgcn_s_setprio(1);
#pragma unroll
    for (int ks = 0; ks < 2; ++ks) {
      short8 pf = *(const short8*)(PtW + poff[ks]);
      lacc = __builtin_amdgcn_mfma_f32_16x16x32_bf16(pf, vones, lacc, 0, 0, 0);
#pragma unroll
      for (int nd = 0; nd < 4; ++nd) {
        short8 vf = *(const short8*)(Vc + koff[nd][ks]);
        accO[nd] = __builtin_amdgcn_mfma_f32_16x16x32_bf16(pf, vf, accO[nd], 0, 0, 0);
      }
    }
    __builtin_amdgcn_s_setprio(0);

    if (kt > lo) STAGE_WRITE(cur ^ 1);
    __syncthreads();
    cur ^= 1;
    ktoff -= dko;
  }

  if (nsp == 1) {
    float ib[4];
#pragma unroll
    for (int r = 0; r < 4; ++r) ib[r] = 1.0f / lacc[r];
    u16* aop = ao + ((size_t)(b * S_LEN + qt * 64 + wid * 16 + lh * 4)) * D_DIM + h * HDIM;
#pragma unroll
    for (int nd = 0; nd < 4; ++nd)
#pragma unroll
      for (int r = 0; r < 4; ++r)
        aop[(size_t)r * D_DIM + nd * 16 + l4] = f2bf(accO[nd][r] * ib[r]);
  } else {
    const int sbase = (h <= 10) ? (h - 9) * 2 : 4 + (h - 11) * 3;
    const int pidx = sub * 19 + sbase + j;
    float* Op = pO + (size_t)pidx * 4096;
#pragma unroll
    for (int nd = 0; nd < 4; ++nd)
#pragma unroll
      for (int r = 0; r < 4; ++r)
        Op[(wid * 16 + lh * 4 + r) * 64 + nd * 16 + l4] = accO[nd][r];
    float mq[4];
#pragma unroll
    for (int r = 0; r < 4; ++r)
      mq[r] = __shfl(m, (lane & 48) | (lh * 4 + r));
    if (l4 == 0) {
      float* mlp = pML + (size_t)pidx * 128 + (wid * 16 + lh * 4) * 2;
#pragma unroll
      for (int r = 0; r < 4; ++r) {
        mlp[r * 2] = mq[r];
        mlp[r * 2 + 1] = lacc[r];
      }
    }
  }
#undef STAGE_LOAD
#undef STAGE_WRITE
}

// ---------------- combine partials for split heads (h>=9) ----------------
__global__ __launch_bounds__(256) void attn_combine(const float* __restrict__ pO,
                                                    const float* __restrict__ pML,
                                                    u16* __restrict__ ao) {
  const int g = blockIdx.x;        // 448 = 64 subs x 7 heads
  const int sub = g & 63;
  const int h = 9 + (g >> 6);
  const int b = sub >> 5, qt = sub & 31;
  const int nsp = (h <= 10) ? 2 : 3;
  const int sbase = (h <= 10) ? (h - 9) * 2 : 4 + (h - 11) * 3;
  const int pidx0 = sub * 19 + sbase;
  const int tid = threadIdx.x;
  const int row = tid >> 2;
  const int d0 = (tid & 3) * 16;

  float mj[3], lj[3];
#pragma unroll
  for (int k = 0; k < 3; ++k) { mj[k] = -1e30f; lj[k] = 0.f; }
  for (int k = 0; k < nsp; ++k) {
    mj[k] = pML[(size_t)(pidx0 + k) * 128 + row * 2];
    lj[k] = pML[(size_t)(pidx0 + k) * 128 + row * 2 + 1];
  }
  float ms = fmaxf(mj[0], fmaxf(mj[1], mj[2]));
  float w[3];
  float lsum = 0.f;
#pragma unroll
  for (int k = 0; k < 3; ++k) {
    w[k] = exp2f(mj[k] - ms);
    lsum += w[k] * lj[k];
  }
  float inv = 1.0f / lsum;

  u16* aop = ao + ((size_t)(b * S_LEN + qt * 64 + row)) * D_DIM + h * HDIM + d0;
#pragma unroll
  for (int c = 0; c < 4; ++c) {
    float4 o = {0.f, 0.f, 0.f, 0.f};
    for (int k = 0; k < nsp; ++k) {
      const float4 v = *(const float4*)(pO + (size_t)(pidx0 + k) * 4096 + row * 64 + d0 + c * 4);
      o.x += w[k] * v.x; o.y += w[k] * v.y; o.z += w[k] * v.z; o.w += w[k] * v.w;
    }
    ushort4 u4 = make_ushort4(f2bf(o.x * inv), f2bf(o.y * inv), f2bf(o.z * inv), f2bf(o.w * inv));
    *(ushort4*)(aop + c * 4) = u4;
  }
}

extern "C" void kernel_launch(void* const* d_in, const int* in_sizes, int n_in,
                              void* d_out, int out_size, void* d_ws, size_t ws_size,
                              hipStream_t stream) {
  const float* x   = (const float*)d_in[0];
  const float* Wq  = (const float*)d_in[1];
  const float* Wk  = (const float*)d_in[2];
  const float* Wv  = (const float*)d_in[3];
  const float* Wo  = (const float*)d_in[4];
  const float* bo  = (const float*)d_in[5];
  const float* W1  = (const float*)d_in[6];
  const float* b1  = (const float*)d_in[7];
  const float* W2  = (const float*)d_in[8];
  const float* b2  = (const float*)d_in[9];
  const float* g1  = (const float*)d_in[10];
  const float* be1 = (const float*)d_in[11];
  const float* g2  = (const float*)d_in[12];
  const float* be2 = (const float*)d_in[13];

  char* p = (char*)d_ws;
  u16* wqkv = (u16*)p; p += (size_t)3072 * 1024 * 2;
  u16* wo   = (u16*)p; p += (size_t)1024 * 1024 * 2;
  u16* w1   = (u16*)p; p += (size_t)4096 * 1024 * 2;
  u16* w2   = (u16*)p; p += (size_t)4096 * 1024 * 2;
  u16* hb   = (u16*)p; p += (size_t)4096 * 1024 * 2;
  u16* qkvb = (u16*)p; p += (size_t)4096 * 3072 * 2;
  u16* aob  = (u16*)p; p += (size_t)4096 * 1024 * 2;
  float* x1 = (float*)p; p += (size_t)4096 * 1024 * 4;
  u16* h2b  = (u16*)p; p += (size_t)4096 * 1024 * 2;
  u16* ff1  = (u16*)p; p += (size_t)4096 * 4096 * 2;
  u16* vt   = ff1;                                        // 8MB, dead before FFN1
  float* pO = (float*)(ff1 + (size_t)4 * 1024 * 1024);    // partial O (inside ff1)
  float* pML = pO + (size_t)1216 * 4096;                  // partial m,l
  u16* pk = hb;   // FFN2 split-K=4 bf16 partials: 4 x 8MB = hb+qkvb (32MB, dead)

  cast_all<<<12288, 256, 0, stream>>>(Wq, Wk, Wv, Wo, W1, W2, wqkv, wo, w1, w2);

  ln_kernel<<<4096, 256, 0, stream>>>(x, g1, be1, hb);
  gemm_bt2<0><<<16 * 12, 512, 0, stream>>>(hb, wqkv, qkvb, nullptr, 4096, 3072, 1024, 1);
  transpose_v<<<256, 256, 0, stream>>>(qkvb, vt);
  attn_kernel<<<1792, 256, 0, stream>>>(qkvb, vt, aob, pO, pML);
  attn_combine<<<448, 256, 0, stream>>>(pO, pML, aob);
  gemm_bt<1><<<32 * 8, 256, 0, stream>>>(aob, wo, x1, bo, x, 4096, 1024, 1024, 1);
  ln_kernel<<<4096, 256, 0, stream>>>(x1, g2, be2, h2b);
  gemm_bt2<2><<<16 * 16, 512, 0, stream>>>(h2b, w1, ff1, b1, 4096, 4096, 1024, 1);
  // FFN2: 256x256 triple-buffer, split-K=4, bf16 partials -> reduce
  gemm_bt2<3><<<4 * 64, 512, 0, stream>>>(ff1, w2, pk, nullptr, 4096, 1024, 4096, 4);
  reduce4_kernel<<<2048, 256, 0, stream>>>(pk, x1, b2, (float*)d_out);
}

// Round 13
// 223.769 us; speedup vs baseline: 1.8711x; 1.0020x over previous
//
#include <hip/hip_runtime.h>
#include <hip/hip_bf16.h>
#include <stdint.h>

typedef unsigned short u16;
typedef __attribute__((ext_vector_type(8))) short short8;
typedef __attribute__((ext_vector_type(4))) float f32x4;

#define S_LEN 2048
#define D_DIM 1024
#define NHEAD 16
#define HDIM 64
#define NROWS 4096

__device__ __forceinline__ u16 f2bf(float f) {
  union { float f; uint32_t u; } c; c.f = f;
  uint32_t r = (c.u + 0x7fffu + ((c.u >> 16) & 1u)) >> 16;
  return (u16)r;
}

__device__ __forceinline__ float bf2f(u16 v) {
  union { uint32_t u; float f; } c; c.u = ((uint32_t)v) << 16;
  return c.f;
}

__device__ __forceinline__ uint32_t pack_bf2(float a, float b) {
  __hip_bfloat162 h = __float22bfloat162_rn(float2{a, b});
  union { __hip_bfloat162 h; uint32_t u; } c; c.h = h;
  return c.u;
}

__device__ __forceinline__ void gload_lds16(const void* g, void* l) {
  typedef const __attribute__((address_space(1))) unsigned int gq_t;
  typedef __attribute__((address_space(3))) unsigned int lq_t;
  __builtin_amdgcn_global_load_lds((gq_t*)(uintptr_t)g,
                                   (lq_t*)(uint32_t)(uintptr_t)l, 16, 0, 0);
}

// ---------------- all weight casts fused (fp32 -> bf16) ----------------
__global__ __launch_bounds__(256) void cast_all(const float* __restrict__ Wq,
                                                const float* __restrict__ Wk,
                                                const float* __restrict__ Wv,
                                                const float* __restrict__ Wo,
                                                const float* __restrict__ W1,
                                                const float* __restrict__ W2,
                                                u16* __restrict__ wqkv,
                                                u16* __restrict__ wo,
                                                u16* __restrict__ w1,
                                                u16* __restrict__ w2) {
  int i = blockIdx.x * 256 + threadIdx.x;  // 0..3145727
  const float* src;
  u16* dst;
  int rel;
  if (i < 786432) {
    int ws = i / 262144;
    rel = i - ws * 262144;
    src = (ws == 0) ? Wq : ((ws == 1) ? Wk : Wv);
    dst = wqkv + (size_t)ws * 1048576;
  } else if (i < 1048576) {
    rel = i - 786432; src = Wo; dst = wo;
  } else if (i < 2097152) {
    rel = i - 1048576; src = W1; dst = w1;
  } else {
    rel = i - 2097152; src = W2; dst = w2;
  }
  float4 v = ((const float4*)src)[rel];
  ((ushort4*)dst)[rel] = make_ushort4(f2bf(v.x), f2bf(v.y), f2bf(v.z), f2bf(v.w));
}

// ---------------- LayerNorm fp32 -> bf16 ----------------
__global__ __launch_bounds__(256) void ln_kernel(const float* __restrict__ x,
                                                 const float* __restrict__ g,
                                                 const float* __restrict__ be,
                                                 u16* __restrict__ out) {
  int row = blockIdx.x;
  int tid = threadIdx.x;
  const float4 v = ((const float4*)(x + (size_t)row * D_DIM))[tid];
  float s = v.x + v.y + v.z + v.w;
  float s2 = v.x * v.x + v.y * v.y + v.z * v.z + v.w * v.w;
#pragma unroll
  for (int off = 1; off < 64; off <<= 1) {
    s += __shfl_xor(s, off);
    s2 += __shfl_xor(s2, off);
  }
  __shared__ float ss[4], ss2[4];
  if ((tid & 63) == 0) { ss[tid >> 6] = s; ss2[tid >> 6] = s2; }
  __syncthreads();
  s = ss[0] + ss[1] + ss[2] + ss[3];
  s2 = ss2[0] + ss2[1] + ss2[2] + ss2[3];
  float mu = s * (1.0f / D_DIM);
  float var = s2 * (1.0f / D_DIM) - mu * mu;
  float rs = rsqrtf(var + 1e-5f);
  float4 gv = ((const float4*)g)[tid];
  float4 bv = ((const float4*)be)[tid];
  ushort4 o = make_ushort4(f2bf((v.x - mu) * rs * gv.x + bv.x),
                           f2bf((v.y - mu) * rs * gv.y + bv.y),
                           f2bf((v.z - mu) * rs * gv.z + bv.z),
                           f2bf((v.w - mu) * rs * gv.w + bv.w));
  ((ushort4*)(out + (size_t)row * D_DIM))[tid] = o;
}

// ====== 256x256 8-phase deep-pipeline NT GEMM (T2+T3+T4+T5) ======
// 8 waves (2Mx4N), per-wave 128x64 out. LDS 128KB: 2 buf x {A,B} x [2kh][256][32].
// Per 64-K tile = 4 phases: {ds_read subtile || stage half-tile -> BAR ->
// lgkm0 -> prio1 -> 16 MFMA -> prio0 -> BAR}. vmcnt(4) once per K-tile.
// Stagger: A-halves of kt g+1 staged at phases g.0/g.1 (into other buf, whose
// reads retired at end of group g-1); B-halves of kt g+2 at g.2/g.3 (into cur
// buf B region, whose reads retired at end of phase g.1).
// EPI 0: bf16 out. EPI 2: bf16 relu(acc+bias). EPI 3: bf16 split-K partial.
template <int EPI>
__global__ __launch_bounds__(512, 2) void gemm8p(const u16* __restrict__ A,
                                                 const u16* __restrict__ Bw,
                                                 void* __restrict__ Cout,
                                                 const float* __restrict__ bias,
                                                 int M, int N, int K, int ksl) {
  __shared__ char L0[131072];  // [buf:64KB][mat:32KB][kh:16KB][row:64B][blk:16B]
  const int tid = threadIdx.x;
  const int wid = tid >> 6, lane = tid & 63;
  const int l4 = lane & 15, lh = lane >> 4;
  const int wr = wid >> 2, wc = wid & 3;
  const int nbn = N >> 8;
  const int nwg = (M >> 8) * nbn;
  const int slice = blockIdx.x / nwg;
  const int id0 = blockIdx.x % nwg;
  const int t0 = (id0 & 7) * (nwg >> 3) + (id0 >> 3);
  const int bm = t0 / nbn, bn = t0 % nbn;
  const int Ks = K / ksl;
  const int NG = Ks >> 6;  // 64-K tiles

  f32x4 acc[8][4];
#pragma unroll
  for (int i = 0; i < 8; ++i)
#pragma unroll
    for (int j = 0; j < 4; ++j) acc[i][j] = (f32x4){0.f, 0.f, 0.f, 0.f};

  // staging: wave w covers rows w*16..w*16+15 of a 128-row half-tile;
  // source 16B-block pre-swizzled so LDS stays linear (rule #21).
  const int srow4 = lane >> 2;
  const int sblk = (lane & 3) ^ ((lane >> 3) & 3);
  const u16* Asrc = A + ((size_t)(bm * 256 + wid * 16 + srow4)) * K + (size_t)slice * Ks + sblk * 8;
  const u16* Bsrc = Bw + ((size_t)(bn * 256 + wid * 16 + srow4)) * K + (size_t)slice * Ks + sblk * 8;
  const size_t hstr = (size_t)128 * K;
  // STG(mat, src, h, kt, tb): stage one half-tile (2 x gload_lds, kh 0/1)
#define STG(MAT, SRC, H, KT, TB)                                             \
  {                                                                          \
    const u16* s_ = (SRC) + (size_t)(H) * hstr + (KT) * 64;                  \
    char* d_ = L0 + (TB) * 65536 + (MAT) * 32768 + ((H) * 128 + wid * 16) * 64; \
    gload_lds16(s_, d_);                                                     \
    gload_lds16(s_ + 32, d_ + 16384);                                        \
  }

  // fragment read bases (byte offsets within a buffer)
  const int swz = (lh ^ ((l4 >> 1) & 3)) << 4;
  const int aB = (wr * 128 + l4) * 64 + swz;
  const int bB = 32768 + (wc * 64 + l4) * 64 + swz;
#define RDA(LC, M_, KS) (*(const short8*)((LC) + (KS)*16384 + (M_)*1024 + aB))
#define RDB(LC, N_, KS) (*(const short8*)((LC) + (KS)*16384 + (N_)*1024 + bB))

  // prologue: kt0 full (A+B) into buf0, kt1 B into buf1. Leave kt1's B in
  // flight is NOT ok (group0 doesn't guard them until ph3) -> they are the
  // 4 newest; group0 ph0-3 only reads kt0 -> vmcnt(4) drains kt0 fully.
  STG(0, Asrc, 0, 0, 0); STG(0, Asrc, 1, 0, 0);
  STG(1, Bsrc, 0, 0, 0); STG(1, Bsrc, 1, 0, 0);
  STG(1, Bsrc, 0, 1, 1); STG(1, Bsrc, 1, 1, 1);
  asm volatile("s_waitcnt vmcnt(4)" ::: "memory");
  __builtin_amdgcn_s_barrier();

  for (int g = 0; g < NG; ++g) {
    const char* Lc = L0 + (g & 1) * 65536;
    const int tbo = (g + 1) & 1;
    short8 aF[4][2], aG[4][2], bF[2][2], bG[2][2];

    // ---- phase 0: read aF(8) + bF(4); stage A h0 of kt g+1 -> other buf
#pragma unroll
    for (int m = 0; m < 4; ++m) { aF[m][0] = RDA(Lc, m, 0); aF[m][1] = RDA(Lc, m, 1); }
#pragma unroll
    for (int n = 0; n < 2; ++n) { bF[n][0] = RDB(Lc, n, 0); bF[n][1] = RDB(Lc, n, 1); }
    if (g + 1 < NG) STG(0, Asrc, 0, g + 1, tbo);
    __builtin_amdgcn_s_barrier();
    asm volatile("s_waitcnt lgkmcnt(0)" ::: "memory");
    __builtin_amdgcn_sched_barrier(0);
    __builtin_amdgcn_s_setprio(1);
#pragma unroll
    for (int m = 0; m < 4; ++m)
#pragma unroll
      for (int n = 0; n < 2; ++n) {
        acc[m][n] = __builtin_amdgcn_mfma_f32_16x16x32_bf16(aF[m][0], bF[n][0], acc[m][n], 0, 0, 0);
        acc[m][n] = __builtin_amdgcn_mfma_f32_16x16x32_bf16(aF[m][1], bF[n][1], acc[m][n], 0, 0, 0);
      }
    __builtin_amdgcn_s_setprio(0);
    __builtin_amdgcn_s_barrier();

    // ---- phase 1: read bG(4); stage A h1 of kt g+1; MFMA aF x bG
#pragma unroll
    for (int n = 0; n < 2; ++n) { bG[n][0] = RDB(Lc, n + 2, 0); bG[n][1] = RDB(Lc, n + 2, 1); }
    if (g + 1 < NG) STG(0, Asrc, 1, g + 1, tbo);
    __builtin_amdgcn_s_barrier();
    asm volatile("s_waitcnt lgkmcnt(0)" ::: "memory");
    __builtin_amdgcn_sched_barrier(0);
    __builtin_amdgcn_s_setprio(1);
#pragma unroll
    for (int m = 0; m < 4; ++m)
#pragma unroll
      for (int n = 0; n < 2; ++n) {
        acc[m][n + 2] = __builtin_amdgcn_mfma_f32_16x16x32_bf16(aF[m][0], bG[n][0], acc[m][n + 2], 0, 0, 0);
        acc[m][n + 2] = __builtin_amdgcn_mfma_f32_16x16x32_bf16(aF[m][1], bG[n][1], acc[m][n + 2], 0, 0, 0);
      }
    __builtin_amdgcn_s_setprio(0);
    __builtin_amdgcn_s_barrier();

    // ---- phase 2: read aG(8); stage B h0 of kt g+2 -> cur buf (B reads done)
#pragma unroll
    for (int m = 0; m < 4; ++m) { aG[m][0] = RDA(Lc, m + 4, 0); aG[m][1] = RDA(Lc, m + 4, 1); }
    if (g + 2 < NG) STG(1, Bsrc, 0, g + 2, (g & 1));
    __builtin_amdgcn_s_barrier();
    asm volatile("s_waitcnt lgkmcnt(0)" ::: "memory");
    __builtin_amdgcn_sched_barrier(0);
    __builtin_amdgcn_s_setprio(1);
#pragma unroll
    for (int m = 0; m < 4; ++m)
#pragma unroll
      for (int n = 0; n < 2; ++n) {
        acc[m + 4][n] = __builtin_amdgcn_mfma_f32_16x16x32_bf16(aG[m][0], bF[n][0], acc[m + 4][n], 0, 0, 0);
        acc[m + 4][n] = __builtin_amdgcn_mfma_f32_16x16x32_bf16(aG[m][1], bF[n][1], acc[m + 4][n], 0, 0, 0);
      }
    __builtin_amdgcn_s_setprio(0);
    __builtin_amdgcn_s_barrier();

    // ---- phase 3: stage B h1 of kt g+2; MFMA aG x bG; per-K-tile vmcnt guard
    if (g + 2 < NG) STG(1, Bsrc, 1, g + 2, (g & 1));
    __builtin_amdgcn_s_setprio(1);
#pragma unroll
    for (int m = 0; m < 4; ++m)
#pragma unroll
      for (int n = 0; n < 2; ++n) {
        acc[m + 4][n + 2] = __builtin_amdgcn_mfma_f32_16x16x32_bf16(aG[m][0], bG[n][0], acc[m + 4][n + 2], 0, 0, 0);
        acc[m + 4][n + 2] = __builtin_amdgcn_mfma_f32_16x16x32_bf16(aG[m][1], bG[n][1], acc[m + 4][n + 2], 0, 0, 0);
      }
    __builtin_amdgcn_s_setprio(0);
    if (g + 1 < NG) {
      if (g + 2 < NG) {
        asm volatile("s_waitcnt vmcnt(4)" ::: "memory");  // leave B kt g+2 in flight
      } else {
        asm volatile("s_waitcnt vmcnt(0)" ::: "memory");  // tail: drain all
      }
      __builtin_amdgcn_s_barrier();
    }
  }

  const int row0 = bm * 256 + wr * 128 + lh * 4;
  const int col0 = bn * 256 + wc * 64 + l4;
  u16* Cp = (u16*)Cout + (size_t)slice * M * N;
#pragma unroll
  for (int m = 0; m < 8; ++m) {
#pragma unroll
    for (int n = 0; n < 4; ++n) {
      int col = col0 + n * 16;
#pragma unroll
      for (int r = 0; r < 4; ++r) {
        size_t idx = (size_t)(row0 + m * 16 + r) * N + col;
        float v = acc[m][n][r];
        if (EPI == 0) {
          ((u16*)Cout)[idx] = f2bf(v);
        } else if (EPI == 2) {
          v += bias[col];
          ((u16*)Cout)[idx] = f2bf(v > 0.f ? v : 0.f);
        } else {
          Cp[idx] = f2bf(v);
        }
      }
    }
  }
#undef STG
#undef RDA
#undef RDB
}

// ---------------- 128x128 NT GEMM (O-proj) ----------
template <int EPI>
__global__ __launch_bounds__(256) void gemm_bt(const u16* __restrict__ A,
                                               const u16* __restrict__ Bw,
                                               void* __restrict__ Cout,
                                               const float* __restrict__ bias,
                                               const float* __restrict__ resid,
                                               int M, int N, int K, int ksl) {
  __shared__ u16 lsA[128 * 64];
  __shared__ u16 lsB[128 * 64];
  const int tid = threadIdx.x;
  const int wid = tid >> 6, lane = tid & 63;
  const int l4 = lane & 15, lh = lane >> 4;
  const int nbn = N >> 7;
  const int nwgs = (M >> 7) * nbn;
  const int slice = blockIdx.x / nwgs;
  const int id0 = blockIdx.x % nwgs;
  const int t = (id0 & 7) * (nwgs >> 3) + (id0 >> 3);
  const int bm = t / nbn, bn = t % nbn;
  const int wr = wid >> 1, wc = wid & 1;
  const int Ks = K / ksl;

  f32x4 acc[4][4];
#pragma unroll
  for (int i = 0; i < 4; ++i)
#pragma unroll
    for (int j = 0; j < 4; ++j) acc[i][j] = (f32x4){0.f, 0.f, 0.f, 0.f};

  const u16* Ab = A + (size_t)bm * 128 * K + (size_t)slice * Ks;
  const u16* Bb = Bw + (size_t)bn * 128 * K + (size_t)slice * Ks;
  const int srow = (lane >> 3);
  const int scol = (lane & 7) * 8;

  for (int k0 = 0; k0 < Ks; k0 += 64) {
#pragma unroll
    for (int c = 0; c < 4; ++c) {
      int ch = wid * 4 + c;
      int row = ch * 8 + srow;
      gload_lds16(Ab + (size_t)row * K + k0 + scol, &lsA[ch * 512]);
      gload_lds16(Bb + (size_t)row * K + k0 + scol, &lsB[ch * 512]);
    }
    __syncthreads();
#pragma unroll
    for (int ks = 0; ks < 2; ++ks) {
      short8 af[4], bf[4];
#pragma unroll
      for (int i = 0; i < 4; ++i) {
        af[i] = *(const short8*)&lsA[(wr * 64 + i * 16 + l4) * 64 + ks * 32 + lh * 8];
        bf[i] = *(const short8*)&lsB[(wc * 64 + i * 16 + l4) * 64 + ks * 32 + lh * 8];
      }
#pragma unroll
      for (int i = 0; i < 4; ++i)
#pragma unroll
        for (int j = 0; j < 4; ++j)
          acc[i][j] = __builtin_amdgcn_mfma_f32_16x16x32_bf16(af[i], bf[j], acc[i][j], 0, 0, 0);
    }
    __syncthreads();
  }

  const int row0 = bm * 128 + wr * 64;
  const int col0 = bn * 128 + wc * 64;
  float* Cp = (float*)Cout + (size_t)slice * M * N;
#pragma unroll
  for (int i = 0; i < 4; ++i) {
#pragma unroll
    for (int j = 0; j < 4; ++j) {
      int col = col0 + j * 16 + l4;
#pragma unroll
      for (int r = 0; r < 4; ++r) {
        int row = row0 + i * 16 + lh * 4 + r;
        size_t idx = (size_t)row * N + col;
        float v = acc[i][j][r];
        if (EPI == 1) {
          ((float*)Cout)[idx] = v + bias[col] + resid[idx];
        } else {
          Cp[idx] = v;
        }
      }
    }
  }
}

// ------- split-K=4 reduce: out = sum(bf16 partials) + bias + resid -------
__global__ __launch_bounds__(256) void reduce4_kernel(const u16* __restrict__ pk,
                                                      const float* __restrict__ resid,
                                                      const float* __restrict__ bias,
                                                      float* __restrict__ out) {
  const size_t SL = (size_t)NROWS * D_DIM;
  int i = blockIdx.x * 256 + threadIdx.x;  // x8 elements
  short8 p0 = *(const short8*)(pk + (size_t)i * 8);
  short8 p1 = *(const short8*)(pk + SL + (size_t)i * 8);
  short8 p2 = *(const short8*)(pk + 2 * SL + (size_t)i * 8);
  short8 p3 = *(const short8*)(pk + 3 * SL + (size_t)i * 8);
  int col = (i * 8) & (D_DIM - 1);
  float4 b0 = *(const float4*)(bias + col);
  float4 b1 = *(const float4*)(bias + col + 4);
  float4 r0 = ((const float4*)resid)[i * 2];
  float4 r1 = ((const float4*)resid)[i * 2 + 1];
  float o[8];
#pragma unroll
  for (int j = 0; j < 8; ++j)
    o[j] = bf2f((u16)p0[j]) + bf2f((u16)p1[j]) + bf2f((u16)p2[j]) + bf2f((u16)p3[j]);
  float4 w0 = {o[0] + b0.x + r0.x, o[1] + b0.y + r0.y, o[2] + b0.z + r0.z, o[3] + b0.w + r0.w};
  float4 w1 = {o[4] + b1.x + r1.x, o[5] + b1.y + r1.y, o[6] + b1.z + r1.z, o[7] + b1.w + r1.w};
  ((float4*)out)[i * 2] = w0;
  ((float4*)out)[i * 2 + 1] = w1;
}

// ---------------- V transpose ----------------
__global__ __launch_bounds__(256) void transpose_v(const u16* __restrict__ qkv,
                                                   u16* __restrict__ vt) {
  const int gw = blockIdx.x * 4 + (threadIdx.x >> 6);
  const int lane = threadIdx.x & 63;
  const int bh = gw >> 5;
  const int st = gw & 31;
  const int b = bh >> 4, h = bh & 15;
  const u16* src = qkv + (size_t)(b * S_LEN + st * 64) * 3072 + 2048 + h * 64 + lane;
  short8 acc8[8];
#pragma unroll
  for (int o = 0; o < 8; ++o)
#pragma unroll
    for (int i = 0; i < 8; ++i)
      acc8[o][i] = (short)src[(size_t)(o * 8 + i) * 3072];
  u16* dst = vt + ((size_t)bh * 64 + lane) * S_LEN + st * 64;
#pragma unroll
  for (int o = 0; o < 8; ++o) *(short8*)(dst + o * 8) = acc8[o];
}

// ---------------- Flash attention with ALiBi (KV-split flash-decode) --------
__global__ __launch_bounds__(256, 4) void attn_kernel(const u16* __restrict__ qkv,
                                                      const u16* __restrict__ vt,
                                                      u16* __restrict__ ao,
                                                      float* __restrict__ pO,
                                                      float* __restrict__ pML) {
  const int id = blockIdx.x;
  const int sub = id & 63;   // (b,qt)
  const int ugrp = id >> 6;  // 0..27
  int h, j;
  if (ugrp < 15) { h = 15 - ugrp / 3; j = ugrp % 3; }
  else if (ugrp < 19) { h = 10 - ((ugrp - 15) >> 1); j = (ugrp - 15) & 1; }
  else { h = 27 - ugrp; j = 0; }
  const int b = sub >> 5, qt = sub & 31;
  const int bh = b * 16 + h;
  const int tid = threadIdx.x;
  const int wid = tid >> 6, lane = tid & 63;
  const int l4 = lane & 15, lh = lane >> 4;

  __shared__ u16 Kt[2][64 * 64];
  __shared__ u16 Vt[2][64 * 64];
  __shared__ u16 Pt[4][16 * 64];

  const size_t RS = 3 * D_DIM;
  const u16* base = qkv + (size_t)b * S_LEN * RS + h * HDIM;
  const u16* kbase = base + D_DIM;
  const u16* vtb = vt + (size_t)bh * HDIM * S_LEN;
  char* PtW = (char*)Pt[wid];

  short8 qf[2];
  {
    const u16* qp = base + (size_t)(qt * 64 + wid * 16 + l4) * RS + lh * 8;
    qf[0] = *(const short8*)qp;
    qf[1] = *(const short8*)(qp + 32);
  }

  int koff[4][2];
#pragma unroll
  for (int nb = 0; nb < 4; ++nb)
#pragma unroll
    for (int ks = 0; ks < 2; ++ks) {
      int row = nb * 16 + l4;
      koff[nb][ks] = row * 128 + (((ks * 32 + lh * 8) * 2) ^ ((row & 7) << 4));
    }
  int poff[2];
#pragma unroll
  for (int ks = 0; ks < 2; ++ks)
    poff[ks] = l4 * 128 + (((ks * 64 + lh * 16)) ^ ((l4 & 7) << 4));
  int pwoff[4];
#pragma unroll
  for (int nb = 0; nb < 4; ++nb)
    pwoff[nb] = l4 * 128 + (((lh * 8 + nb * 32)) ^ ((l4 & 7) << 4));

  const float slope2 = exp2f(-0.5f * (float)(h + 1)) * 1.44269504088896f;
  const float scale2 = 0.125f * 1.44269504088896f;
  const int ibase = lh * 4 - (qt * 64 + wid * 16 + l4);
  float bc[4][4];
#pragma unroll
  for (int nb = 0; nb < 4; ++nb)
#pragma unroll
    for (int r = 0; r < 4; ++r)
      bc[nb][r] = slope2 * (float)(ibase + 16 * nb + r);

  int nt = (int)ceilf(40.0f / (64.0f * slope2)) + 1;
  if (nt > 32) nt = 32;
  const int nsp = (nt + 11) / 12;
  const int ktmin = 32 - nt;
  const int hi = 31 - j * 12;
  int lo = hi - 11;
  if (lo < ktmin) lo = ktmin;

  float m = -1e30f;
  f32x4 lacc = (f32x4){0.f, 0.f, 0.f, 0.f};
  f32x4 accO[4];
#pragma unroll
  for (int nd = 0; nd < 4; ++nd) accO[nd] = (f32x4){0.f, 0.f, 0.f, 0.f};
  const short8 vones = {(short)0x3F80, (short)0x3F80, (short)0x3F80, (short)0x3F80,
                        (short)0x3F80, (short)0x3F80, (short)0x3F80, (short)0x3F80};

  const int srow = tid >> 3;
  const int sc8 = (tid & 7) * 8;
  const int swo = srow * 128 + ((sc8 * 2) ^ ((srow & 7) << 4));
  short8 kreg[2], vreg[2];
#define STAGE_LOAD(KT)                                                              \
  {                                                                                 \
    kreg[0] = *(const short8*)(kbase + (size_t)((KT)*64 + srow) * RS + sc8);        \
    kreg[1] = *(const short8*)(kbase + (size_t)((KT)*64 + srow + 32) * RS + sc8);   \
    vreg[0] = *(const short8*)(vtb + (size_t)srow * S_LEN + (KT)*64 + sc8);         \
    vreg[1] = *(const short8*)(vtb + (size_t)(srow + 32) * S_LEN + (KT)*64 + sc8);  \
  }
#define STAGE_WRITE(B)                                   \
  {                                                      \
    *(short8*)((char*)Kt[B] + swo) = kreg[0];            \
    *(short8*)((char*)Kt[B] + swo + 4096) = kreg[1];     \
    *(short8*)((char*)Vt[B] + swo) = vreg[0];            \
    *(short8*)((char*)Vt[B] + swo + 4096) = vreg[1];     \
  }

  STAGE_LOAD(hi);
  STAGE_WRITE(0);
  __syncthreads();
  int cur = 0;
  float ktoff = slope2 * 64.0f * (float)hi;
  const float dko = slope2 * 64.0f;

  for (int kt = hi; kt >= lo; --kt) {
    if (kt > lo) STAGE_LOAD(kt - 1);
    const char* Kc = (const char*)Kt[cur];
    const char* Vc = (const char*)Vt[cur];

    f32x4 sacc[4];
#pragma unroll
    for (int nb = 0; nb < 4; ++nb) sacc[nb] = (f32x4){0.f, 0.f, 0.f, 0.f};
    __builtin_amdgcn_s_setprio(1);
#pragma unroll
    for (int ks = 0; ks < 2; ++ks)
#pragma unroll
      for (int nb = 0; nb < 4; ++nb) {
        short8 kf = *(const short8*)(Kc + koff[nb][ks]);
        sacc[nb] = __builtin_amdgcn_mfma_f32_16x16x32_bf16(kf, qf[ks], sacc[nb], 0, 0, 0);
      }
    __builtin_amdgcn_s_setprio(0);

    float p[4][4];
#pragma unroll
    for (int nb = 0; nb < 4; ++nb)
#pragma unroll
      for (int r = 0; r < 4; ++r)
        p[nb][r] = fmaf(sacc[nb][r], scale2, bc[nb][r]);

    float mx0 = fmaxf(fmaxf(p[0][0], p[0][1]), fmaxf(p[0][2], p[0][3]));
    float mx1 = fmaxf(fmaxf(p[1][0], p[1][1]), fmaxf(p[1][2], p[1][3]));
    float mx2 = fmaxf(fmaxf(p[2][0], p[2][1]), fmaxf(p[2][2], p[2][3]));
    float mx3 = fmaxf(fmaxf(p[3][0], p[3][1]), fmaxf(p[3][2], p[3][3]));
    float tm = fmaxf(fmaxf(mx0, mx1), fmaxf(mx2, mx3));
    tm = fmaxf(tm, __shfl_xor(tm, 16));
    tm = fmaxf(tm, __shfl_xor(tm, 32));

    float mm = m - ktoff;
    if (__any(tm > mm)) {
      float mn = fmaxf(mm, tm);
      float corr = exp2f(mm - mn);
      m = mn + ktoff;
      mm = mn;
      float cb[4];
#pragma unroll
      for (int r = 0; r < 4; ++r)
        cb[r] = __shfl(corr, (lane & 48) | (lh * 4 + r));
#pragma unroll
      for (int nd = 0; nd < 4; ++nd)
#pragma unroll
        for (int r = 0; r < 4; ++r) accO[nd][r] *= cb[r];
#pragma unroll
      for (int r = 0; r < 4; ++r) lacc[r] *= cb[r];
    }

#pragma unroll
    for (int nb = 0; nb < 4; ++nb)
#pragma unroll
      for (int r = 0; r < 4; ++r) p[nb][r] = exp2f(p[nb][r] - mm);

#pragma unroll
    for (int nb = 0; nb < 4; ++nb) {
      uint32_t w0 = pack_bf2(p[nb][0], p[nb][1]);
      uint32_t w1 = pack_bf2(p[nb][2], p[nb][3]);
      *(uint2*)(PtW + pwoff[nb]) = make_uint2(w0, w1);
    }
    asm volatile("s_waitcnt lgkmcnt(0)" ::: "memory");

    __builtin_amdgcn_s_setprio(1);
#pragma unroll
    for (int ks = 0; ks < 2; ++ks) {
      short8 pf = *(const short8*)(PtW + poff[ks]);
      lacc = __builtin_amdgcn_mfma_f32_16x16x32_bf16(pf, vones, lacc, 0, 0, 0);
#pragma unroll
      for (int nd = 0; nd < 4; ++nd) {
        short8 vf = *(const short8*)(Vc + koff[nd][ks]);
        accO[nd] = __builtin_amdgcn_mfma_f32_16x16x32_bf16(pf, vf, accO[nd], 0, 0, 0);
      }
    }
    __builtin_amdgcn_s_setprio(0);

    if (kt > lo) STAGE_WRITE(cur ^ 1);
    __syncthreads();
    cur ^= 1;
    ktoff -= dko;
  }

  if (nsp == 1) {
    float ib[4];
#pragma unroll
    for (int r = 0; r < 4; ++r) ib[r] = 1.0f / lacc[r];
    u16* aop = ao + ((size_t)(b * S_LEN + qt * 64 + wid * 16 + lh * 4)) * D_DIM + h * HDIM;
#pragma unroll
    for (int nd = 0; nd < 4; ++nd)
#pragma unroll
      for (int r = 0; r < 4; ++r)
        aop[(size_t)r * D_DIM + nd * 16 + l4] = f2bf(accO[nd][r] * ib[r]);
  } else {
    const int sbase = (h <= 10) ? (h - 9) * 2 : 4 + (h - 11) * 3;
    const int pidx = sub * 19 + sbase + j;
    float* Op = pO + (size_t)pidx * 4096;
#pragma unroll
    for (int nd = 0; nd < 4; ++nd)
#pragma unroll
      for (int r = 0; r < 4; ++r)
        Op[(wid * 16 + lh * 4 + r) * 64 + nd * 16 + l4] = accO[nd][r];
    float mq[4];
#pragma unroll
    for (int r = 0; r < 4; ++r)
      mq[r] = __shfl(m, (lane & 48) | (lh * 4 + r));
    if (l4 == 0) {
      float* mlp = pML + (size_t)pidx * 128 + (wid * 16 + lh * 4) * 2;
#pragma unroll
      for (int r = 0; r < 4; ++r) {
        mlp[r * 2] = mq[r];
        mlp[r * 2 + 1] = lacc[r];
      }
    }
  }
#undef STAGE_LOAD
#undef STAGE_WRITE
}

// ---------------- combine partials for split heads (h>=9) ----------------
__global__ __launch_bounds__(256) void attn_combine(const float* __restrict__ pO,
                                                    const float* __restrict__ pML,
                                                    u16* __restrict__ ao) {
  const int g = blockIdx.x;        // 448 = 64 subs x 7 heads
  const int sub = g & 63;
  const int h = 9 + (g >> 6);
  const int b = sub >> 5, qt = sub & 31;
  const int nsp = (h <= 10) ? 2 : 3;
  const int sbase = (h <= 10) ? (h - 9) * 2 : 4 + (h - 11) * 3;
  const int pidx0 = sub * 19 + sbase;
  const int tid = threadIdx.x;
  const int row = tid >> 2;
  const int d0 = (tid & 3) * 16;

  float mj[3], lj[3];
#pragma unroll
  for (int k = 0; k < 3; ++k) { mj[k] = -1e30f; lj[k] = 0.f; }
  for (int k = 0; k < nsp; ++k) {
    mj[k] = pML[(size_t)(pidx0 + k) * 128 + row * 2];
    lj[k] = pML[(size_t)(pidx0 + k) * 128 + row * 2 + 1];
  }
  float ms = fmaxf(mj[0], fmaxf(mj[1], mj[2]));
  float w[3];
  float lsum = 0.f;
#pragma unroll
  for (int k = 0; k < 3; ++k) {
    w[k] = exp2f(mj[k] - ms);
    lsum += w[k] * lj[k];
  }
  float inv = 1.0f / lsum;

  u16* aop = ao + ((size_t)(b * S_LEN + qt * 64 + row)) * D_DIM + h * HDIM + d0;
#pragma unroll
  for (int c = 0; c < 4; ++c) {
    float4 o = {0.f, 0.f, 0.f, 0.f};
    for (int k = 0; k < nsp; ++k) {
      const float4 v = *(const float4*)(pO + (size_t)(pidx0 + k) * 4096 + row * 64 + d0 + c * 4);
      o.x += w[k] * v.x; o.y += w[k] * v.y; o.z += w[k] * v.z; o.w += w[k] * v.w;
    }
    ushort4 u4 = make_ushort4(f2bf(o.x * inv), f2bf(o.y * inv), f2bf(o.z * inv), f2bf(o.w * inv));
    *(ushort4*)(aop + c * 4) = u4;
  }
}

extern "C" void kernel_launch(void* const* d_in, const int* in_sizes, int n_in,
                              void* d_out, int out_size, void* d_ws, size_t ws_size,
                              hipStream_t stream) {
  const float* x   = (const float*)d_in[0];
  const float* Wq  = (const float*)d_in[1];
  const float* Wk  = (const float*)d_in[2];
  const float* Wv  = (const float*)d_in[3];
  const float* Wo  = (const float*)d_in[4];
  const float* bo  = (const float*)d_in[5];
  const float* W1  = (const float*)d_in[6];
  const float* b1  = (const float*)d_in[7];
  const float* W2  = (const float*)d_in[8];
  const float* b2  = (const float*)d_in[9];
  const float* g1  = (const float*)d_in[10];
  const float* be1 = (const float*)d_in[11];
  const float* g2  = (const float*)d_in[12];
  const float* be2 = (const float*)d_in[13];

  char* p = (char*)d_ws;
  u16* wqkv = (u16*)p; p += (size_t)3072 * 1024 * 2;
  u16* wo   = (u16*)p; p += (size_t)1024 * 1024 * 2;
  u16* w1   = (u16*)p; p += (size_t)4096 * 1024 * 2;
  u16* w2   = (u16*)p; p += (size_t)4096 * 1024 * 2;
  u16* hb   = (u16*)p; p += (size_t)4096 * 1024 * 2;
  u16* qkvb = (u16*)p; p += (size_t)4096 * 3072 * 2;
  u16* aob  = (u16*)p; p += (size_t)4096 * 1024 * 2;
  float* x1 = (float*)p; p += (size_t)4096 * 1024 * 4;
  u16* h2b  = (u16*)p; p += (size_t)4096 * 1024 * 2;
  u16* ff1  = (u16*)p; p += (size_t)4096 * 4096 * 2;
  u16* vt   = ff1;                                        // 8MB, dead before FFN1
  float* pO = (float*)(ff1 + (size_t)4 * 1024 * 1024);    // partial O (inside ff1)
  float* pML = pO + (size_t)1216 * 4096;                  // partial m,l
  u16* pk = hb;   // FFN2 split-K=4 bf16 partials: 4 x 8MB = hb+qkvb (32MB, dead)

  cast_all<<<12288, 256, 0, stream>>>(Wq, Wk, Wv, Wo, W1, W2, wqkv, wo, w1, w2);

  ln_kernel<<<4096, 256, 0, stream>>>(x, g1, be1, hb);
  gemm8p<0><<<16 * 12, 512, 0, stream>>>(hb, wqkv, qkvb, nullptr, 4096, 3072, 1024, 1);
  transpose_v<<<256, 256, 0, stream>>>(qkvb, vt);
  attn_kernel<<<1792, 256, 0, stream>>>(qkvb, vt, aob, pO, pML);
  attn_combine<<<448, 256, 0, stream>>>(pO, pML, aob);
  gemm_bt<1><<<32 * 8, 256, 0, stream>>>(aob, wo, x1, bo, x, 4096, 1024, 1024, 1);
  ln_kernel<<<4096, 256, 0, stream>>>(x1, g2, be2, h2b);
  gemm8p<2><<<16 * 16, 512, 0, stream>>>(h2b, w1, ff1, b1, 4096, 4096, 1024, 1);
  // FFN2: 8-phase, split-K=4, bf16 partials -> fused reduce
  gemm8p<3><<<4 * 64, 512, 0, stream>>>(ff1, w2, pk, nullptr, 4096, 1024, 4096, 4);
  reduce4_kernel<<<2048, 256, 0, stream>>>(pk, x1, b2, (float*)d_out);
}